// Round 1
// baseline (3496.415 us; speedup 1.0000x reference)
//
#include <hip/hip_runtime.h>

#define BB 2
#define CC 256
#define NN 3600
#define NCH 2
#define HO 473
#define WO 473

// ---------------------------------------------------------------------------
// Generic 64x64x16 fp32 tiled GEMM, 256 threads, 4x4 per thread.
// AL=0: A[m*lda+k] ; AL=1: A[k*lda+m]
// BL=0: B[k*ldb+n] ; BL=1: B[n*ldb+k]
// EXPW=1: B element -> exp(raw - mx[n]); epilogue scales column n by 1/sm[n]
// blockIdx.x -> n tiles, blockIdx.y -> m tiles, blockIdx.z -> batch
// K must be a multiple of 16; M,N multiples of 4.
// ---------------------------------------------------------------------------
template<int AL, int BL, int EXPW>
__global__ __launch_bounds__(256)
void gemm_kernel(const float* __restrict__ A, const float* __restrict__ B,
                 float* __restrict__ C, int M, int N, int K,
                 int lda, int ldb, int ldc,
                 long sA, long sB, long sC,
                 const float* __restrict__ mx, const float* __restrict__ sm, int sStat)
{
    const int b = blockIdx.z;
    A += (long)b * sA;
    B += (long)b * sB;
    C += (long)b * sC;
    const float* mxp = nullptr;
    const float* smp = nullptr;
    if (EXPW) { mxp = mx + (long)b * sStat; smp = sm + (long)b * sStat; }

    __shared__ float As[16][68];
    __shared__ float Bs[16][68];

    const int t  = threadIdx.x;
    const int tx = t & 15;   // n direction
    const int ty = t >> 4;   // m direction
    const int m0 = blockIdx.y * 64;
    const int n0 = blockIdx.x * 64;

    float acc[4][4];
#pragma unroll
    for (int i = 0; i < 4; ++i)
#pragma unroll
        for (int j = 0; j < 4; ++j) acc[i][j] = 0.f;

    for (int k0 = 0; k0 < K; k0 += 16) {
        // ---- stage A tile -> As[k][m]
        if (AL == 1) {
            int kk = t >> 4, ml = (t & 15) * 4;
            int m = m0 + ml;
            float4 v = make_float4(0.f, 0.f, 0.f, 0.f);
            if (m < M) v = *(const float4*)(A + (long)(k0 + kk) * lda + m);
            As[kk][ml + 0] = v.x; As[kk][ml + 1] = v.y;
            As[kk][ml + 2] = v.z; As[kk][ml + 3] = v.w;
        } else {
            int ml = t >> 2, kl = (t & 3) * 4;
            int m = m0 + ml;
            float4 v = make_float4(0.f, 0.f, 0.f, 0.f);
            if (m < M) v = *(const float4*)(A + (long)m * lda + k0 + kl);
            As[kl + 0][ml] = v.x; As[kl + 1][ml] = v.y;
            As[kl + 2][ml] = v.z; As[kl + 3][ml] = v.w;
        }
        // ---- stage B tile -> Bs[k][n]
        if (BL == 0) {
            int kk = t >> 4, nl = (t & 15) * 4;
            int n = n0 + nl;
            float4 v = make_float4(0.f, 0.f, 0.f, 0.f);
            if (n < N) {
                v = *(const float4*)(B + (long)(k0 + kk) * ldb + n);
                if (EXPW) {
                    v.x = __expf(v.x - mxp[n + 0]);
                    v.y = __expf(v.y - mxp[n + 1]);
                    v.z = __expf(v.z - mxp[n + 2]);
                    v.w = __expf(v.w - mxp[n + 3]);
                }
            }
            Bs[kk][nl + 0] = v.x; Bs[kk][nl + 1] = v.y;
            Bs[kk][nl + 2] = v.z; Bs[kk][nl + 3] = v.w;
        } else {
            int nl = t >> 2, kl = (t & 3) * 4;
            int n = n0 + nl;
            float4 v = make_float4(0.f, 0.f, 0.f, 0.f);
            if (n < N) {
                v = *(const float4*)(B + (long)n * ldb + k0 + kl);
                if (EXPW) {
                    float mv = mxp[n];
                    v.x = __expf(v.x - mv); v.y = __expf(v.y - mv);
                    v.z = __expf(v.z - mv); v.w = __expf(v.w - mv);
                }
            }
            Bs[kl + 0][nl] = v.x; Bs[kl + 1][nl] = v.y;
            Bs[kl + 2][nl] = v.z; Bs[kl + 3][nl] = v.w;
        }
        __syncthreads();

#pragma unroll
        for (int kk = 0; kk < 16; ++kk) {
            float a0 = As[kk][ty * 4 + 0], a1 = As[kk][ty * 4 + 1];
            float a2 = As[kk][ty * 4 + 2], a3 = As[kk][ty * 4 + 3];
            float b0 = Bs[kk][tx * 4 + 0], b1 = Bs[kk][tx * 4 + 1];
            float b2 = Bs[kk][tx * 4 + 2], b3 = Bs[kk][tx * 4 + 3];
            acc[0][0] += a0 * b0; acc[0][1] += a0 * b1; acc[0][2] += a0 * b2; acc[0][3] += a0 * b3;
            acc[1][0] += a1 * b0; acc[1][1] += a1 * b1; acc[1][2] += a1 * b2; acc[1][3] += a1 * b3;
            acc[2][0] += a2 * b0; acc[2][1] += a2 * b1; acc[2][2] += a2 * b2; acc[2][3] += a2 * b3;
            acc[3][0] += a3 * b0; acc[3][1] += a3 * b1; acc[3][2] += a3 * b2; acc[3][3] += a3 * b3;
        }
        __syncthreads();
    }

    float scl[4] = {1.f, 1.f, 1.f, 1.f};
    int nbase = n0 + tx * 4;
    if (EXPW && nbase < N) {
        scl[0] = 1.f / smp[nbase + 0];
        scl[1] = 1.f / smp[nbase + 1];
        scl[2] = 1.f / smp[nbase + 2];
        scl[3] = 1.f / smp[nbase + 3];
    }
    if (nbase < N) {
#pragma unroll
        for (int i = 0; i < 4; ++i) {
            int m = m0 + ty * 4 + i;
            if (m < M) {
                float4 o;
                o.x = acc[i][0] * scl[0]; o.y = acc[i][1] * scl[1];
                o.z = acc[i][2] * scl[2]; o.w = acc[i][3] * scl[3];
                *(float4*)(C + (long)m * ldc + nbase) = o;
            }
        }
    }
}

// ---------------------------------------------------------------------------
// 3x3 same-pad conv as implicit GEMM. Wt: [9*CIN][256] (k-major, co contig).
// Input: up to 3 channel-planes of 256ch each, per-batch stride CC*NN.
// Output Y: [B][256][3600].
// ---------------------------------------------------------------------------
template<int CIN>
__global__ __launch_bounds__(256)
void conv3x3_kernel(const float* __restrict__ Wt,
                    const float* __restrict__ P0, const float* __restrict__ P1,
                    const float* __restrict__ P2, float* __restrict__ Y)
{
    const int b = blockIdx.z;
    const float* pl0 = P0 + (long)b * CC * NN;
    const float* pl1 = P1 + (long)b * CC * NN;
    const float* pl2 = P2 + (long)b * CC * NN;

    __shared__ float As[16][68];
    __shared__ float Bs[16][68];

    const int t = threadIdx.x;
    const int tx = t & 15;   // p direction
    const int ty = t >> 4;   // co direction
    const int co0 = blockIdx.y * 64;
    const int p0  = blockIdx.x * 64;

    float acc[4][4];
#pragma unroll
    for (int i = 0; i < 4; ++i)
#pragma unroll
        for (int j = 0; j < 4; ++j) acc[i][j] = 0.f;

    const int KT = 9 * CIN;
    for (int k0 = 0; k0 < KT; k0 += 16) {
        { // weights
            int kk = t >> 4, ml = (t & 15) * 4;
            float4 v = *(const float4*)(Wt + (long)(k0 + kk) * CC + co0 + ml);
            As[kk][ml + 0] = v.x; As[kk][ml + 1] = v.y;
            As[kk][ml + 2] = v.z; As[kk][ml + 3] = v.w;
        }
        { // shifted input gather
            int kk = t >> 4, jl = (t & 15) * 4;
            int k = k0 + kk;
            int tap = k / CIN;
            int ci  = k - tap * CIN;
            int dh = tap / 3 - 1;
            int dw = tap - (tap / 3) * 3 - 1;
            int pidx = ci >> 8;
            const float* src = (pidx == 0) ? pl0 : ((pidx == 1) ? pl1 : pl2);
            src += (long)(ci & 255) * NN;
            int off = dh * 60 + dw;
#pragma unroll
            for (int i = 0; i < 4; ++i) {
                int p = p0 + jl + i;
                float v = 0.f;
                if (p < NN) {
                    int h = p / 60;
                    int w = p - h * 60;
                    int hh = h + dh, ww = w + dw;
                    if (hh >= 0 && hh < 60 && ww >= 0 && ww < 60) v = src[p + off];
                }
                Bs[kk][jl + i] = v;
            }
        }
        __syncthreads();
#pragma unroll
        for (int kk = 0; kk < 16; ++kk) {
            float a0 = As[kk][ty * 4 + 0], a1 = As[kk][ty * 4 + 1];
            float a2 = As[kk][ty * 4 + 2], a3 = As[kk][ty * 4 + 3];
            float b0 = Bs[kk][tx * 4 + 0], b1 = Bs[kk][tx * 4 + 1];
            float b2 = Bs[kk][tx * 4 + 2], b3 = Bs[kk][tx * 4 + 3];
            acc[0][0] += a0 * b0; acc[0][1] += a0 * b1; acc[0][2] += a0 * b2; acc[0][3] += a0 * b3;
            acc[1][0] += a1 * b0; acc[1][1] += a1 * b1; acc[1][2] += a1 * b2; acc[1][3] += a1 * b3;
            acc[2][0] += a2 * b0; acc[2][1] += a2 * b1; acc[2][2] += a2 * b2; acc[2][3] += a2 * b3;
            acc[3][0] += a3 * b0; acc[3][1] += a3 * b1; acc[3][2] += a3 * b2; acc[3][3] += a3 * b3;
        }
        __syncthreads();
    }

    int pbase = p0 + tx * 4;
    if (pbase < NN) {
        float* Yb = Y + (long)b * CC * NN;
#pragma unroll
        for (int i = 0; i < 4; ++i) {
            int co = co0 + ty * 4 + i;
            float4 o;
            o.x = acc[i][0]; o.y = acc[i][1]; o.z = acc[i][2]; o.w = acc[i][3];
            *(float4*)(Yb + (long)co * NN + pbase) = o;
        }
    }
}

// ---------------------------------------------------------------------------
// Online-softmax stats
// ---------------------------------------------------------------------------
__global__ __launch_bounds__(256)
void rowstats_kernel(const float* __restrict__ S, float* __restrict__ rmax, float* __restrict__ rsum)
{
    int row = blockIdx.x;           // 0..BB*NN-1
    int b = row / NN, n = row - b * NN;
    const float* Sp = S + (long)b * NN * NN + (long)n * NN;
    int t = threadIdx.x;
    float mx = -3.0e38f, s = 0.f;
    for (int i = t; i < NN; i += 256) {
        float v = Sp[i];
        if (v > mx) { s = s * __expf(mx - v) + 1.f; mx = v; }
        else        { s += __expf(v - mx); }
    }
    __shared__ float lm[256], ls[256];
    lm[t] = mx; ls[t] = s;
    __syncthreads();
    for (int off = 128; off > 0; off >>= 1) {
        if (t < off) {
            float m1 = lm[t], m2 = lm[t + off];
            float M = fmaxf(m1, m2);
            ls[t] = ls[t] * __expf(m1 - M) + ls[t + off] * __expf(m2 - M);
            lm[t] = M;
        }
        __syncthreads();
    }
    if (t == 0) { rmax[row] = lm[0]; rsum[row] = ls[0]; }
}

__global__ __launch_bounds__(256)
void colstats_kernel(const float* __restrict__ S, float* __restrict__ cmax, float* __restrict__ csum)
{
    int tid = blockIdx.x * 256 + threadIdx.x;
    if (tid >= BB * NN) return;
    int b = tid / NN, m = tid - b * NN;
    const float* Sp = S + (long)b * NN * NN + m;
    float mx = -3.0e38f, s = 0.f;
    for (int n = 0; n < NN; ++n) {
        float v = Sp[(long)n * NN];
        if (v > mx) { s = s * __expf(mx - v) + 1.f; mx = v; }
        else        { s += __expf(v - mx); }
    }
    cmax[tid] = mx; csum[tid] = s;
}

// ---------------------------------------------------------------------------
// Gate: Z *= sigmoid(sum_c gate_w[c] * Z[c, p])   (in place)
// block = 64 pixels x 4 channel-chunks
// ---------------------------------------------------------------------------
__global__ __launch_bounds__(256)
void gate_kernel(float* __restrict__ Z, const float* __restrict__ gw)
{
    int t = threadIdx.x;
    int px = t & 63, ck = t >> 6;
    int b = blockIdx.y;
    int p = blockIdx.x * 64 + px;
    float* Zb = Z + (long)b * CC * NN;
    float g = 0.f;
    if (p < NN) {
        for (int c = ck * 64; c < ck * 64 + 64; ++c) g += gw[c] * Zb[(long)c * NN + p];
    }
    __shared__ float red[256];
    __shared__ float sg[64];
    red[t] = g;
    __syncthreads();
    if (t < 64) {
        float tot = red[t] + red[t + 64] + red[t + 128] + red[t + 192];
        sg[t] = 1.f / (1.f + __expf(-tot));
    }
    __syncthreads();
    if (p < NN) {
        float s = sg[px];
        for (int c = ck * 64; c < ck * 64 + 64; ++c) Zb[(long)c * NN + p] *= s;
    }
}

// ---------------------------------------------------------------------------
// BatchNorm batch-stats -> scale/shift
// ---------------------------------------------------------------------------
__global__ __launch_bounds__(256)
void bn_stats_kernel(const float* __restrict__ Y, const float* __restrict__ g,
                     const float* __restrict__ beta, float* __restrict__ scale,
                     float* __restrict__ shift)
{
    int c = blockIdx.x, t = threadIdx.x;
    float s = 0.f, sq = 0.f;
    for (int b = 0; b < BB; ++b) {
        const float* p = Y + (long)b * CC * NN + (long)c * NN;
        for (int i = t; i < NN; i += 256) { float v = p[i]; s += v; sq += v * v; }
    }
    __shared__ float ls[256], lq[256];
    ls[t] = s; lq[t] = sq;
    __syncthreads();
    for (int off = 128; off > 0; off >>= 1) {
        if (t < off) { ls[t] += ls[t + off]; lq[t] += lq[t + off]; }
        __syncthreads();
    }
    if (t == 0) {
        const float inv = 1.f / (float)(BB * NN);
        float mean = ls[0] * inv;
        float var = fmaxf(lq[0] * inv - mean * mean, 0.f);
        float sc = g[c] * rsqrtf(var + 1e-5f);
        scale[c] = sc;
        shift[c] = beta[c] - mean * sc;
    }
}

// ---------------------------------------------------------------------------
// Fused BN-normalize + ReLU + 1x1 cls conv + bias.
// block = 64 pixels x 4 channel-chunks
// ---------------------------------------------------------------------------
__global__ __launch_bounds__(256)
void cls_kernel(const float* __restrict__ Y, const float* __restrict__ scale,
                const float* __restrict__ shift, const float* __restrict__ cw,
                const float* __restrict__ cb, float* __restrict__ O)
{
    int t = threadIdx.x;
    int px = t & 63, ck = t >> 6;
    int b = blockIdx.y;
    int p = blockIdx.x * 64 + px;
    const float* Yb = Y + (long)b * CC * NN;
    float a0 = 0.f, a1 = 0.f;
    if (p < NN) {
        for (int c = ck * 64; c < ck * 64 + 64; ++c) {
            float v = Yb[(long)c * NN + p] * scale[c] + shift[c];
            v = fmaxf(v, 0.f);
            a0 += cw[c] * v;
            a1 += cw[CC + c] * v;
        }
    }
    __shared__ float r0[256], r1[256];
    r0[t] = a0; r1[t] = a1;
    __syncthreads();
    if (t < 64) {
        int pp = blockIdx.x * 64 + t;
        if (pp < NN) {
            float s0 = r0[t] + r0[t + 64] + r0[t + 128] + r0[t + 192];
            float s1 = r1[t] + r1[t + 64] + r1[t + 128] + r1[t + 192];
            O[(long)b * NCH * NN + pp] = s0 + cb[0];
            O[(long)b * NCH * NN + NN + pp] = s1 + cb[1];
        }
    }
}

// ---------------------------------------------------------------------------
// Bilinear resize 60x60 -> 473x473 (half-pixel, clamp) + sigmoid
// ---------------------------------------------------------------------------
__global__ __launch_bounds__(256)
void resize_sig_kernel(const float* __restrict__ I1, const float* __restrict__ I2,
                       float* __restrict__ O)
{
    const long HALF = (long)BB * NCH * HO * WO;
    long gid = (long)blockIdx.x * 256 + threadIdx.x;
    if (gid >= HALF) return;
    int half = blockIdx.y;
    const float* I = half ? I2 : I1;
    float* Op = O + half * HALF;

    int j = (int)(gid % WO);
    long r = gid / WO;
    int i = (int)(r % HO);
    int pc = (int)(r / HO);          // b*NCH + nc
    const float* ip = I + (long)pc * NN;

    const float SCL = 60.0f / 473.0f;
    float fy = (i + 0.5f) * SCL - 0.5f;
    float fx = (j + 0.5f) * SCL - 0.5f;
    int y0 = (int)floorf(fy);
    int x0 = (int)floorf(fx);
    float ty = fy - (float)y0;
    float tx = fx - (float)x0;
    int y0c = max(y0, 0), y1c = min(y0 + 1, 59);
    int x0c = max(x0, 0), x1c = min(x0 + 1, 59);
    float va = ip[y0c * 60 + x0c], vb = ip[y0c * 60 + x1c];
    float vc = ip[y1c * 60 + x0c], vd = ip[y1c * 60 + x1c];
    float v = (1.f - ty) * ((1.f - tx) * va + tx * vb) + ty * ((1.f - tx) * vc + tx * vd);
    Op[gid] = 1.f / (1.f + __expf(-v));
}

// ---------------------------------------------------------------------------
// Small weight transposes
// ---------------------------------------------------------------------------
__global__ __launch_bounds__(256)
void transpose_we(const float* __restrict__ W, float* __restrict__ WT)
{
    int idx = blockIdx.x * 256 + threadIdx.x;
    if (idx < CC * CC) {
        int c = idx >> 8, d = idx & 255;
        WT[idx] = W[d * CC + c];
    }
}

template<int CIN>
__global__ __launch_bounds__(256)
void transpose_convw(const float* __restrict__ W, float* __restrict__ WT)
{
    int idx = blockIdx.x * 256 + threadIdx.x;
    if (idx < 9 * CIN * CC) {
        int co = idx & 255;
        int rest = idx >> 8;
        int ci = rest % CIN;
        int tap = rest / CIN;
        WT[idx] = W[((long)co * CIN + ci) * 9 + tap];
    }
}

// ---------------------------------------------------------------------------
extern "C" void kernel_launch(void* const* d_in, const int* in_sizes, int n_in,
                              void* d_out, int out_size, void* d_ws, size_t ws_size,
                              hipStream_t stream)
{
    const float* V_a    = (const float*)d_in[0];
    const float* V_b    = (const float*)d_in[1];
    const float* D_a    = (const float*)d_in[2];
    const float* W_e    = (const float*)d_in[3];
    const float* gate_w = (const float*)d_in[4];
    const float* conv1_w = (const float*)d_in[5];
    const float* conv2_w = (const float*)d_in[6];
    const float* bn1_g = (const float*)d_in[7];
    const float* bn1_b = (const float*)d_in[8];
    const float* bn2_g = (const float*)d_in[9];
    const float* bn2_b = (const float*)d_in[10];
    const float* cls1_w = (const float*)d_in[11];
    const float* cls1_b = (const float*)d_in[12];
    const float* cls2_w = (const float*)d_in[13];
    const float* cls2_b = (const float*)d_in[14];
    float* out = (float*)d_out;
    float* ws  = (float*)d_ws;

    // workspace layout (floats)
    float* wet = ws;                    // 256*256          = 65536
    float* w1t = wet + 65536;           // 9*768*256        = 1769472
    float* w2t = w1t + 1769472;         // 9*512*256        = 1179648
    float* wgt = w2t + 1179648;         // B*N*C            = 1843200
    float* S   = wgt + 1843200;         // B*N*N            = 25920000
    float* rmx = S   + 25920000;        // 7200
    float* rsm = rmx + 7200;
    float* cmx = rsm + 7200;
    float* csm = cmx + 7200;
    float* Za  = csm + 7200;            // 1843200 (att1)
    float* Zb  = Za  + 1843200;         // 1843200 (att2)
    float* y1  = Zb  + 1843200;         // 1843200
    float* y2  = y1  + 1843200;         // 1843200
    float* b1s = y2  + 1843200;         // 256
    float* b1h = b1s + 256;
    float* b2s = b1h + 256;
    float* b2h = b2s + 256;
    float* c1o = b2h + 256;             // B*NC*N = 14400
    float* c2o = c1o + 14400;           // 14400

    dim3 blk(256);

    transpose_we<<<256, blk, 0, stream>>>(W_e, wet);
    transpose_convw<768><<<6912, blk, 0, stream>>>(conv1_w, w1t);
    transpose_convw<512><<<4608, blk, 0, stream>>>(conv2_w, w2t);

    // weighted[b,n,d] = sum_c V_a[b,c,n] * W_e[d,c]   (M=N(3600), N=C, K=C)
    gemm_kernel<1,0,0><<<dim3(4, 57, BB), blk, 0, stream>>>(
        V_a, wet, wgt, NN, CC, CC, NN, CC, CC,
        (long)CC * NN, 0L, (long)NN * CC, nullptr, nullptr, 0);

    // S[b,n,m] = sum_d weighted[b,n,d] * V_b[b,d,m]   (M=3600, N=3600, K=256)
    gemm_kernel<0,0,0><<<dim3(57, 57, BB), blk, 0, stream>>>(
        wgt, V_b, S, NN, NN, CC, CC, NN, NN,
        (long)NN * CC, (long)CC * NN, (long)NN * NN, nullptr, nullptr, 0);

    rowstats_kernel<<<dim3(BB * NN), blk, 0, stream>>>(S, rmx, rsm);
    colstats_kernel<<<dim3((BB * NN + 255) / 256), blk, 0, stream>>>(S, cmx, csm);

    // Z_b[b,c,m] = sum_n V_a[b,c,n] * exp(S[n,m]-cmax[m])/csum[m]
    gemm_kernel<0,0,1><<<dim3(57, 4, BB), blk, 0, stream>>>(
        V_a, S, Zb, CC, NN, NN, NN, NN, NN,
        (long)CC * NN, (long)NN * NN, (long)CC * NN, cmx, csm, NN);

    // Z_a[b,c,m] = sum_n V_b[b,c,n] * exp(S[m,n]-rmax[m])/rsum[m]
    gemm_kernel<0,1,1><<<dim3(57, 4, BB), blk, 0, stream>>>(
        V_b, S, Za, CC, NN, NN, NN, NN, NN,
        (long)CC * NN, (long)NN * NN, (long)CC * NN, rmx, rsm, NN);

    gate_kernel<<<dim3(57, BB), blk, 0, stream>>>(Za, gate_w);
    gate_kernel<<<dim3(57, BB), blk, 0, stream>>>(Zb, gate_w);

    // conv1: input = [att1(Za), V_a, D_a]  (768 ch)
    conv3x3_kernel<768><<<dim3(57, 4, BB), blk, 0, stream>>>(w1t, Za, V_a, D_a, y1);
    // conv2: input = [att2(Zb), V_b]       (512 ch)
    conv3x3_kernel<512><<<dim3(57, 4, BB), blk, 0, stream>>>(w2t, Zb, V_b, V_b, y2);

    bn_stats_kernel<<<256, blk, 0, stream>>>(y1, bn1_g, bn1_b, b1s, b1h);
    bn_stats_kernel<<<256, blk, 0, stream>>>(y2, bn2_g, bn2_b, b2s, b2h);

    cls_kernel<<<dim3(57, BB), blk, 0, stream>>>(y1, b1s, b1h, cls1_w, cls1_b, c1o);
    cls_kernel<<<dim3(57, BB), blk, 0, stream>>>(y2, b2s, b2h, cls2_w, cls2_b, c2o);

    resize_sig_kernel<<<dim3((BB * NCH * HO * WO + 255) / 256, 2), blk, 0, stream>>>(c1o, c2o, out);
}

// Round 2
// 2356.274 us; speedup vs baseline: 1.4839x; 1.4839x over previous
//
#include <hip/hip_runtime.h>

#define BB 2
#define CC 256
#define NN 3600
#define NCH 2
#define HO 473
#define WO 473
#define RCH 36          // row chunks for column-stats partial pass (100 rows each)

// ---------------------------------------------------------------------------
// Generic 64x64x16 fp32 tiled GEMM, 256 threads, 4x4 per thread.
// AL=0: A[m*lda+k] ; AL=1: A[k*lda+m]
// BL=0: B[k*ldb+n] ; BL=1: B[n*ldb+k]
// EXPW=1: B element -> exp(raw - mx[n]); epilogue scales column n by 1/sm[n]
// blockIdx.x -> n tiles, blockIdx.y -> m tiles, blockIdx.z -> batch
// K must be a multiple of 16; M,N multiples of 4.
// ---------------------------------------------------------------------------
template<int AL, int BL, int EXPW>
__global__ __launch_bounds__(256)
void gemm_kernel(const float* __restrict__ A, const float* __restrict__ B,
                 float* __restrict__ C, int M, int N, int K,
                 int lda, int ldb, int ldc,
                 long sA, long sB, long sC,
                 const float* __restrict__ mx, const float* __restrict__ sm, int sStat)
{
    const int b = blockIdx.z;
    A += (long)b * sA;
    B += (long)b * sB;
    C += (long)b * sC;
    const float* mxp = nullptr;
    const float* smp = nullptr;
    if (EXPW) { mxp = mx + (long)b * sStat; smp = sm + (long)b * sStat; }

    __shared__ float As[16][68];
    __shared__ float Bs[16][68];

    const int t  = threadIdx.x;
    const int tx = t & 15;   // n direction
    const int ty = t >> 4;   // m direction
    const int m0 = blockIdx.y * 64;
    const int n0 = blockIdx.x * 64;

    float acc[4][4];
#pragma unroll
    for (int i = 0; i < 4; ++i)
#pragma unroll
        for (int j = 0; j < 4; ++j) acc[i][j] = 0.f;

    for (int k0 = 0; k0 < K; k0 += 16) {
        // ---- stage A tile -> As[k][m]
        if (AL == 1) {
            int kk = t >> 4, ml = (t & 15) * 4;
            int m = m0 + ml;
            float4 v = make_float4(0.f, 0.f, 0.f, 0.f);
            if (m < M) v = *(const float4*)(A + (long)(k0 + kk) * lda + m);
            As[kk][ml + 0] = v.x; As[kk][ml + 1] = v.y;
            As[kk][ml + 2] = v.z; As[kk][ml + 3] = v.w;
        } else {
            int ml = t >> 2, kl = (t & 3) * 4;
            int m = m0 + ml;
            float4 v = make_float4(0.f, 0.f, 0.f, 0.f);
            if (m < M) v = *(const float4*)(A + (long)m * lda + k0 + kl);
            As[kl + 0][ml] = v.x; As[kl + 1][ml] = v.y;
            As[kl + 2][ml] = v.z; As[kl + 3][ml] = v.w;
        }
        // ---- stage B tile -> Bs[k][n]
        if (BL == 0) {
            int kk = t >> 4, nl = (t & 15) * 4;
            int n = n0 + nl;
            float4 v = make_float4(0.f, 0.f, 0.f, 0.f);
            if (n < N) {
                v = *(const float4*)(B + (long)(k0 + kk) * ldb + n);
                if (EXPW) {
                    v.x = __expf(v.x - mxp[n + 0]);
                    v.y = __expf(v.y - mxp[n + 1]);
                    v.z = __expf(v.z - mxp[n + 2]);
                    v.w = __expf(v.w - mxp[n + 3]);
                }
            }
            Bs[kk][nl + 0] = v.x; Bs[kk][nl + 1] = v.y;
            Bs[kk][nl + 2] = v.z; Bs[kk][nl + 3] = v.w;
        } else {
            int nl = t >> 2, kl = (t & 3) * 4;
            int n = n0 + nl;
            float4 v = make_float4(0.f, 0.f, 0.f, 0.f);
            if (n < N) {
                v = *(const float4*)(B + (long)n * ldb + k0 + kl);
                if (EXPW) {
                    float mv = mxp[n];
                    v.x = __expf(v.x - mv); v.y = __expf(v.y - mv);
                    v.z = __expf(v.z - mv); v.w = __expf(v.w - mv);
                }
            }
            Bs[kl + 0][nl] = v.x; Bs[kl + 1][nl] = v.y;
            Bs[kl + 2][nl] = v.z; Bs[kl + 3][nl] = v.w;
        }
        __syncthreads();

#pragma unroll
        for (int kk = 0; kk < 16; ++kk) {
            float a0 = As[kk][ty * 4 + 0], a1 = As[kk][ty * 4 + 1];
            float a2 = As[kk][ty * 4 + 2], a3 = As[kk][ty * 4 + 3];
            float b0 = Bs[kk][tx * 4 + 0], b1 = Bs[kk][tx * 4 + 1];
            float b2 = Bs[kk][tx * 4 + 2], b3 = Bs[kk][tx * 4 + 3];
            acc[0][0] += a0 * b0; acc[0][1] += a0 * b1; acc[0][2] += a0 * b2; acc[0][3] += a0 * b3;
            acc[1][0] += a1 * b0; acc[1][1] += a1 * b1; acc[1][2] += a1 * b2; acc[1][3] += a1 * b3;
            acc[2][0] += a2 * b0; acc[2][1] += a2 * b1; acc[2][2] += a2 * b2; acc[2][3] += a2 * b3;
            acc[3][0] += a3 * b0; acc[3][1] += a3 * b1; acc[3][2] += a3 * b2; acc[3][3] += a3 * b3;
        }
        __syncthreads();
    }

    float scl[4] = {1.f, 1.f, 1.f, 1.f};
    int nbase = n0 + tx * 4;
    if (EXPW && nbase < N) {
        scl[0] = 1.f / smp[nbase + 0];
        scl[1] = 1.f / smp[nbase + 1];
        scl[2] = 1.f / smp[nbase + 2];
        scl[3] = 1.f / smp[nbase + 3];
    }
    if (nbase < N) {
#pragma unroll
        for (int i = 0; i < 4; ++i) {
            int m = m0 + ty * 4 + i;
            if (m < M) {
                float4 o;
                o.x = acc[i][0] * scl[0]; o.y = acc[i][1] * scl[1];
                o.z = acc[i][2] * scl[2]; o.w = acc[i][3] * scl[3];
                *(float4*)(C + (long)m * ldc + nbase) = o;
            }
        }
    }
}

// ---------------------------------------------------------------------------
// 3x3 same-pad conv as implicit GEMM. Wt: [9*CIN][256] (k-major, co contig).
// Input: up to 3 channel-planes of 256ch each, per-batch stride CC*NN.
// Output Y: [B][256][3600].
// ---------------------------------------------------------------------------
template<int CIN>
__global__ __launch_bounds__(256)
void conv3x3_kernel(const float* __restrict__ Wt,
                    const float* __restrict__ P0, const float* __restrict__ P1,
                    const float* __restrict__ P2, float* __restrict__ Y)
{
    const int b = blockIdx.z;
    const float* pl0 = P0 + (long)b * CC * NN;
    const float* pl1 = P1 + (long)b * CC * NN;
    const float* pl2 = P2 + (long)b * CC * NN;

    __shared__ float As[16][68];
    __shared__ float Bs[16][68];

    const int t = threadIdx.x;
    const int tx = t & 15;   // p direction
    const int ty = t >> 4;   // co direction
    const int co0 = blockIdx.y * 64;
    const int p0  = blockIdx.x * 64;

    float acc[4][4];
#pragma unroll
    for (int i = 0; i < 4; ++i)
#pragma unroll
        for (int j = 0; j < 4; ++j) acc[i][j] = 0.f;

    const int KT = 9 * CIN;
    for (int k0 = 0; k0 < KT; k0 += 16) {
        { // weights
            int kk = t >> 4, ml = (t & 15) * 4;
            float4 v = *(const float4*)(Wt + (long)(k0 + kk) * CC + co0 + ml);
            As[kk][ml + 0] = v.x; As[kk][ml + 1] = v.y;
            As[kk][ml + 2] = v.z; As[kk][ml + 3] = v.w;
        }
        { // shifted input gather
            int kk = t >> 4, jl = (t & 15) * 4;
            int k = k0 + kk;
            int tap = k / CIN;
            int ci  = k - tap * CIN;
            int dh = tap / 3 - 1;
            int dw = tap - (tap / 3) * 3 - 1;
            int pidx = ci >> 8;
            const float* src = (pidx == 0) ? pl0 : ((pidx == 1) ? pl1 : pl2);
            src += (long)(ci & 255) * NN;
            int off = dh * 60 + dw;
#pragma unroll
            for (int i = 0; i < 4; ++i) {
                int p = p0 + jl + i;
                float v = 0.f;
                if (p < NN) {
                    int h = p / 60;
                    int w = p - h * 60;
                    int hh = h + dh, ww = w + dw;
                    if (hh >= 0 && hh < 60 && ww >= 0 && ww < 60) v = src[p + off];
                }
                Bs[kk][jl + i] = v;
            }
        }
        __syncthreads();
#pragma unroll
        for (int kk = 0; kk < 16; ++kk) {
            float a0 = As[kk][ty * 4 + 0], a1 = As[kk][ty * 4 + 1];
            float a2 = As[kk][ty * 4 + 2], a3 = As[kk][ty * 4 + 3];
            float b0 = Bs[kk][tx * 4 + 0], b1 = Bs[kk][tx * 4 + 1];
            float b2 = Bs[kk][tx * 4 + 2], b3 = Bs[kk][tx * 4 + 3];
            acc[0][0] += a0 * b0; acc[0][1] += a0 * b1; acc[0][2] += a0 * b2; acc[0][3] += a0 * b3;
            acc[1][0] += a1 * b0; acc[1][1] += a1 * b1; acc[1][2] += a1 * b2; acc[1][3] += a1 * b3;
            acc[2][0] += a2 * b0; acc[2][1] += a2 * b1; acc[2][2] += a2 * b2; acc[2][3] += a2 * b3;
            acc[3][0] += a3 * b0; acc[3][1] += a3 * b1; acc[3][2] += a3 * b2; acc[3][3] += a3 * b3;
        }
        __syncthreads();
    }

    int pbase = p0 + tx * 4;
    if (pbase < NN) {
        float* Yb = Y + (long)b * CC * NN;
#pragma unroll
        for (int i = 0; i < 4; ++i) {
            int co = co0 + ty * 4 + i;
            float4 o;
            o.x = acc[i][0]; o.y = acc[i][1]; o.z = acc[i][2]; o.w = acc[i][3];
            *(float4*)(Yb + (long)co * NN + pbase) = o;
        }
    }
}

// ---------------------------------------------------------------------------
// Row stats (softmax over the contiguous dim): one block per row, coalesced.
// ---------------------------------------------------------------------------
__global__ __launch_bounds__(256)
void rowstats_kernel(const float* __restrict__ S, float* __restrict__ rmax, float* __restrict__ rsum)
{
    int row = blockIdx.x;           // 0..BB*NN-1
    int b = row / NN, n = row - b * NN;
    const float* Sp = S + (long)b * NN * NN + (long)n * NN;
    int t = threadIdx.x;
    float mx = -3.0e38f, s = 0.f;
    for (int i = t; i < NN; i += 256) {
        float v = Sp[i];
        if (v > mx) { s = s * __expf(mx - v) + 1.f; mx = v; }
        else        { s += __expf(v - mx); }
    }
    __shared__ float lm[256], ls[256];
    lm[t] = mx; ls[t] = s;
    __syncthreads();
    for (int off = 128; off > 0; off >>= 1) {
        if (t < off) {
            float m1 = lm[t], m2 = lm[t + off];
            float M = fmaxf(m1, m2);
            ls[t] = ls[t] * __expf(m1 - M) + ls[t + off] * __expf(m2 - M);
            lm[t] = M;
        }
        __syncthreads();
    }
    if (t == 0) { rmax[row] = lm[0]; rsum[row] = ls[0]; }
}

// ---------------------------------------------------------------------------
// Column stats, phase 1: coalesced partials.
// grid: (ceil(NN/256), RCH, BB). Thread owns one column within a 256-col
// chunk, scans NN/RCH rows -> per-row reads are 256 consecutive floats.
// partial layout: [b][rc][NN]
// ---------------------------------------------------------------------------
__global__ __launch_bounds__(256)
void colstats_part_kernel(const float* __restrict__ S,
                          float* __restrict__ pmax, float* __restrict__ psum)
{
    const int ROWS = NN / RCH;      // 100
    int col = blockIdx.x * 256 + threadIdx.x;
    int rc = blockIdx.y;
    int b = blockIdx.z;
    if (col >= NN) return;
    const float* Sp = S + (long)b * NN * NN + (long)(rc * ROWS) * NN + col;
    float mx = -3.0e38f, s = 0.f;
    for (int r = 0; r < ROWS; ++r) {
        float v = Sp[(long)r * NN];
        if (v > mx) { s = s * __expf(mx - v) + 1.f; mx = v; }
        else        { s += __expf(v - mx); }
    }
    long o = ((long)b * RCH + rc) * NN + col;
    pmax[o] = mx; psum[o] = s;
}

// phase 2: merge RCH partials per column
__global__ __launch_bounds__(256)
void colstats_comb_kernel(const float* __restrict__ pmax, const float* __restrict__ psum,
                          float* __restrict__ cmax, float* __restrict__ csum)
{
    int tid = blockIdx.x * 256 + threadIdx.x;
    if (tid >= BB * NN) return;
    int b = tid / NN, col = tid - b * NN;
    float mx = -3.0e38f, s = 0.f;
    for (int rc = 0; rc < RCH; ++rc) {
        long o = ((long)b * RCH + rc) * NN + col;
        float m2 = pmax[o], s2 = psum[o];
        float M = fmaxf(mx, m2);
        s = s * __expf(mx - M) + s2 * __expf(m2 - M);
        mx = M;
    }
    cmax[tid] = mx; csum[tid] = s;
}

// ---------------------------------------------------------------------------
// Gate: Z *= sigmoid(sum_c gate_w[c] * Z[c, p])   (in place)
// block = 64 pixels x 4 channel-chunks
// ---------------------------------------------------------------------------
__global__ __launch_bounds__(256)
void gate_kernel(float* __restrict__ Z, const float* __restrict__ gw)
{
    int t = threadIdx.x;
    int px = t & 63, ck = t >> 6;
    int b = blockIdx.y;
    int p = blockIdx.x * 64 + px;
    float* Zb = Z + (long)b * CC * NN;
    float g = 0.f;
    if (p < NN) {
        for (int c = ck * 64; c < ck * 64 + 64; ++c) g += gw[c] * Zb[(long)c * NN + p];
    }
    __shared__ float red[256];
    __shared__ float sg[64];
    red[t] = g;
    __syncthreads();
    if (t < 64) {
        float tot = red[t] + red[t + 64] + red[t + 128] + red[t + 192];
        sg[t] = 1.f / (1.f + __expf(-tot));
    }
    __syncthreads();
    if (p < NN) {
        float s = sg[px];
        for (int c = ck * 64; c < ck * 64 + 64; ++c) Zb[(long)c * NN + p] *= s;
    }
}

// ---------------------------------------------------------------------------
// BatchNorm batch-stats -> scale/shift
// ---------------------------------------------------------------------------
__global__ __launch_bounds__(256)
void bn_stats_kernel(const float* __restrict__ Y, const float* __restrict__ g,
                     const float* __restrict__ beta, float* __restrict__ scale,
                     float* __restrict__ shift)
{
    int c = blockIdx.x, t = threadIdx.x;
    float s = 0.f, sq = 0.f;
    for (int b = 0; b < BB; ++b) {
        const float* p = Y + (long)b * CC * NN + (long)c * NN;
        for (int i = t; i < NN; i += 256) { float v = p[i]; s += v; sq += v * v; }
    }
    __shared__ float ls[256], lq[256];
    ls[t] = s; lq[t] = sq;
    __syncthreads();
    for (int off = 128; off > 0; off >>= 1) {
        if (t < off) { ls[t] += ls[t + off]; lq[t] += lq[t + off]; }
        __syncthreads();
    }
    if (t == 0) {
        const float inv = 1.f / (float)(BB * NN);
        float mean = ls[0] * inv;
        float var = fmaxf(lq[0] * inv - mean * mean, 0.f);
        float sc = g[c] * rsqrtf(var + 1e-5f);
        scale[c] = sc;
        shift[c] = beta[c] - mean * sc;
    }
}

// ---------------------------------------------------------------------------
// Fused BN-normalize + ReLU + 1x1 cls conv + bias.
// block = 64 pixels x 4 channel-chunks
// ---------------------------------------------------------------------------
__global__ __launch_bounds__(256)
void cls_kernel(const float* __restrict__ Y, const float* __restrict__ scale,
                const float* __restrict__ shift, const float* __restrict__ cw,
                const float* __restrict__ cb, float* __restrict__ O)
{
    int t = threadIdx.x;
    int px = t & 63, ck = t >> 6;
    int b = blockIdx.y;
    int p = blockIdx.x * 64 + px;
    const float* Yb = Y + (long)b * CC * NN;
    float a0 = 0.f, a1 = 0.f;
    if (p < NN) {
        for (int c = ck * 64; c < ck * 64 + 64; ++c) {
            float v = Yb[(long)c * NN + p] * scale[c] + shift[c];
            v = fmaxf(v, 0.f);
            a0 += cw[c] * v;
            a1 += cw[CC + c] * v;
        }
    }
    __shared__ float r0[256], r1[256];
    r0[t] = a0; r1[t] = a1;
    __syncthreads();
    if (t < 64) {
        int pp = blockIdx.x * 64 + t;
        if (pp < NN) {
            float s0 = r0[t] + r0[t + 64] + r0[t + 128] + r0[t + 192];
            float s1 = r1[t] + r1[t + 64] + r1[t + 128] + r1[t + 192];
            O[(long)b * NCH * NN + pp] = s0 + cb[0];
            O[(long)b * NCH * NN + NN + pp] = s1 + cb[1];
        }
    }
}

// ---------------------------------------------------------------------------
// Bilinear resize 60x60 -> 473x473 (half-pixel, clamp) + sigmoid
// ---------------------------------------------------------------------------
__global__ __launch_bounds__(256)
void resize_sig_kernel(const float* __restrict__ I1, const float* __restrict__ I2,
                       float* __restrict__ O)
{
    const long HALF = (long)BB * NCH * HO * WO;
    long gid = (long)blockIdx.x * 256 + threadIdx.x;
    if (gid >= HALF) return;
    int half = blockIdx.y;
    const float* I = half ? I2 : I1;
    float* Op = O + half * HALF;

    int j = (int)(gid % WO);
    long r = gid / WO;
    int i = (int)(r % HO);
    int pc = (int)(r / HO);          // b*NCH + nc
    const float* ip = I + (long)pc * NN;

    const float SCL = 60.0f / 473.0f;
    float fy = (i + 0.5f) * SCL - 0.5f;
    float fx = (j + 0.5f) * SCL - 0.5f;
    int y0 = (int)floorf(fy);
    int x0 = (int)floorf(fx);
    float ty = fy - (float)y0;
    float tx = fx - (float)x0;
    int y0c = max(y0, 0), y1c = min(y0 + 1, 59);
    int x0c = max(x0, 0), x1c = min(x0 + 1, 59);
    float va = ip[y0c * 60 + x0c], vb = ip[y0c * 60 + x1c];
    float vc = ip[y1c * 60 + x0c], vd = ip[y1c * 60 + x1c];
    float v = (1.f - ty) * ((1.f - tx) * va + tx * vb) + ty * ((1.f - tx) * vc + tx * vd);
    Op[gid] = 1.f / (1.f + __expf(-v));
}

// ---------------------------------------------------------------------------
// Small weight transposes
// ---------------------------------------------------------------------------
__global__ __launch_bounds__(256)
void transpose_we(const float* __restrict__ W, float* __restrict__ WT)
{
    int idx = blockIdx.x * 256 + threadIdx.x;
    if (idx < CC * CC) {
        int c = idx >> 8, d = idx & 255;
        WT[idx] = W[d * CC + c];
    }
}

template<int CIN>
__global__ __launch_bounds__(256)
void transpose_convw(const float* __restrict__ W, float* __restrict__ WT)
{
    int idx = blockIdx.x * 256 + threadIdx.x;
    if (idx < 9 * CIN * CC) {
        int co = idx & 255;
        int rest = idx >> 8;
        int ci = rest % CIN;
        int tap = rest / CIN;
        WT[idx] = W[((long)co * CIN + ci) * 9 + tap];
    }
}

// ---------------------------------------------------------------------------
extern "C" void kernel_launch(void* const* d_in, const int* in_sizes, int n_in,
                              void* d_out, int out_size, void* d_ws, size_t ws_size,
                              hipStream_t stream)
{
    const float* V_a    = (const float*)d_in[0];
    const float* V_b    = (const float*)d_in[1];
    const float* D_a    = (const float*)d_in[2];
    const float* W_e    = (const float*)d_in[3];
    const float* gate_w = (const float*)d_in[4];
    const float* conv1_w = (const float*)d_in[5];
    const float* conv2_w = (const float*)d_in[6];
    const float* bn1_g = (const float*)d_in[7];
    const float* bn1_b = (const float*)d_in[8];
    const float* bn2_g = (const float*)d_in[9];
    const float* bn2_b = (const float*)d_in[10];
    const float* cls1_w = (const float*)d_in[11];
    const float* cls1_b = (const float*)d_in[12];
    const float* cls2_w = (const float*)d_in[13];
    const float* cls2_b = (const float*)d_in[14];
    float* out = (float*)d_out;
    float* ws  = (float*)d_ws;

    // workspace layout (floats)
    float* wet = ws;                    // 256*256          = 65536
    float* w1t = wet + 65536;           // 9*768*256        = 1769472
    float* w2t = w1t + 1769472;         // 9*512*256        = 1179648
    float* wgt = w2t + 1179648;         // B*N*C            = 1843200
    float* S   = wgt + 1843200;         // B*N*N            = 25920000
    float* rmx = S   + 25920000;        // 7200
    float* rsm = rmx + 7200;
    float* cmx = rsm + 7200;
    float* csm = cmx + 7200;
    float* Za  = csm + 7200;            // 1843200 (att1)
    float* Zb  = Za  + 1843200;         // 1843200 (att2)
    float* y1  = Zb  + 1843200;         // 1843200
    float* y2  = y1  + 1843200;         // 1843200
    float* b1s = y2  + 1843200;         // 256
    float* b1h = b1s + 256;
    float* b2s = b1h + 256;
    float* b2h = b2s + 256;
    float* c1o = b2h + 256;             // B*NC*N = 14400
    float* c2o = c1o + 14400;           // 14400
    float* pcm = c2o + 14400;           // B*RCH*NN = 259200
    float* pcs = pcm + 259200;          // 259200

    dim3 blk(256);

    transpose_we<<<256, blk, 0, stream>>>(W_e, wet);
    transpose_convw<768><<<6912, blk, 0, stream>>>(conv1_w, w1t);
    transpose_convw<512><<<4608, blk, 0, stream>>>(conv2_w, w2t);

    // weighted[b,n,d] = sum_c V_a[b,c,n] * W_e[d,c]   (M=N(3600), N=C, K=C)
    gemm_kernel<1,0,0><<<dim3(4, 57, BB), blk, 0, stream>>>(
        V_a, wet, wgt, NN, CC, CC, NN, CC, CC,
        (long)CC * NN, 0L, (long)NN * CC, nullptr, nullptr, 0);

    // S[b,n,m] = sum_d weighted[b,n,d] * V_b[b,d,m]   (M=3600, N=3600, K=256)
    gemm_kernel<0,0,0><<<dim3(57, 57, BB), blk, 0, stream>>>(
        wgt, V_b, S, NN, NN, CC, CC, NN, NN,
        (long)NN * CC, (long)CC * NN, (long)NN * NN, nullptr, nullptr, 0);

    rowstats_kernel<<<dim3(BB * NN), blk, 0, stream>>>(S, rmx, rsm);
    colstats_part_kernel<<<dim3((NN + 255) / 256, RCH, BB), blk, 0, stream>>>(S, pcm, pcs);
    colstats_comb_kernel<<<dim3((BB * NN + 255) / 256), blk, 0, stream>>>(pcm, pcs, cmx, csm);

    // Z_b[b,c,m] = sum_n V_a[b,c,n] * exp(S[n,m]-cmax[m])/csum[m]
    gemm_kernel<0,0,1><<<dim3(57, 4, BB), blk, 0, stream>>>(
        V_a, S, Zb, CC, NN, NN, NN, NN, NN,
        (long)CC * NN, (long)NN * NN, (long)CC * NN, cmx, csm, NN);

    // Z_a[b,c,m] = sum_n V_b[b,c,n] * exp(S[m,n]-rmax[m])/rsum[m]
    gemm_kernel<0,1,1><<<dim3(57, 4, BB), blk, 0, stream>>>(
        V_b, S, Za, CC, NN, NN, NN, NN, NN,
        (long)CC * NN, (long)NN * NN, (long)CC * NN, rmx, rsm, NN);

    gate_kernel<<<dim3(57, BB), blk, 0, stream>>>(Za, gate_w);
    gate_kernel<<<dim3(57, BB), blk, 0, stream>>>(Zb, gate_w);

    // conv1: input = [att1(Za), V_a, D_a]  (768 ch)
    conv3x3_kernel<768><<<dim3(57, 4, BB), blk, 0, stream>>>(w1t, Za, V_a, D_a, y1);
    // conv2: input = [att2(Zb), V_b]       (512 ch)
    conv3x3_kernel<512><<<dim3(57, 4, BB), blk, 0, stream>>>(w2t, Zb, V_b, V_b, y2);

    bn_stats_kernel<<<256, blk, 0, stream>>>(y1, bn1_g, bn1_b, b1s, b1h);
    bn_stats_kernel<<<256, blk, 0, stream>>>(y2, bn2_g, bn2_b, b2s, b2h);

    cls_kernel<<<dim3(57, BB), blk, 0, stream>>>(y1, b1s, b1h, cls1_w, cls1_b, c1o);
    cls_kernel<<<dim3(57, BB), blk, 0, stream>>>(y2, b2s, b2h, cls2_w, cls2_b, c2o);

    resize_sig_kernel<<<dim3((BB * NCH * HO * WO + 255) / 256, 2), blk, 0, stream>>>(c1o, c2o, out);
}

// Round 4
// 1711.001 us; speedup vs baseline: 2.0435x; 1.3771x over previous
//
#include <hip/hip_runtime.h>

#define BB 2
#define CC 256
#define NN 3600
#define NCH 2
#define HO 473
#define WO 473
#define RCH 36
#define NP 3648          // NN padded to mult of 64 (K padding)
#define NR 3712          // NN padded to mult of 128 (row padding)
#define LDT 72           // LDS tile row stride in u16 (16B-aligned)

typedef unsigned short u16;
typedef __attribute__((ext_vector_type(8))) short short8;
typedef __attribute__((ext_vector_type(4))) float f32x4;

static __device__ __forceinline__ u16 f2bf(float f) {
    unsigned u = __float_as_uint(f);
    unsigned r = (u + 0x7FFF + ((u >> 16) & 1)) >> 16;
    return (u16)r;
}

// ---------------------------------------------------------------------------
// bf16 MFMA GEMM core: C[m][n] = sum_k A[m][k] * B[n][k] (both k-contiguous).
// 256 threads = 4 waves. Tile: (MT*32) x 128, BK=64.
//   MT=4 -> 128x128 (waves 2x2 of 64x64); MT=2 -> 64x128 (waves 2x2 of 32x64).
// EXPB=1: B is fp32 src; staged as exp(v - mxp[row]); epilogue scales col by
//         1/smp[col]. Row guard (>=N) and k guard (>=Kv) produce zeros.
// All stagings row-guarded -> no OOB reads, no uninit reads.
// ---------------------------------------------------------------------------
template<int OUTBF, int EXPB, int MT>
static __device__ __forceinline__ void gemm_core(
    const u16* __restrict__ A, long lda,
    const u16* __restrict__ Bb, long ldb,
    const float* __restrict__ Bf, long ldbf,
    const float* __restrict__ mxp, const float* __restrict__ smp,
    void* __restrict__ Cp, long ldc,
    int M, int N, int K, int Kv, int m0, int n0)
{
    __shared__ u16 As[MT * 32 * LDT];
    __shared__ u16 Bs[128 * LDT];

    const int t = threadIdx.x;
    const int w = t >> 6, lane = t & 63;
    const int mh = (w >> 1) * (MT * 16), nh = (w & 1) * 64;
    const int lm = lane & 15, quad = lane >> 4;

    f32x4 acc[MT][4] = {};

    for (int k0 = 0; k0 < K; k0 += 64) {
#pragma unroll
        for (int i = 0; i < MT; ++i) {
            int idx = i * 256 + t;
            int row = idx >> 3, c8 = (idx & 7) * 8;
            int rg = m0 + row;
            uint4 v = make_uint4(0u, 0u, 0u, 0u);
            if (rg < M) v = *(const uint4*)(A + (long)rg * lda + k0 + c8);
            *(uint4*)(&As[row * LDT + c8]) = v;
        }
#pragma unroll
        for (int i = 0; i < 4; ++i) {
            int idx = i * 256 + t;
            int row = idx >> 3, c8 = (idx & 7) * 8;
            int rg = n0 + row;
            if (EXPB) {
                u16 tmp[8] = {0, 0, 0, 0, 0, 0, 0, 0};
                int kg = k0 + c8;
                if (rg < N && kg < Kv) {
                    float mv = mxp[rg];
                    float4 v0 = *(const float4*)(Bf + (long)rg * ldbf + kg);
                    float4 v1 = *(const float4*)(Bf + (long)rg * ldbf + kg + 4);
                    tmp[0] = f2bf(__expf(v0.x - mv)); tmp[1] = f2bf(__expf(v0.y - mv));
                    tmp[2] = f2bf(__expf(v0.z - mv)); tmp[3] = f2bf(__expf(v0.w - mv));
                    tmp[4] = f2bf(__expf(v1.x - mv)); tmp[5] = f2bf(__expf(v1.y - mv));
                    tmp[6] = f2bf(__expf(v1.z - mv)); tmp[7] = f2bf(__expf(v1.w - mv));
                }
                *(uint4*)(&Bs[row * LDT + c8]) = *(const uint4*)tmp;
            } else {
                uint4 v = make_uint4(0u, 0u, 0u, 0u);
                if (rg < N) v = *(const uint4*)(Bb + (long)rg * ldb + k0 + c8);
                *(uint4*)(&Bs[row * LDT + c8]) = v;
            }
        }
        __syncthreads();
#pragma unroll
        for (int s = 0; s < 2; ++s) {
            short8 a[MT], b[4];
#pragma unroll
            for (int i = 0; i < MT; ++i)
                a[i] = *(const short8*)(&As[(mh + i * 16 + lm) * LDT + s * 32 + quad * 8]);
#pragma unroll
            for (int j = 0; j < 4; ++j)
                b[j] = *(const short8*)(&Bs[(nh + j * 16 + lm) * LDT + s * 32 + quad * 8]);
#pragma unroll
            for (int i = 0; i < MT; ++i)
#pragma unroll
                for (int j = 0; j < 4; ++j)
                    acc[i][j] = __builtin_amdgcn_mfma_f32_16x16x32_bf16(a[i], b[j], acc[i][j], 0, 0, 0);
        }
        __syncthreads();
    }

    float scl[4] = {1.f, 1.f, 1.f, 1.f};
    if (EXPB) {
#pragma unroll
        for (int j = 0; j < 4; ++j) {
            int col = n0 + nh + j * 16 + lm;
            if (col < N) scl[j] = 1.f / smp[col];
        }
    }
#pragma unroll
    for (int i = 0; i < MT; ++i) {
#pragma unroll
        for (int r = 0; r < 4; ++r) {
            int row = m0 + mh + i * 16 + quad * 4 + r;
            if (row < M) {
#pragma unroll
                for (int j = 0; j < 4; ++j) {
                    int col = n0 + nh + j * 16 + lm;
                    if (col < N) {
                        float v = acc[i][j][r] * scl[j];
                        if (OUTBF) ((u16*)Cp)[(long)row * ldc + col] = f2bf(v);
                        else       ((float*)Cp)[(long)row * ldc + col] = v;
                    }
                }
            }
        }
    }
}

// weighted[n][d] = sum_c VaT[n][c] * We[d][c]; both batches (z)
__global__ __launch_bounds__(256)
void gemm_we(const u16* __restrict__ vat, const u16* __restrict__ web,
             u16* __restrict__ wgtb)
{
    int b = blockIdx.z;
    gemm_core<1, 0, 4>(vat + (long)b * NR * CC, CC, web, CC, nullptr, 0,
                       nullptr, nullptr, wgtb + (long)b * NR * CC, CC,
                       NN, CC, CC, CC, blockIdx.y * 128, blockIdx.x * 128);
}

// S[n][m] = sum_d wgt[n][d] * VbT[m][d]; per batch
__global__ __launch_bounds__(256)
void gemm_s(const u16* __restrict__ A, const u16* __restrict__ B, float* __restrict__ S)
{
    gemm_core<0, 0, 4>(A, CC, B, CC, nullptr, 0, nullptr, nullptr, S, NN,
                       NN, NN, CC, CC, blockIdx.y * 128, blockIdx.x * 128);
}

// Per-batch fused Z pair. z=0: Z_b = vab . Pb (normalized, bf16).
// z=1: Z_a = vbb . exp(S rows - rmax)/rsum (fp32 S on the fly).
__global__ __launch_bounds__(256)
void gemm_z(const u16* __restrict__ vab_b, const u16* __restrict__ vbb_b,
            const u16* __restrict__ Pb, const float* __restrict__ S,
            const float* __restrict__ rmx_b, const float* __restrict__ rsm_b,
            float* __restrict__ Zb_b, float* __restrict__ Za_b)
{
    if (blockIdx.z == 0)
        gemm_core<0, 0, 2>(vab_b, NP, Pb, NP, nullptr, 0, nullptr, nullptr,
                           Zb_b, NN, CC, NN, NP, NN, blockIdx.y * 64, blockIdx.x * 128);
    else
        gemm_core<0, 1, 2>(vbb_b, NP, nullptr, 0, S, NN, rmx_b, rsm_b,
                           Za_b, NN, CC, NN, NP, NN, blockIdx.y * 64, blockIdx.x * 128);
}

// conv GEMM: Y[co][p] = sum_k W[co][k] * col[p][k]; per batch
__global__ __launch_bounds__(256)
void gemm_conv(const u16* __restrict__ W, int KT, const u16* __restrict__ col,
               float* __restrict__ Y)
{
    gemm_core<0, 0, 2>(W, KT, col, KT, nullptr, 0, nullptr, nullptr, Y, NN,
                       CC, NN, KT, KT, blockIdx.y * 64, blockIdx.x * 128);
}

// ---------------------------------------------------------------------------
// Converters / transposes
// ---------------------------------------------------------------------------
__global__ __launch_bounds__(256)
void cvt_we(const float* __restrict__ W, u16* __restrict__ O)
{
    int i = blockIdx.x * 256 + threadIdx.x;
    if (i < CC * CC) O[i] = f2bf(W[i]);
}

__global__ __launch_bounds__(256)
void cvt_pad(const float* __restrict__ src, u16* __restrict__ dst, int R)
{
    long idx = (long)blockIdx.x * 256 + threadIdx.x;
    if (idx >= (long)R * NP) return;
    int j = (int)(idx % NP);
    long r = idx / NP;
    dst[idx] = (j < NN) ? f2bf(src[r * NN + j]) : (u16)0;
}

__global__ __launch_bounds__(256)
void cvt_plain(const float* __restrict__ src, u16* __restrict__ dst, long total)
{
    long idx = (long)blockIdx.x * 256 + threadIdx.x;
    if (idx < total) dst[idx] = f2bf(src[idx]);
}

// V [b][256][3600] fp32 -> VT [b][3712][256] bf16 (rows >= NN left unwritten;
// all consumers row-guard).
__global__ __launch_bounds__(256)
void transpose_cvt(const float* __restrict__ V, u16* __restrict__ VT)
{
    __shared__ float tile[64][65];
    int b = blockIdx.z, c0 = blockIdx.y * 64, n0 = blockIdx.x * 64;
    int t = threadIdx.x;
#pragma unroll
    for (int e = 0; e < 16; ++e) {
        int f = e * 256 + t; int i = f >> 6, j = f & 63;
        int n = n0 + j;
        float v = 0.f;
        if (n < NN) v = V[((long)b * CC + c0 + i) * NN + n];
        tile[i][j] = v;
    }
    __syncthreads();
#pragma unroll
    for (int e = 0; e < 16; ++e) {
        int f = e * 256 + t; int i = f >> 6, j = f & 63;
        int n = n0 + i;
        if (n < NN) VT[((long)b * NR + n) * CC + c0 + j] = f2bf(tile[j][i]);
    }
}

template<int CIN>
__global__ __launch_bounds__(256)
void cvt_convw(const float* __restrict__ W, u16* __restrict__ O)
{
    const int KT = 9 * CIN;
    long idx = (long)blockIdx.x * 256 + threadIdx.x;
    if (idx >= (long)CC * KT) return;
    int co = (int)(idx / KT);
    int r = (int)(idx % KT);
    int tap = r / CIN, ci = r % CIN;
    O[idx] = f2bf(W[((long)co * CIN + ci) * 9 + tap]);
}

// ---------------------------------------------------------------------------
// Softmax stats on per-batch fp32 S
// ---------------------------------------------------------------------------
__global__ __launch_bounds__(256)
void rowstats_kernel(const float* __restrict__ S, float* __restrict__ rmax,
                     float* __restrict__ rsum)
{
    int n = blockIdx.x;
    const float* Sp = S + (long)n * NN;
    int t = threadIdx.x;
    float mx = -3.0e38f, s = 0.f;
    for (int i = t; i < NN; i += 256) {
        float v = Sp[i];
        if (v > mx) { s = s * __expf(mx - v) + 1.f; mx = v; }
        else        { s += __expf(v - mx); }
    }
    __shared__ float lm[256], ls[256];
    lm[t] = mx; ls[t] = s;
    __syncthreads();
    for (int off = 128; off > 0; off >>= 1) {
        if (t < off) {
            float m1 = lm[t], m2 = lm[t + off];
            float M = fmaxf(m1, m2);
            ls[t] = ls[t] * __expf(m1 - M) + ls[t + off] * __expf(m2 - M);
            lm[t] = M;
        }
        __syncthreads();
    }
    if (t == 0) { rmax[n] = lm[0]; rsum[n] = ls[0]; }
}

__global__ __launch_bounds__(256)
void colstats_part_kernel(const float* __restrict__ S,
                          float* __restrict__ pmax, float* __restrict__ psum)
{
    const int ROWS = NN / RCH;
    int col = blockIdx.x * 256 + threadIdx.x;
    int rc = blockIdx.y;
    if (col >= NN) return;
    const float* Sp = S + (long)(rc * ROWS) * NN + col;
    float mx = -3.0e38f, s = 0.f;
    for (int r = 0; r < ROWS; ++r) {
        float v = Sp[(long)r * NN];
        if (v > mx) { s = s * __expf(mx - v) + 1.f; mx = v; }
        else        { s += __expf(v - mx); }
    }
    long o = (long)rc * NN + col;
    pmax[o] = mx; psum[o] = s;
}

__global__ __launch_bounds__(256)
void colstats_comb_kernel(const float* __restrict__ pmax, const float* __restrict__ psum,
                          float* __restrict__ cmax, float* __restrict__ csum)
{
    int col = blockIdx.x * 256 + threadIdx.x;
    if (col >= NN) return;
    float mx = -3.0e38f, s = 0.f;
    for (int rc = 0; rc < RCH; ++rc) {
        long o = (long)rc * NN + col;
        float m2 = pmax[o], s2 = psum[o];
        float M = fmaxf(mx, m2);
        s = s * __expf(mx - M) + s2 * __expf(m2 - M);
        mx = M;
    }
    cmax[col] = mx; csum[col] = s;
}

// Pb[m][n] = exp(S[n][m]-cmax[m])/csum[m], bf16, cols padded to NP with 0
__global__ __launch_bounds__(256)
void pb_build(const float* __restrict__ S, const float* __restrict__ cmx,
              const float* __restrict__ csm, u16* __restrict__ Pb)
{
    __shared__ float tile[64][65];
    int m0 = blockIdx.y * 64;
    int n0 = blockIdx.x * 64;
    int t = threadIdx.x;
#pragma unroll
    for (int e = 0; e < 16; ++e) {
        int f = e * 256 + t; int i = f >> 6, j = f & 63;  // i: n-local, j: m-local
        int n = n0 + i, m = m0 + j;
        float v = 0.f;
        if (n < NN && m < NN)
            v = __expf(S[(long)n * NN + m] - cmx[m]) * (1.f / csm[m]);
        tile[j][i] = v;
    }
    __syncthreads();
#pragma unroll
    for (int e = 0; e < 16; ++e) {
        int f = e * 256 + t; int i = f >> 6, j = f & 63;  // i: m-local, j: n-local
        int m = m0 + i;
        if (m < NN) Pb[(long)m * NP + n0 + j] = f2bf(tile[i][j]);
    }
}

// ---------------------------------------------------------------------------
// Gate: G = bf16( Z * sigmoid(sum_c gw[c]*Z[c,p]) ), full batch
// ---------------------------------------------------------------------------
__global__ __launch_bounds__(256)
void gate_kernel(const float* __restrict__ Z, const float* __restrict__ gw,
                 u16* __restrict__ G)
{
    int t = threadIdx.x;
    int px = t & 63, ck = t >> 6;
    int b = blockIdx.y;
    int p = blockIdx.x * 64 + px;
    const float* Zp = Z + (long)b * CC * NN;
    u16* Gp = G + (long)b * CC * NN;
    float g = 0.f;
    if (p < NN) {
        for (int c = ck * 64; c < ck * 64 + 64; ++c) g += gw[c] * Zp[(long)c * NN + p];
    }
    __shared__ float red[256];
    __shared__ float sg[64];
    red[t] = g;
    __syncthreads();
    if (t < 64) {
        float tot = red[t] + red[t + 64] + red[t + 128] + red[t + 192];
        sg[t] = 1.f / (1.f + __expf(-tot));
    }
    __syncthreads();
    if (p < NN) {
        float s = sg[px];
        for (int c = ck * 64; c < ck * 64 + 64; ++c)
            Gp[(long)c * NN + p] = f2bf(Zp[(long)c * NN + p] * s);
    }
}

// ---------------------------------------------------------------------------
// im2col per batch: col[p][tap*CIN+ci] = plane[ci][p+off] (border zero), bf16
// ---------------------------------------------------------------------------
template<int CIN>
__global__ __launch_bounds__(256)
void im2col_kernel(const u16* __restrict__ P0, long ld0,
                   const u16* __restrict__ P1, long ld1,
                   const u16* __restrict__ P2, long ld2,
                   u16* __restrict__ col)
{
    __shared__ u16 tile[64][66];
    const int KT = 9 * CIN;
    int tap = blockIdx.y / (CIN / 64);
    int cg = blockIdx.y % (CIN / 64);
    int ci0 = cg * 64;
    int p0 = blockIdx.x * 64;
    int dh = tap / 3 - 1, dw = tap % 3 - 1, off = dh * 60 + dw;
    int plane = ci0 >> 8;
    const u16* src; long lds_;
    if (plane == 0) { src = P0; lds_ = ld0; }
    else if (plane == 1) { src = P1; lds_ = ld1; }
    else { src = P2; lds_ = ld2; }
    src += (long)(ci0 & 255) * lds_;
    int t = threadIdx.x;
#pragma unroll
    for (int e = 0; e < 16; ++e) {
        int f = e * 256 + t; int i = f >> 6, j = f & 63;  // i: ci-local, j: p-local
        int p = p0 + j;
        u16 v = 0;
        if (p < NN) {
            int h = p / 60, wI = p - h * 60;
            int hh = h + dh, wwI = wI + dw;
            if (hh >= 0 && hh < 60 && wwI >= 0 && wwI < 60) v = src[(long)i * lds_ + p + off];
        }
        tile[i][j] = v;
    }
    __syncthreads();
#pragma unroll
    for (int e = 0; e < 16; ++e) {
        int f = e * 256 + t; int j = f >> 6, i = f & 63;  // j: p-local, i: ci-local
        int p = p0 + j;
        if (p < NN) col[(long)p * KT + tap * CIN + ci0 + i] = tile[i][j];
    }
}

// ---------------------------------------------------------------------------
// BatchNorm batch-stats -> scale/shift
// ---------------------------------------------------------------------------
__global__ __launch_bounds__(256)
void bn_stats_kernel(const float* __restrict__ Y, const float* __restrict__ g,
                     const float* __restrict__ beta, float* __restrict__ scale,
                     float* __restrict__ shift)
{
    int c = blockIdx.x, t = threadIdx.x;
    float s = 0.f, sq = 0.f;
    for (int b = 0; b < BB; ++b) {
        const float* p = Y + (long)b * CC * NN + (long)c * NN;
        for (int i = t; i < NN; i += 256) { float v = p[i]; s += v; sq += v * v; }
    }
    __shared__ float ls[256], lq[256];
    ls[t] = s; lq[t] = sq;
    __syncthreads();
    for (int off = 128; off > 0; off >>= 1) {
        if (t < off) { ls[t] += ls[t + off]; lq[t] += lq[t + off]; }
        __syncthreads();
    }
    if (t == 0) {
        const float inv = 1.f / (float)(BB * NN);
        float mean = ls[0] * inv;
        float var = fmaxf(lq[0] * inv - mean * mean, 0.f);
        float sc = g[c] * rsqrtf(var + 1e-5f);
        scale[c] = sc;
        shift[c] = beta[c] - mean * sc;
    }
}

// ---------------------------------------------------------------------------
// Fused BN-normalize + ReLU + 1x1 cls conv + bias
// ---------------------------------------------------------------------------
__global__ __launch_bounds__(256)
void cls_kernel(const float* __restrict__ Y, const float* __restrict__ scale,
                const float* __restrict__ shift, const float* __restrict__ cw,
                const float* __restrict__ cb, float* __restrict__ O)
{
    int t = threadIdx.x;
    int px = t & 63, ck = t >> 6;
    int b = blockIdx.y;
    int p = blockIdx.x * 64 + px;
    const float* Yb = Y + (long)b * CC * NN;
    float a0 = 0.f, a1 = 0.f;
    if (p < NN) {
        for (int c = ck * 64; c < ck * 64 + 64; ++c) {
            float v = Yb[(long)c * NN + p] * scale[c] + shift[c];
            v = fmaxf(v, 0.f);
            a0 += cw[c] * v;
            a1 += cw[CC + c] * v;
        }
    }
    __shared__ float r0[256], r1[256];
    r0[t] = a0; r1[t] = a1;
    __syncthreads();
    if (t < 64) {
        int pp = blockIdx.x * 64 + t;
        if (pp < NN) {
            float s0 = r0[t] + r0[t + 64] + r0[t + 128] + r0[t + 192];
            float s1 = r1[t] + r1[t + 64] + r1[t + 128] + r1[t + 192];
            O[(long)b * NCH * NN + pp] = s0 + cb[0];
            O[(long)b * NCH * NN + NN + pp] = s1 + cb[1];
        }
    }
}

// ---------------------------------------------------------------------------
// Bilinear resize 60x60 -> 473x473 (half-pixel, clamp) + sigmoid
// ---------------------------------------------------------------------------
__global__ __launch_bounds__(256)
void resize_sig_kernel(const float* __restrict__ I1, const float* __restrict__ I2,
                       float* __restrict__ O)
{
    const long HALF = (long)BB * NCH * HO * WO;
    long gid = (long)blockIdx.x * 256 + threadIdx.x;
    if (gid >= HALF) return;
    int half = blockIdx.y;
    const float* I = half ? I2 : I1;
    float* Op = O + half * HALF;

    int j = (int)(gid % WO);
    long r = gid / WO;
    int i = (int)(r % HO);
    int pc = (int)(r / HO);
    const float* ip = I + (long)pc * NN;

    const float SCL = 60.0f / 473.0f;
    float fy = (i + 0.5f) * SCL - 0.5f;
    float fx = (j + 0.5f) * SCL - 0.5f;
    int y0 = (int)floorf(fy);
    int x0 = (int)floorf(fx);
    float ty = fy - (float)y0;
    float tx = fx - (float)x0;
    int y0c = max(y0, 0), y1c = min(y0 + 1, 59);
    int x0c = max(x0, 0), x1c = min(x0 + 1, 59);
    float va = ip[y0c * 60 + x0c], vb = ip[y0c * 60 + x1c];
    float vc = ip[y1c * 60 + x0c], vd = ip[y1c * 60 + x1c];
    float v = (1.f - ty) * ((1.f - tx) * va + tx * vb) + ty * ((1.f - tx) * vc + tx * vd);
    Op[gid] = 1.f / (1.f + __expf(-v));
}

// ---------------------------------------------------------------------------
extern "C" void kernel_launch(void* const* d_in, const int* in_sizes, int n_in,
                              void* d_out, int out_size, void* d_ws, size_t ws_size,
                              hipStream_t stream)
{
    const float* V_a    = (const float*)d_in[0];
    const float* V_b    = (const float*)d_in[1];
    const float* D_a    = (const float*)d_in[2];
    const float* W_e    = (const float*)d_in[3];
    const float* gate_w = (const float*)d_in[4];
    const float* conv1_w = (const float*)d_in[5];
    const float* conv2_w = (const float*)d_in[6];
    const float* bn1_g = (const float*)d_in[7];
    const float* bn1_b = (const float*)d_in[8];
    const float* bn2_g = (const float*)d_in[9];
    const float* bn2_b = (const float*)d_in[10];
    const float* cls1_w = (const float*)d_in[11];
    const float* cls1_b = (const float*)d_in[12];
    const float* cls2_w = (const float*)d_in[13];
    const float* cls2_b = (const float*)d_in[14];
    float* out = (float*)d_out;

    // ---- workspace arena: total 130.9 MB (known-safe bound: 154.9 MB) ----
    size_t off = 0;
    char* wsb = (char*)d_ws;
    auto carve = [&](size_t bytes) -> char* {
        char* p = wsb + off; off += (bytes + 255) & ~(size_t)255; return p;
    };

    float* S   = (float*)carve((size_t)NN * NN * 4);          // 51.84 MB, per-batch; col aliases
    u16* col   = (u16*)S;                                     // NR*6912*2 = 51.3 MB fits
    u16* Pb    = (u16*)carve((size_t)NR * NP * 2);            // 27.08 MB, per-batch
    u16* vab   = (u16*)carve((size_t)BB * CC * NP * 2);
    u16* vbb   = (u16*)carve((size_t)BB * CC * NP * 2);
    u16* dab   = (u16*)carve((size_t)BB * CC * NN * 2);
    u16* gza   = (u16*)carve((size_t)BB * CC * NN * 2);
    u16* gzb   = (u16*)carve((size_t)BB * CC * NN * 2);
    u16* vat   = (u16*)carve((size_t)BB * NR * CC * 2);
    u16* vbt   = (u16*)carve((size_t)BB * NR * CC * 2);
    u16* wgtb  = (u16*)carve((size_t)BB * NR * CC * 2);
    u16* web   = (u16*)carve((size_t)CC * CC * 2);
    u16* wt1   = (u16*)carve((size_t)CC * 9 * 768 * 2);
    u16* wt2   = (u16*)carve((size_t)CC * 9 * 512 * 2);
    float* Za  = (float*)carve((size_t)BB * CC * NN * 4);     // y1 aliases after gates
    float* Zb  = (float*)carve((size_t)BB * CC * NN * 4);     // y2 aliases after gates
    float* y1  = Za;
    float* y2  = Zb;
    float* rmx = (float*)carve((size_t)BB * NN * 4);
    float* rsm = (float*)carve((size_t)BB * NN * 4);
    float* cmx = (float*)carve((size_t)BB * NN * 4);
    float* csm = (float*)carve((size_t)BB * NN * 4);
    float* pcm = (float*)carve((size_t)RCH * NN * 4);         // per-batch
    float* pcs = (float*)carve((size_t)RCH * NN * 4);
    float* c1o = (float*)carve((size_t)BB * NCH * NN * 4);
    float* c2o = (float*)carve((size_t)BB * NCH * NN * 4);

    dim3 blk(256);

    // --- input conversions ---
    cvt_we<<<256, blk, 0, stream>>>(W_e, web);
    cvt_pad<<<(int)(((long)BB * CC * NP + 255) / 256), blk, 0, stream>>>(V_a, vab, BB * CC);
    cvt_pad<<<(int)(((long)BB * CC * NP + 255) / 256), blk, 0, stream>>>(V_b, vbb, BB * CC);
    cvt_plain<<<(int)(((long)BB * CC * NN + 255) / 256), blk, 0, stream>>>(D_a, dab, (long)BB * CC * NN);
    transpose_cvt<<<dim3(57, 4, BB), blk, 0, stream>>>(V_a, vat);
    transpose_cvt<<<dim3(57, 4, BB), blk, 0, stream>>>(V_b, vbt);
    cvt_convw<768><<<(int)(((long)CC * 9 * 768 + 255) / 256), blk, 0, stream>>>(conv1_w, wt1);
    cvt_convw<512><<<(int)(((long)CC * 9 * 512 + 255) / 256), blk, 0, stream>>>(conv2_w, wt2);

    // --- weighted (both batches) ---
    gemm_we<<<dim3(2, 29, BB), blk, 0, stream>>>(vat, web, wgtb);

    // --- attention, per batch (S + Pb buffers reused) ---
    for (int b = 0; b < BB; ++b) {
        const u16* wgtb_b = wgtb + (long)b * NR * CC;
        const u16* vbt_b  = vbt + (long)b * NR * CC;
        const u16* vab_b  = vab + (long)b * CC * NP;
        const u16* vbb_b  = vbb + (long)b * CC * NP;
        float* rmx_b = rmx + b * NN; float* rsm_b = rsm + b * NN;
        float* cmx_b = cmx + b * NN; float* csm_b = csm + b * NN;

        gemm_s<<<dim3(29, 29), blk, 0, stream>>>(wgtb_b, vbt_b, S);
        rowstats_kernel<<<dim3(NN), blk, 0, stream>>>(S, rmx_b, rsm_b);
        colstats_part_kernel<<<dim3((NN + 255) / 256, RCH), blk, 0, stream>>>(S, pcm, pcs);
        colstats_comb_kernel<<<dim3((NN + 255) / 256), blk, 0, stream>>>(pcm, pcs, cmx_b, csm_b);
        pb_build<<<dim3(57, 57), blk, 0, stream>>>(S, cmx_b, csm_b, Pb);
        gemm_z<<<dim3(29, 4, 2), blk, 0, stream>>>(
            vab_b, vbb_b, Pb, S, rmx_b, rsm_b,
            Zb + (long)b * CC * NN, Za + (long)b * CC * NN);
    }

    // --- gates -> bf16 planes ---
    gate_kernel<<<dim3(57, BB), blk, 0, stream>>>(Za, gate_w, gza);
    gate_kernel<<<dim3(57, BB), blk, 0, stream>>>(Zb, gate_w, gzb);

    // --- convs, per batch (col aliases S; Za/Zb regions become y1/y2) ---
    for (int b = 0; b < BB; ++b) {
        const u16* gza_b = gza + (long)b * CC * NN;
        const u16* gzb_b = gzb + (long)b * CC * NN;
        const u16* vab_b = vab + (long)b * CC * NP;
        const u16* vbb_b = vbb + (long)b * CC * NP;
        const u16* dab_b = dab + (long)b * CC * NN;

        im2col_kernel<768><<<dim3(57, 9 * (768 / 64)), blk, 0, stream>>>(
            gza_b, (long)NN, vab_b, (long)NP, dab_b, (long)NN, col);
        gemm_conv<<<dim3(29, 4), blk, 0, stream>>>(wt1, 9 * 768, col, y1 + (long)b * CC * NN);

        im2col_kernel<512><<<dim3(57, 9 * (512 / 64)), blk, 0, stream>>>(
            gzb_b, (long)NN, vbb_b, (long)NP, vbb_b, (long)NP, col);
        gemm_conv<<<dim3(29, 4), blk, 0, stream>>>(wt2, 9 * 512, col, y2 + (long)b * CC * NN);
    }

    // --- BN + cls + resize ---  (rmx/rsm/cmx/csm reused as scale/shift)
    bn_stats_kernel<<<256, blk, 0, stream>>>(y1, bn1_g, bn1_b, rmx, rsm);
    bn_stats_kernel<<<256, blk, 0, stream>>>(y2, bn2_g, bn2_b, cmx, csm);
    cls_kernel<<<dim3(57, BB), blk, 0, stream>>>(y1, rmx, rsm, cls1_w, cls1_b, c1o);
    cls_kernel<<<dim3(57, BB), blk, 0, stream>>>(y2, cmx, csm, cls2_w, cls2_b, c2o);

    resize_sig_kernel<<<dim3((int)(((long)BB * NCH * HO * WO + 255) / 256), 2), blk, 0, stream>>>(c1o, c2o, out);
}

// Round 5
// 975.368 us; speedup vs baseline: 3.5847x; 1.7542x over previous
//
#include <hip/hip_runtime.h>

#define BB 2
#define CC 256
#define NN 3600
#define NCH 2
#define HO 473
#define WO 473
#define RCH 36
#define NP 3648          // NN padded to mult of 64 (K padding)
#define NR 3712          // NN padded to mult of 128 (row padding)
#define LDT 72           // LDS tile row stride in u16 (16B-aligned)

typedef unsigned short u16;
typedef __attribute__((ext_vector_type(8))) short short8;
typedef __attribute__((ext_vector_type(4))) float f32x4;

static __device__ __forceinline__ u16 f2bf(float f) {
    unsigned u = __float_as_uint(f);
    unsigned r = (u + 0x7FFF + ((u >> 16) & 1)) >> 16;
    return (u16)r;
}

// ---------------------------------------------------------------------------
// bf16 MFMA GEMM core: C[m][n] = sum_k A[m][k] * B[n][k] (both k-contiguous).
// 256 threads = 4 waves. Tile: (MT*32) x 128, BK=64.
// EXPB=1: B is fp32 src; staged as exp(v - mxp[row]); epilogue scales col by
//         1/smp[col]. All stagings row-guarded.
// ---------------------------------------------------------------------------
template<int OUTBF, int EXPB, int MT>
static __device__ __forceinline__ void gemm_core(
    const u16* __restrict__ A, long lda,
    const u16* __restrict__ Bb, long ldb,
    const float* __restrict__ Bf, long ldbf,
    const float* __restrict__ mxp, const float* __restrict__ smp,
    void* __restrict__ Cp, long ldc,
    int M, int N, int K, int Kv, int m0, int n0)
{
    __shared__ u16 As[MT * 32 * LDT];
    __shared__ u16 Bs[128 * LDT];

    const int t = threadIdx.x;
    const int w = t >> 6, lane = t & 63;
    const int mh = (w >> 1) * (MT * 16), nh = (w & 1) * 64;
    const int lm = lane & 15, quad = lane >> 4;

    f32x4 acc[MT][4] = {};

    for (int k0 = 0; k0 < K; k0 += 64) {
#pragma unroll
        for (int i = 0; i < MT; ++i) {
            int idx = i * 256 + t;
            int row = idx >> 3, c8 = (idx & 7) * 8;
            int rg = m0 + row;
            uint4 v = make_uint4(0u, 0u, 0u, 0u);
            if (rg < M) v = *(const uint4*)(A + (long)rg * lda + k0 + c8);
            *(uint4*)(&As[row * LDT + c8]) = v;
        }
#pragma unroll
        for (int i = 0; i < 4; ++i) {
            int idx = i * 256 + t;
            int row = idx >> 3, c8 = (idx & 7) * 8;
            int rg = n0 + row;
            if (EXPB) {
                u16 tmp[8] = {0, 0, 0, 0, 0, 0, 0, 0};
                int kg = k0 + c8;
                if (rg < N && kg < Kv) {
                    float mv = mxp[rg];
                    float4 v0 = *(const float4*)(Bf + (long)rg * ldbf + kg);
                    float4 v1 = *(const float4*)(Bf + (long)rg * ldbf + kg + 4);
                    tmp[0] = f2bf(__expf(v0.x - mv)); tmp[1] = f2bf(__expf(v0.y - mv));
                    tmp[2] = f2bf(__expf(v0.z - mv)); tmp[3] = f2bf(__expf(v0.w - mv));
                    tmp[4] = f2bf(__expf(v1.x - mv)); tmp[5] = f2bf(__expf(v1.y - mv));
                    tmp[6] = f2bf(__expf(v1.z - mv)); tmp[7] = f2bf(__expf(v1.w - mv));
                }
                *(uint4*)(&Bs[row * LDT + c8]) = *(const uint4*)tmp;
            } else {
                uint4 v = make_uint4(0u, 0u, 0u, 0u);
                if (rg < N) v = *(const uint4*)(Bb + (long)rg * ldb + k0 + c8);
                *(uint4*)(&Bs[row * LDT + c8]) = v;
            }
        }
        __syncthreads();
#pragma unroll
        for (int s = 0; s < 2; ++s) {
            short8 a[MT], b[4];
#pragma unroll
            for (int i = 0; i < MT; ++i)
                a[i] = *(const short8*)(&As[(mh + i * 16 + lm) * LDT + s * 32 + quad * 8]);
#pragma unroll
            for (int j = 0; j < 4; ++j)
                b[j] = *(const short8*)(&Bs[(nh + j * 16 + lm) * LDT + s * 32 + quad * 8]);
#pragma unroll
            for (int i = 0; i < MT; ++i)
#pragma unroll
                for (int j = 0; j < 4; ++j)
                    acc[i][j] = __builtin_amdgcn_mfma_f32_16x16x32_bf16(a[i], b[j], acc[i][j], 0, 0, 0);
        }
        __syncthreads();
    }

    float scl[4] = {1.f, 1.f, 1.f, 1.f};
    if (EXPB) {
#pragma unroll
        for (int j = 0; j < 4; ++j) {
            int col = n0 + nh + j * 16 + lm;
            if (col < N) scl[j] = 1.f / smp[col];
        }
    }
#pragma unroll
    for (int i = 0; i < MT; ++i) {
#pragma unroll
        for (int r = 0; r < 4; ++r) {
            int row = m0 + mh + i * 16 + quad * 4 + r;
            if (row < M) {
#pragma unroll
                for (int j = 0; j < 4; ++j) {
                    int col = n0 + nh + j * 16 + lm;
                    if (col < N) {
                        float v = acc[i][j][r] * scl[j];
                        if (OUTBF) ((u16*)Cp)[(long)row * ldc + col] = f2bf(v);
                        else       ((float*)Cp)[(long)row * ldc + col] = v;
                    }
                }
            }
        }
    }
}

// weighted[n][d] = sum_c VaT[n][c] * We[d][c]; both batches
__global__ __launch_bounds__(256)
void gemm_we(const u16* __restrict__ vat, const u16* __restrict__ web,
             u16* __restrict__ wgtb)
{
    int b = blockIdx.z;
    gemm_core<1, 0, 4>(vat + (long)b * NR * CC, CC, web, CC, nullptr, 0,
                       nullptr, nullptr, wgtb + (long)b * NR * CC, CC,
                       NN, CC, CC, CC, blockIdx.y * 128, blockIdx.x * 128);
}

// S[n][m] = sum_d wgt[n][d] * VbT[m][d]; per batch
__global__ __launch_bounds__(256)
void gemm_s(const u16* __restrict__ A, const u16* __restrict__ B, float* __restrict__ S)
{
    gemm_core<0, 0, 4>(A, CC, B, CC, nullptr, 0, nullptr, nullptr, S, NN,
                       NN, NN, CC, CC, blockIdx.y * 128, blockIdx.x * 128);
}

// Per-batch fused Z pair. z=0: Z_b = vab . Pb; z=1: Z_a = vbb . softmax-rows(S)
__global__ __launch_bounds__(256)
void gemm_z(const u16* __restrict__ vab_b, const u16* __restrict__ vbb_b,
            const u16* __restrict__ Pb, const float* __restrict__ S,
            const float* __restrict__ rmx_b, const float* __restrict__ rsm_b,
            float* __restrict__ Zb_b, float* __restrict__ Za_b)
{
    if (blockIdx.z == 0)
        gemm_core<0, 0, 2>(vab_b, NP, Pb, NP, nullptr, 0, nullptr, nullptr,
                           Zb_b, NN, CC, NN, NP, NN, blockIdx.y * 64, blockIdx.x * 128);
    else
        gemm_core<0, 1, 2>(vbb_b, NP, nullptr, 0, S, NN, rmx_b, rsm_b,
                           Za_b, NN, CC, NN, NP, NN, blockIdx.y * 64, blockIdx.x * 128);
}

// ---------------------------------------------------------------------------
// Direct 3x3 conv as split-K MFMA GEMM over virtual im2col.
// W: [256][9*CIN] bf16 (k = tap*CIN + ci). Planes: [p][256] bf16, row stride
// CC, batch stride NR*CC (256-ch groups; CIN/256 planes).
// grid: (29 p-tiles, 4 co-tiles, 6 = b*3 + ksplit); ksplit covers 3 taps.
// Writes fp32 partial slice z of part[6][CC][NN].
// ---------------------------------------------------------------------------
template<int CIN>
__global__ __launch_bounds__(256)
void conv_direct(const u16* __restrict__ W,
                 const u16* __restrict__ P0, const u16* __restrict__ P1,
                 const u16* __restrict__ P2, float* __restrict__ part)
{
    const int KT = 9 * CIN;
    __shared__ u16 As[64 * LDT];
    __shared__ u16 Bs[128 * LDT];

    const int t = threadIdx.x;
    const int w = t >> 6, lane = t & 63;
    const int mh = (w >> 1) * 32, nh = (w & 1) * 64;
    const int lm = lane & 15, quad = lane >> 4;
    const int z = blockIdx.z, b = z / 3, ks = z - 3 * (z / 3);
    const int m0 = blockIdx.y * 64, n0 = blockIdx.x * 128;
    const long pstride = (long)NR * CC;

    f32x4 acc[2][4] = {};

    const int kbeg = ks * 3 * CIN, kend = kbeg + 3 * CIN;
    for (int k0 = kbeg; k0 < kend; k0 += 64) {
        int tap = k0 / CIN;
        int kloc = k0 - tap * CIN;
        int plane = kloc >> 8, cip = kloc & 255;
        int dh = tap / 3 - 1, dw = tap - (tap / 3) * 3 - 1;
        int off = dh * 60 + dw;
        const u16* src = (plane == 0) ? P0 : ((plane == 1) ? P1 : P2);
        src += (long)b * pstride + cip;

#pragma unroll
        for (int i = 0; i < 2; ++i) {              // A: weights (co rows exact)
            int idx = i * 256 + t;
            int row = idx >> 3, c8 = (idx & 7) * 8;
            uint4 v = *(const uint4*)(W + (long)(m0 + row) * KT + k0 + c8);
            *(uint4*)(&As[row * LDT + c8]) = v;
        }
#pragma unroll
        for (int i = 0; i < 4; ++i) {              // B: shifted plane rows
            int idx = i * 256 + t;
            int row = idx >> 3, c8 = (idx & 7) * 8;
            int p = n0 + row;
            uint4 v = make_uint4(0u, 0u, 0u, 0u);
            if (p < NN) {
                int h = p / 60, wp = p - h * 60;
                int hh = h + dh, wq = wp + dw;
                if (hh >= 0 && hh < 60 && wq >= 0 && wq < 60)
                    v = *(const uint4*)(src + (long)(p + off) * CC + c8);
            }
            *(uint4*)(&Bs[row * LDT + c8]) = v;
        }
        __syncthreads();
#pragma unroll
        for (int s = 0; s < 2; ++s) {
            short8 a[2], bfr[4];
#pragma unroll
            for (int i = 0; i < 2; ++i)
                a[i] = *(const short8*)(&As[(mh + i * 16 + lm) * LDT + s * 32 + quad * 8]);
#pragma unroll
            for (int j = 0; j < 4; ++j)
                bfr[j] = *(const short8*)(&Bs[(nh + j * 16 + lm) * LDT + s * 32 + quad * 8]);
#pragma unroll
            for (int i = 0; i < 2; ++i)
#pragma unroll
                for (int j = 0; j < 4; ++j)
                    acc[i][j] = __builtin_amdgcn_mfma_f32_16x16x32_bf16(a[i], bfr[j], acc[i][j], 0, 0, 0);
        }
        __syncthreads();
    }

    float* out = part + (long)z * CC * NN;
#pragma unroll
    for (int i = 0; i < 2; ++i) {
#pragma unroll
        for (int r = 0; r < 4; ++r) {
            int row = m0 + mh + i * 16 + quad * 4 + r;
#pragma unroll
            for (int j = 0; j < 4; ++j) {
                int col = n0 + nh + j * 16 + lm;
                if (col < NN) out[(long)row * NN + col] = acc[i][j][r];
            }
        }
    }
}

// Y[b][co][p] = sum of 3 partial slices
__global__ __launch_bounds__(256)
void conv_reduce(const float* __restrict__ part, float* __restrict__ Y)
{
    long idx = (long)blockIdx.x * 256 + threadIdx.x;
    if (idx >= (long)BB * CC * NN) return;
    long b = idx / ((long)CC * NN), r = idx - b * (long)CC * NN;
    const float* p0 = part + (b * 3 + 0) * (long)CC * NN;
    const float* p1 = part + (b * 3 + 1) * (long)CC * NN;
    const float* p2 = part + (b * 3 + 2) * (long)CC * NN;
    Y[idx] = p0[r] + p1[r] + p2[r];
}

// ---------------------------------------------------------------------------
// Converters / transposes
// ---------------------------------------------------------------------------
__global__ __launch_bounds__(256)
void cvt_we(const float* __restrict__ W, u16* __restrict__ O)
{
    int i = blockIdx.x * 256 + threadIdx.x;
    if (i < CC * CC) O[i] = f2bf(W[i]);
}

__global__ __launch_bounds__(256)
void cvt_pad(const float* __restrict__ src, u16* __restrict__ dst, int R)
{
    long idx = (long)blockIdx.x * 256 + threadIdx.x;
    if (idx >= (long)R * NP) return;
    int j = (int)(idx % NP);
    long r = idx / NP;
    dst[idx] = (j < NN) ? f2bf(src[r * NN + j]) : (u16)0;
}

// V [b][256][3600] fp32 -> VT [b][3712][256] bf16 (rows >= NN unwritten; all
// consumers row-guard).
__global__ __launch_bounds__(256)
void transpose_cvt(const float* __restrict__ V, u16* __restrict__ VT)
{
    __shared__ float tile[64][65];
    int b = blockIdx.z, c0 = blockIdx.y * 64, n0 = blockIdx.x * 64;
    int t = threadIdx.x;
#pragma unroll
    for (int e = 0; e < 16; ++e) {
        int f = e * 256 + t; int i = f >> 6, j = f & 63;
        int n = n0 + j;
        float v = 0.f;
        if (n < NN) v = V[((long)b * CC + c0 + i) * NN + n];
        tile[i][j] = v;
    }
    __syncthreads();
#pragma unroll
    for (int e = 0; e < 16; ++e) {
        int f = e * 256 + t; int i = f >> 6, j = f & 63;
        int n = n0 + i;
        if (n < NN) VT[((long)b * NR + n) * CC + c0 + j] = f2bf(tile[j][i]);
    }
}

// Za fp32 [b][c][p] * sg[b][p] -> ZT bf16 [b][p][c]
__global__ __launch_bounds__(256)
void transpose_gate(const float* __restrict__ Z, const float* __restrict__ sg,
                    u16* __restrict__ ZT)
{
    __shared__ float tile[64][65];
    int b = blockIdx.z, c0 = blockIdx.y * 64, n0 = blockIdx.x * 64;
    int t = threadIdx.x;
#pragma unroll
    for (int e = 0; e < 16; ++e) {
        int f = e * 256 + t; int i = f >> 6, j = f & 63;
        int n = n0 + j;
        float v = 0.f;
        if (n < NN) v = Z[((long)b * CC + c0 + i) * NN + n];
        tile[i][j] = v;
    }
    __syncthreads();
#pragma unroll
    for (int e = 0; e < 16; ++e) {
        int f = e * 256 + t; int i = f >> 6, j = f & 63;
        int n = n0 + i;
        if (n < NN)
            ZT[((long)b * NR + n) * CC + c0 + j] = f2bf(tile[j][i] * sg[b * NN + n]);
    }
}

template<int CIN>
__global__ __launch_bounds__(256)
void cvt_convw(const float* __restrict__ W, u16* __restrict__ O)
{
    const int KT = 9 * CIN;
    long idx = (long)blockIdx.x * 256 + threadIdx.x;
    if (idx >= (long)CC * KT) return;
    int co = (int)(idx / KT);
    int r = (int)(idx % KT);
    int tap = r / CIN, ci = r % CIN;
    O[idx] = f2bf(W[((long)co * CIN + ci) * 9 + tap]);
}

// ---------------------------------------------------------------------------
// Softmax stats on per-batch fp32 S
// ---------------------------------------------------------------------------
__global__ __launch_bounds__(256)
void rowstats_kernel(const float* __restrict__ S, float* __restrict__ rmax,
                     float* __restrict__ rsum)
{
    int n = blockIdx.x;
    const float* Sp = S + (long)n * NN;
    int t = threadIdx.x;
    float mx = -3.0e38f, s = 0.f;
    for (int i = t; i < NN; i += 256) {
        float v = Sp[i];
        if (v > mx) { s = s * __expf(mx - v) + 1.f; mx = v; }
        else        { s += __expf(v - mx); }
    }
    __shared__ float lm[256], ls[256];
    lm[t] = mx; ls[t] = s;
    __syncthreads();
    for (int off = 128; off > 0; off >>= 1) {
        if (t < off) {
            float m1 = lm[t], m2 = lm[t + off];
            float M = fmaxf(m1, m2);
            ls[t] = ls[t] * __expf(m1 - M) + ls[t + off] * __expf(m2 - M);
            lm[t] = M;
        }
        __syncthreads();
    }
    if (t == 0) { rmax[n] = lm[0]; rsum[n] = ls[0]; }
}

__global__ __launch_bounds__(256)
void colstats_part_kernel(const float* __restrict__ S,
                          float* __restrict__ pmax, float* __restrict__ psum)
{
    const int ROWS = NN / RCH;
    int col = blockIdx.x * 256 + threadIdx.x;
    int rc = blockIdx.y;
    if (col >= NN) return;
    const float* Sp = S + (long)(rc * ROWS) * NN + col;
    float mx = -3.0e38f, s = 0.f;
    for (int r = 0; r < ROWS; ++r) {
        float v = Sp[(long)r * NN];
        if (v > mx) { s = s * __expf(mx - v) + 1.f; mx = v; }
        else        { s += __expf(v - mx); }
    }
    long o = (long)rc * NN + col;
    pmax[o] = mx; psum[o] = s;
}

__global__ __launch_bounds__(256)
void colstats_comb_kernel(const float* __restrict__ pmax, const float* __restrict__ psum,
                          float* __restrict__ cmax, float* __restrict__ csum)
{
    int col = blockIdx.x * 256 + threadIdx.x;
    if (col >= NN) return;
    float mx = -3.0e38f, s = 0.f;
    for (int rc = 0; rc < RCH; ++rc) {
        long o = (long)rc * NN + col;
        float m2 = pmax[o], s2 = psum[o];
        float M = fmaxf(mx, m2);
        s = s * __expf(mx - M) + s2 * __expf(m2 - M);
        mx = M;
    }
    cmax[col] = mx; csum[col] = s;
}

// Pb[m][n] = exp(S[n][m]-cmax[m])/csum[m], bf16, cols padded to NP with 0
__global__ __launch_bounds__(256)
void pb_build(const float* __restrict__ S, const float* __restrict__ cmx,
              const float* __restrict__ csm, u16* __restrict__ Pb)
{
    __shared__ float tile[64][65];
    int m0 = blockIdx.y * 64;
    int n0 = blockIdx.x * 64;
    int t = threadIdx.x;
#pragma unroll
    for (int e = 0; e < 16; ++e) {
        int f = e * 256 + t; int i = f >> 6, j = f & 63;
        int n = n0 + i, m = m0 + j;
        float v = 0.f;
        if (n < NN && m < NN)
            v = __expf(S[(long)n * NN + m] - cmx[m]) * (1.f / csm[m]);
        tile[j][i] = v;
    }
    __syncthreads();
#pragma unroll
    for (int e = 0; e < 16; ++e) {
        int f = e * 256 + t; int i = f >> 6, j = f & 63;
        int m = m0 + i;
        if (m < NN) Pb[(long)m * NP + n0 + j] = f2bf(tile[i][j]);
    }
}

// ---------------------------------------------------------------------------
// Per-pixel gate sigmoid: sg[b][p] = sigmoid(sum_c gw[c]*Z[c,p])
// ---------------------------------------------------------------------------
__global__ __launch_bounds__(256)
void gate_sig(const float* __restrict__ Z, const float* __restrict__ gw,
              float* __restrict__ sg)
{
    int t = threadIdx.x;
    int px = t & 63, ck = t >> 6;
    int b = blockIdx.y;
    int p = blockIdx.x * 64 + px;
    const float* Zp = Z + (long)b * CC * NN;
    float g = 0.f;
    if (p < NN) {
        for (int c = ck * 64; c < ck * 64 + 64; ++c) g += gw[c] * Zp[(long)c * NN + p];
    }
    __shared__ float red[256];
    red[t] = g;
    __syncthreads();
    if (t < 64) {
        int pp = blockIdx.x * 64 + t;
        if (pp < NN) {
            float tot = red[t] + red[t + 64] + red[t + 128] + red[t + 192];
            sg[b * NN + pp] = 1.f / (1.f + __expf(-tot));
        }
    }
}

// ---------------------------------------------------------------------------
// BatchNorm batch-stats -> scale/shift
// ---------------------------------------------------------------------------
__global__ __launch_bounds__(256)
void bn_stats_kernel(const float* __restrict__ Y, const float* __restrict__ g,
                     const float* __restrict__ beta, float* __restrict__ scale,
                     float* __restrict__ shift)
{
    int c = blockIdx.x, t = threadIdx.x;
    float s = 0.f, sq = 0.f;
    for (int b = 0; b < BB; ++b) {
        const float* p = Y + (long)b * CC * NN + (long)c * NN;
        for (int i = t; i < NN; i += 256) { float v = p[i]; s += v; sq += v * v; }
    }
    __shared__ float ls[256], lq[256];
    ls[t] = s; lq[t] = sq;
    __syncthreads();
    for (int off = 128; off > 0; off >>= 1) {
        if (t < off) { ls[t] += ls[t + off]; lq[t] += lq[t + off]; }
        __syncthreads();
    }
    if (t == 0) {
        const float inv = 1.f / (float)(BB * NN);
        float mean = ls[0] * inv;
        float var = fmaxf(lq[0] * inv - mean * mean, 0.f);
        float sc = g[c] * rsqrtf(var + 1e-5f);
        scale[c] = sc;
        shift[c] = beta[c] - mean * sc;
    }
}

// ---------------------------------------------------------------------------
// Fused BN-normalize + ReLU + 1x1 cls conv + bias
// ---------------------------------------------------------------------------
__global__ __launch_bounds__(256)
void cls_kernel(const float* __restrict__ Y, const float* __restrict__ scale,
                const float* __restrict__ shift, const float* __restrict__ cw,
                const float* __restrict__ cb, float* __restrict__ O)
{
    int t = threadIdx.x;
    int px = t & 63, ck = t >> 6;
    int b = blockIdx.y;
    int p = blockIdx.x * 64 + px;
    const float* Yb = Y + (long)b * CC * NN;
    float a0 = 0.f, a1 = 0.f;
    if (p < NN) {
        for (int c = ck * 64; c < ck * 64 + 64; ++c) {
            float v = Yb[(long)c * NN + p] * scale[c] + shift[c];
            v = fmaxf(v, 0.f);
            a0 += cw[c] * v;
            a1 += cw[CC + c] * v;
        }
    }
    __shared__ float r0[256], r1[256];
    r0[t] = a0; r1[t] = a1;
    __syncthreads();
    if (t < 64) {
        int pp = blockIdx.x * 64 + t;
        if (pp < NN) {
            float s0 = r0[t] + r0[t + 64] + r0[t + 128] + r0[t + 192];
            float s1 = r1[t] + r1[t + 64] + r1[t + 128] + r1[t + 192];
            O[(long)b * NCH * NN + pp] = s0 + cb[0];
            O[(long)b * NCH * NN + NN + pp] = s1 + cb[1];
        }
    }
}

// ---------------------------------------------------------------------------
// Bilinear resize 60x60 -> 473x473 (half-pixel, clamp) + sigmoid
// ---------------------------------------------------------------------------
__global__ __launch_bounds__(256)
void resize_sig_kernel(const float* __restrict__ I1, const float* __restrict__ I2,
                       float* __restrict__ O)
{
    const long HALF = (long)BB * NCH * HO * WO;
    long gid = (long)blockIdx.x * 256 + threadIdx.x;
    if (gid >= HALF) return;
    int half = blockIdx.y;
    const float* I = half ? I2 : I1;
    float* Op = O + half * HALF;

    int j = (int)(gid % WO);
    long r = gid / WO;
    int i = (int)(r % HO);
    int pc = (int)(r / HO);
    const float* ip = I + (long)pc * NN;

    const float SCL = 60.0f / 473.0f;
    float fy = (i + 0.5f) * SCL - 0.5f;
    float fx = (j + 0.5f) * SCL - 0.5f;
    int y0 = (int)floorf(fy);
    int x0 = (int)floorf(fx);
    float ty = fy - (float)y0;
    float tx = fx - (float)x0;
    int y0c = max(y0, 0), y1c = min(y0 + 1, 59);
    int x0c = max(x0, 0), x1c = min(x0 + 1, 59);
    float va = ip[y0c * 60 + x0c], vb = ip[y0c * 60 + x1c];
    float vc = ip[y1c * 60 + x0c], vd = ip[y1c * 60 + x1c];
    float v = (1.f - ty) * ((1.f - tx) * va + tx * vb) + ty * ((1.f - tx) * vc + tx * vd);
    Op[gid] = 1.f / (1.f + __expf(-v));
}

// ---------------------------------------------------------------------------
extern "C" void kernel_launch(void* const* d_in, const int* in_sizes, int n_in,
                              void* d_out, int out_size, void* d_ws, size_t ws_size,
                              hipStream_t stream)
{
    const float* V_a    = (const float*)d_in[0];
    const float* V_b    = (const float*)d_in[1];
    const float* D_a    = (const float*)d_in[2];
    const float* W_e    = (const float*)d_in[3];
    const float* gate_w = (const float*)d_in[4];
    const float* conv1_w = (const float*)d_in[5];
    const float* conv2_w = (const float*)d_in[6];
    const float* bn1_g = (const float*)d_in[7];
    const float* bn1_b = (const float*)d_in[8];
    const float* bn2_g = (const float*)d_in[9];
    const float* bn2_b = (const float*)d_in[10];
    const float* cls1_w = (const float*)d_in[11];
    const float* cls1_b = (const float*)d_in[12];
    const float* cls2_w = (const float*)d_in[13];
    const float* cls2_b = (const float*)d_in[14];
    float* out = (float*)d_out;

    // ---- workspace arena: ~146 MB (known-safe bound: 154.9 MB) ----
    size_t off = 0;
    char* wsb = (char*)d_ws;
    auto carve = [&](size_t bytes) -> char* {
        char* p = wsb + off; off += (bytes + 255) & ~(size_t)255; return p;
    };

    float* S    = (float*)carve((size_t)NN * NN * 4);      // 51.8 MB; conv partials alias
    float* part = S;                                       // 6*CC*NN*4 = 22.1 MB fits
    u16* Pb    = (u16*)carve((size_t)NR * NP * 2);         // 27.1 MB, per-batch
    u16* vab   = (u16*)carve((size_t)BB * CC * NP * 2);
    u16* vbb   = (u16*)carve((size_t)BB * CC * NP * 2);
    u16* vat   = (u16*)carve((size_t)BB * NR * CC * 2);
    u16* vbt   = (u16*)carve((size_t)BB * NR * CC * 2);
    u16* daT   = (u16*)carve((size_t)BB * NR * CC * 2);
    u16* gzaT  = (u16*)carve((size_t)BB * NR * CC * 2);
    u16* gzbT  = (u16*)carve((size_t)BB * NR * CC * 2);
    u16* wgtb  = (u16*)carve((size_t)BB * NR * CC * 2);
    u16* web   = (u16*)carve((size_t)CC * CC * 2);
    u16* wt1   = (u16*)carve((size_t)CC * 9 * 768 * 2);
    u16* wt2   = (u16*)carve((size_t)CC * 9 * 512 * 2);
    float* Za  = (float*)carve((size_t)BB * CC * NN * 4);  // y1 aliases after gates
    float* Zb  = (float*)carve((size_t)BB * CC * NN * 4);  // y2 aliases after gates
    float* y1  = Za;
    float* y2  = Zb;
    float* rmx = (float*)carve((size_t)BB * NN * 4);
    float* rsm = (float*)carve((size_t)BB * NN * 4);
    float* cmx = (float*)carve((size_t)BB * NN * 4);
    float* csm = (float*)carve((size_t)BB * NN * 4);
    float* sga = (float*)carve((size_t)BB * NN * 4);
    float* sgb = (float*)carve((size_t)BB * NN * 4);
    float* pcm = (float*)carve((size_t)RCH * NN * 4);
    float* pcs = (float*)carve((size_t)RCH * NN * 4);
    float* c1o = (float*)carve((size_t)BB * NCH * NN * 4);
    float* c2o = (float*)carve((size_t)BB * NCH * NN * 4);

    dim3 blk(256);

    // --- input conversions ---
    cvt_we<<<256, blk, 0, stream>>>(W_e, web);
    cvt_pad<<<(int)(((long)BB * CC * NP + 255) / 256), blk, 0, stream>>>(V_a, vab, BB * CC);
    cvt_pad<<<(int)(((long)BB * CC * NP + 255) / 256), blk, 0, stream>>>(V_b, vbb, BB * CC);
    transpose_cvt<<<dim3(57, 4, BB), blk, 0, stream>>>(V_a, vat);
    transpose_cvt<<<dim3(57, 4, BB), blk, 0, stream>>>(V_b, vbt);
    transpose_cvt<<<dim3(57, 4, BB), blk, 0, stream>>>(D_a, daT);
    cvt_convw<768><<<(int)(((long)CC * 9 * 768 + 255) / 256), blk, 0, stream>>>(conv1_w, wt1);
    cvt_convw<512><<<(int)(((long)CC * 9 * 512 + 255) / 256), blk, 0, stream>>>(conv2_w, wt2);

    // --- weighted (both batches) ---
    gemm_we<<<dim3(2, 29, BB), blk, 0, stream>>>(vat, web, wgtb);

    // --- attention, per batch (S + Pb buffers reused) ---
    for (int b = 0; b < BB; ++b) {
        const u16* wgtb_b = wgtb + (long)b * NR * CC;
        const u16* vbt_b  = vbt + (long)b * NR * CC;
        const u16* vab_b  = vab + (long)b * CC * NP;
        const u16* vbb_b  = vbb + (long)b * CC * NP;
        float* rmx_b = rmx + b * NN; float* rsm_b = rsm + b * NN;
        float* cmx_b = cmx + b * NN; float* csm_b = csm + b * NN;

        gemm_s<<<dim3(29, 29), blk, 0, stream>>>(wgtb_b, vbt_b, S);
        rowstats_kernel<<<dim3(NN), blk, 0, stream>>>(S, rmx_b, rsm_b);
        colstats_part_kernel<<<dim3((NN + 255) / 256, RCH), blk, 0, stream>>>(S, pcm, pcs);
        colstats_comb_kernel<<<dim3((NN + 255) / 256), blk, 0, stream>>>(pcm, pcs, cmx_b, csm_b);
        pb_build<<<dim3(57, 57), blk, 0, stream>>>(S, cmx_b, csm_b, Pb);
        gemm_z<<<dim3(29, 4, 2), blk, 0, stream>>>(
            vab_b, vbb_b, Pb, S, rmx_b, rsm_b,
            Zb + (long)b * CC * NN, Za + (long)b * CC * NN);
    }

    // --- gates: per-pixel sigmoid, then transpose-scale to [p][c] bf16 ---
    gate_sig<<<dim3(57, BB), blk, 0, stream>>>(Za, gate_w, sga);
    gate_sig<<<dim3(57, BB), blk, 0, stream>>>(Zb, gate_w, sgb);
    transpose_gate<<<dim3(57, 4, BB), blk, 0, stream>>>(Za, sga, gzaT);
    transpose_gate<<<dim3(57, 4, BB), blk, 0, stream>>>(Zb, sgb, gzbT);

    // --- convs: direct split-K GEMM (partials in dead S region) ---
    conv_direct<768><<<dim3(29, 4, 6), blk, 0, stream>>>(wt1, gzaT, vat, daT, part);
    conv_reduce<<<(int)(((long)BB * CC * NN + 255) / 256), blk, 0, stream>>>(part, y1);
    conv_direct<512><<<dim3(29, 4, 6), blk, 0, stream>>>(wt2, gzbT, vbt, vbt, part);
    conv_reduce<<<(int)(((long)BB * CC * NN + 255) / 256), blk, 0, stream>>>(part, y2);

    // --- BN + cls + resize --- (rmx/rsm/cmx/csm reused as scale/shift)
    bn_stats_kernel<<<256, blk, 0, stream>>>(y1, bn1_g, bn1_b, rmx, rsm);
    bn_stats_kernel<<<256, blk, 0, stream>>>(y2, bn2_g, bn2_b, cmx, csm);
    cls_kernel<<<dim3(57, BB), blk, 0, stream>>>(y1, rmx, rsm, cls1_w, cls1_b, c1o);
    cls_kernel<<<dim3(57, BB), blk, 0, stream>>>(y2, cmx, csm, cls2_w, cls2_b, c2o);

    resize_sig_kernel<<<dim3((int)(((long)BB * NCH * HO * WO + 255) / 256), 2), blk, 0, stream>>>(c1o, c2o, out);
}

// Round 6
// 788.460 us; speedup vs baseline: 4.4345x; 1.2371x over previous
//
#include <hip/hip_runtime.h>

#define BB 2
#define CC 256
#define NN 3600
#define NCH 2
#define HO 473
#define WO 473
#define RCH 36
#define NP 3648          // NN padded to mult of 64 (K padding)
#define NR 3712          // NN padded to mult of 128 (row padding)
#define LDT 72           // LDS tile row stride in u16 (16B-aligned)
#define ZKS 3            // split-K factor for Z GEMMs (3 x 1216)

typedef unsigned short u16;
typedef __attribute__((ext_vector_type(8))) short short8;
typedef __attribute__((ext_vector_type(4))) float f32x4;

static __device__ __forceinline__ u16 f2bf(float f) {
    unsigned u = __float_as_uint(f);
    unsigned r = (u + 0x7FFF + ((u >> 16) & 1)) >> 16;
    return (u16)r;
}

// ---------------------------------------------------------------------------
// bf16 MFMA GEMM core: C[m][n] = sum_k A[m][k] * B[n][k] (both k-contiguous).
// 256 threads = 4 waves. Tile: (MT*32) x 128, BK=64.
// EXPB=1: B is fp32 src; staged as exp(v - mxp[row]); epilogue scales col by
//         1/smp[col]. All stagings row-guarded.
// ---------------------------------------------------------------------------
template<int OUTBF, int EXPB, int MT>
static __device__ __forceinline__ void gemm_core(
    const u16* __restrict__ A, long lda,
    const u16* __restrict__ Bb, long ldb,
    const float* __restrict__ Bf, long ldbf,
    const float* __restrict__ mxp, const float* __restrict__ smp,
    void* __restrict__ Cp, long ldc,
    int M, int N, int K, int Kv, int m0, int n0)
{
    __shared__ u16 As[MT * 32 * LDT];
    __shared__ u16 Bs[128 * LDT];

    const int t = threadIdx.x;
    const int w = t >> 6, lane = t & 63;
    const int mh = (w >> 1) * (MT * 16), nh = (w & 1) * 64;
    const int lm = lane & 15, quad = lane >> 4;

    f32x4 acc[MT][4] = {};

    for (int k0 = 0; k0 < K; k0 += 64) {
#pragma unroll
        for (int i = 0; i < MT; ++i) {
            int idx = i * 256 + t;
            int row = idx >> 3, c8 = (idx & 7) * 8;
            int rg = m0 + row;
            uint4 v = make_uint4(0u, 0u, 0u, 0u);
            if (rg < M) v = *(const uint4*)(A + (long)rg * lda + k0 + c8);
            *(uint4*)(&As[row * LDT + c8]) = v;
        }
#pragma unroll
        for (int i = 0; i < 4; ++i) {
            int idx = i * 256 + t;
            int row = idx >> 3, c8 = (idx & 7) * 8;
            int rg = n0 + row;
            if (EXPB) {
                u16 tmp[8] = {0, 0, 0, 0, 0, 0, 0, 0};
                int kg = k0 + c8;
                if (rg < N && kg < Kv) {
                    float mv = mxp[rg];
                    float4 v0 = *(const float4*)(Bf + (long)rg * ldbf + kg);
                    float4 v1 = *(const float4*)(Bf + (long)rg * ldbf + kg + 4);
                    tmp[0] = f2bf(__expf(v0.x - mv)); tmp[1] = f2bf(__expf(v0.y - mv));
                    tmp[2] = f2bf(__expf(v0.z - mv)); tmp[3] = f2bf(__expf(v0.w - mv));
                    tmp[4] = f2bf(__expf(v1.x - mv)); tmp[5] = f2bf(__expf(v1.y - mv));
                    tmp[6] = f2bf(__expf(v1.z - mv)); tmp[7] = f2bf(__expf(v1.w - mv));
                }
                *(uint4*)(&Bs[row * LDT + c8]) = *(const uint4*)tmp;
            } else {
                uint4 v = make_uint4(0u, 0u, 0u, 0u);
                if (rg < N) v = *(const uint4*)(Bb + (long)rg * ldb + k0 + c8);
                *(uint4*)(&Bs[row * LDT + c8]) = v;
            }
        }
        __syncthreads();
#pragma unroll
        for (int s = 0; s < 2; ++s) {
            short8 a[MT], b[4];
#pragma unroll
            for (int i = 0; i < MT; ++i)
                a[i] = *(const short8*)(&As[(mh + i * 16 + lm) * LDT + s * 32 + quad * 8]);
#pragma unroll
            for (int j = 0; j < 4; ++j)
                b[j] = *(const short8*)(&Bs[(nh + j * 16 + lm) * LDT + s * 32 + quad * 8]);
#pragma unroll
            for (int i = 0; i < MT; ++i)
#pragma unroll
                for (int j = 0; j < 4; ++j)
                    acc[i][j] = __builtin_amdgcn_mfma_f32_16x16x32_bf16(a[i], b[j], acc[i][j], 0, 0, 0);
        }
        __syncthreads();
    }

    float scl[4] = {1.f, 1.f, 1.f, 1.f};
    if (EXPB) {
#pragma unroll
        for (int j = 0; j < 4; ++j) {
            int col = n0 + nh + j * 16 + lm;
            if (col < N) scl[j] = 1.f / smp[col];
        }
    }
#pragma unroll
    for (int i = 0; i < MT; ++i) {
#pragma unroll
        for (int r = 0; r < 4; ++r) {
            int row = m0 + mh + i * 16 + quad * 4 + r;
            if (row < M) {
#pragma unroll
                for (int j = 0; j < 4; ++j) {
                    int col = n0 + nh + j * 16 + lm;
                    if (col < N) {
                        float v = acc[i][j][r] * scl[j];
                        if (OUTBF) ((u16*)Cp)[(long)row * ldc + col] = f2bf(v);
                        else       ((float*)Cp)[(long)row * ldc + col] = v;
                    }
                }
            }
        }
    }
}

// weighted[n][d] = sum_c VaT[n][c] * We[d][c]; both batches
__global__ __launch_bounds__(256)
void gemm_we(const u16* __restrict__ vat, const u16* __restrict__ web,
             u16* __restrict__ wgtb)
{
    int b = blockIdx.z;
    gemm_core<1, 0, 4>(vat + (long)b * NR * CC, CC, web, CC, nullptr, 0,
                       nullptr, nullptr, wgtb + (long)b * NR * CC, CC,
                       NN, CC, CC, CC, blockIdx.y * 128, blockIdx.x * 128);
}

// S[n][m] = sum_d wgt[n][d] * VbT[m][d]; per batch
__global__ __launch_bounds__(256)
void gemm_s(const u16* __restrict__ A, const u16* __restrict__ B, float* __restrict__ S)
{
    gemm_core<0, 0, 4>(A, CC, B, CC, nullptr, 0, nullptr, nullptr, S, NN,
                       NN, NN, CC, CC, blockIdx.y * 128, blockIdx.x * 128);
}

// ---------------------------------------------------------------------------
// Split-K Z GEMM core: 64x128 tile over k range [kbeg,kend); atomicAdd fp32
// epilogue. Shared LDS passed in (single allocation for both branches).
// A rows are exact (M=CC); B rows guarded vs N=NN; EXPB k-guarded vs NN.
// ---------------------------------------------------------------------------
template<int EXPB>
static __device__ __forceinline__ void zcore(
    const u16* __restrict__ A, long lda,
    const u16* __restrict__ Bb, long ldb,
    const float* __restrict__ Bf, long ldbf,
    const float* __restrict__ mxp, const float* __restrict__ smp,
    float* __restrict__ Cp,
    int kbeg, int kend, int m0, int n0,
    u16* __restrict__ As, u16* __restrict__ Bs)
{
    const int t = threadIdx.x;
    const int w = t >> 6, lane = t & 63;
    const int mh = (w >> 1) * 32, nh = (w & 1) * 64;
    const int lm = lane & 15, quad = lane >> 4;

    f32x4 acc[2][4] = {};

    for (int k0 = kbeg; k0 < kend; k0 += 64) {
#pragma unroll
        for (int i = 0; i < 2; ++i) {
            int idx = i * 256 + t;
            int row = idx >> 3, c8 = (idx & 7) * 8;
            uint4 v = *(const uint4*)(A + (long)(m0 + row) * lda + k0 + c8);
            *(uint4*)(&As[row * LDT + c8]) = v;
        }
#pragma unroll
        for (int i = 0; i < 4; ++i) {
            int idx = i * 256 + t;
            int row = idx >> 3, c8 = (idx & 7) * 8;
            int rg = n0 + row;
            if (EXPB) {
                u16 tmp[8] = {0, 0, 0, 0, 0, 0, 0, 0};
                int kg = k0 + c8;
                if (rg < NN && kg < NN) {
                    float mv = mxp[rg];
                    float4 v0 = *(const float4*)(Bf + (long)rg * ldbf + kg);
                    float4 v1 = *(const float4*)(Bf + (long)rg * ldbf + kg + 4);
                    tmp[0] = f2bf(__expf(v0.x - mv)); tmp[1] = f2bf(__expf(v0.y - mv));
                    tmp[2] = f2bf(__expf(v0.z - mv)); tmp[3] = f2bf(__expf(v0.w - mv));
                    tmp[4] = f2bf(__expf(v1.x - mv)); tmp[5] = f2bf(__expf(v1.y - mv));
                    tmp[6] = f2bf(__expf(v1.z - mv)); tmp[7] = f2bf(__expf(v1.w - mv));
                }
                *(uint4*)(&Bs[row * LDT + c8]) = *(const uint4*)tmp;
            } else {
                uint4 v = make_uint4(0u, 0u, 0u, 0u);
                if (rg < NN) v = *(const uint4*)(Bb + (long)rg * ldb + k0 + c8);
                *(uint4*)(&Bs[row * LDT + c8]) = v;
            }
        }
        __syncthreads();
#pragma unroll
        for (int s = 0; s < 2; ++s) {
            short8 a[2], b[4];
#pragma unroll
            for (int i = 0; i < 2; ++i)
                a[i] = *(const short8*)(&As[(mh + i * 16 + lm) * LDT + s * 32 + quad * 8]);
#pragma unroll
            for (int j = 0; j < 4; ++j)
                b[j] = *(const short8*)(&Bs[(nh + j * 16 + lm) * LDT + s * 32 + quad * 8]);
#pragma unroll
            for (int i = 0; i < 2; ++i)
#pragma unroll
                for (int j = 0; j < 4; ++j)
                    acc[i][j] = __builtin_amdgcn_mfma_f32_16x16x32_bf16(a[i], b[j], acc[i][j], 0, 0, 0);
        }
        __syncthreads();
    }

    float scl[4] = {1.f, 1.f, 1.f, 1.f};
    if (EXPB) {
#pragma unroll
        for (int j = 0; j < 4; ++j) {
            int col = n0 + nh + j * 16 + lm;
            if (col < NN) scl[j] = 1.f / smp[col];
        }
    }
#pragma unroll
    for (int i = 0; i < 2; ++i) {
#pragma unroll
        for (int r = 0; r < 4; ++r) {
            int row = m0 + mh + i * 16 + quad * 4 + r;
#pragma unroll
            for (int j = 0; j < 4; ++j) {
                int col = n0 + nh + j * 16 + lm;
                if (col < NN)
                    atomicAdd(&Cp[(long)row * NN + col], acc[i][j][r] * scl[j]);
            }
        }
    }
}

// Per-batch split-K Z pair. blockIdx.z: bit0 = branch, >>1 = k-slice (ZKS).
// Za/Zb must be zero-initialized before launch.
__global__ __launch_bounds__(256)
void gemm_z_split(const u16* __restrict__ vab_b, const u16* __restrict__ vbb_b,
                  const u16* __restrict__ Pb, const float* __restrict__ S,
                  const float* __restrict__ rmx_b, const float* __restrict__ rsm_b,
                  float* __restrict__ Zb_b, float* __restrict__ Za_b)
{
    __shared__ u16 smem[(64 + 128) * LDT];
    u16* As = smem;
    u16* Bs = smem + 64 * LDT;
    const int z = blockIdx.z;
    const int ks = z >> 1;
    const int kbeg = ks * (NP / ZKS);
    const int kend = kbeg + (NP / ZKS);
    const int m0 = blockIdx.y * 64, n0 = blockIdx.x * 128;
    if ((z & 1) == 0)
        zcore<0>(vab_b, NP, Pb, NP, nullptr, 0, nullptr, nullptr,
                 Zb_b, kbeg, kend, m0, n0, As, Bs);
    else
        zcore<1>(vbb_b, NP, nullptr, 0, S, NN, rmx_b, rsm_b,
                 Za_b, kbeg, kend, m0, n0, As, Bs);
}

// ---------------------------------------------------------------------------
// Direct 3x3 conv as split-K MFMA GEMM over virtual im2col.
// W: [256][9*CIN] bf16 (k = tap*CIN + ci). Planes: [p][256] bf16, row stride
// CC, batch stride NR*CC. grid: (29 p-tiles, 4 co-tiles, 6 = b*3 + ksplit).
// ---------------------------------------------------------------------------
template<int CIN>
__global__ __launch_bounds__(256)
void conv_direct(const u16* __restrict__ W,
                 const u16* __restrict__ P0, const u16* __restrict__ P1,
                 const u16* __restrict__ P2, float* __restrict__ part)
{
    const int KT = 9 * CIN;
    __shared__ u16 As[64 * LDT];
    __shared__ u16 Bs[128 * LDT];

    const int t = threadIdx.x;
    const int w = t >> 6, lane = t & 63;
    const int mh = (w >> 1) * 32, nh = (w & 1) * 64;
    const int lm = lane & 15, quad = lane >> 4;
    const int z = blockIdx.z, b = z / 3, ks = z - 3 * (z / 3);
    const int m0 = blockIdx.y * 64, n0 = blockIdx.x * 128;
    const long pstride = (long)NR * CC;

    f32x4 acc[2][4] = {};

    const int kbeg = ks * 3 * CIN, kend = kbeg + 3 * CIN;
    for (int k0 = kbeg; k0 < kend; k0 += 64) {
        int tap = k0 / CIN;
        int kloc = k0 - tap * CIN;
        int plane = kloc >> 8, cip = kloc & 255;
        int dh = tap / 3 - 1, dw = tap - (tap / 3) * 3 - 1;
        int off = dh * 60 + dw;
        const u16* src = (plane == 0) ? P0 : ((plane == 1) ? P1 : P2);
        src += (long)b * pstride + cip;

#pragma unroll
        for (int i = 0; i < 2; ++i) {
            int idx = i * 256 + t;
            int row = idx >> 3, c8 = (idx & 7) * 8;
            uint4 v = *(const uint4*)(W + (long)(m0 + row) * KT + k0 + c8);
            *(uint4*)(&As[row * LDT + c8]) = v;
        }
#pragma unroll
        for (int i = 0; i < 4; ++i) {
            int idx = i * 256 + t;
            int row = idx >> 3, c8 = (idx & 7) * 8;
            int p = n0 + row;
            uint4 v = make_uint4(0u, 0u, 0u, 0u);
            if (p < NN) {
                int h = p / 60, wp = p - h * 60;
                int hh = h + dh, wq = wp + dw;
                if (hh >= 0 && hh < 60 && wq >= 0 && wq < 60)
                    v = *(const uint4*)(src + (long)(p + off) * CC + c8);
            }
            *(uint4*)(&Bs[row * LDT + c8]) = v;
        }
        __syncthreads();
#pragma unroll
        for (int s = 0; s < 2; ++s) {
            short8 a[2], bfr[4];
#pragma unroll
            for (int i = 0; i < 2; ++i)
                a[i] = *(const short8*)(&As[(mh + i * 16 + lm) * LDT + s * 32 + quad * 8]);
#pragma unroll
            for (int j = 0; j < 4; ++j)
                bfr[j] = *(const short8*)(&Bs[(nh + j * 16 + lm) * LDT + s * 32 + quad * 8]);
#pragma unroll
            for (int i = 0; i < 2; ++i)
#pragma unroll
                for (int j = 0; j < 4; ++j)
                    acc[i][j] = __builtin_amdgcn_mfma_f32_16x16x32_bf16(a[i], bfr[j], acc[i][j], 0, 0, 0);
        }
        __syncthreads();
    }

    float* out = part + (long)z * CC * NN;
#pragma unroll
    for (int i = 0; i < 2; ++i) {
#pragma unroll
        for (int r = 0; r < 4; ++r) {
            int row = m0 + mh + i * 16 + quad * 4 + r;
#pragma unroll
            for (int j = 0; j < 4; ++j) {
                int col = n0 + nh + j * 16 + lm;
                if (col < NN) out[(long)row * NN + col] = acc[i][j][r];
            }
        }
    }
}

// Y[b][co][p] = sum of 3 partial slices
__global__ __launch_bounds__(256)
void conv_reduce(const float* __restrict__ part, float* __restrict__ Y)
{
    long idx = (long)blockIdx.x * 256 + threadIdx.x;
    if (idx >= (long)BB * CC * NN) return;
    long b = idx / ((long)CC * NN), r = idx - b * (long)CC * NN;
    const float* p0 = part + (b * 3 + 0) * (long)CC * NN;
    const float* p1 = part + (b * 3 + 1) * (long)CC * NN;
    const float* p2 = part + (b * 3 + 2) * (long)CC * NN;
    Y[idx] = p0[r] + p1[r] + p2[r];
}

// ---------------------------------------------------------------------------
// Converters / transposes
// ---------------------------------------------------------------------------
__global__ __launch_bounds__(256)
void cvt_we(const float* __restrict__ W, u16* __restrict__ O)
{
    int i = blockIdx.x * 256 + threadIdx.x;
    if (i < CC * CC) O[i] = f2bf(W[i]);
}

__global__ __launch_bounds__(256)
void cvt_pad(const float* __restrict__ src, u16* __restrict__ dst, int R)
{
    long idx = (long)blockIdx.x * 256 + threadIdx.x;
    if (idx >= (long)R * NP) return;
    int j = (int)(idx % NP);
    long r = idx / NP;
    dst[idx] = (j < NN) ? f2bf(src[r * NN + j]) : (u16)0;
}

// V [b][256][3600] fp32 -> VT [b][3712][256] bf16
__global__ __launch_bounds__(256)
void transpose_cvt(const float* __restrict__ V, u16* __restrict__ VT)
{
    __shared__ float tile[64][65];
    int b = blockIdx.z, c0 = blockIdx.y * 64, n0 = blockIdx.x * 64;
    int t = threadIdx.x;
#pragma unroll
    for (int e = 0; e < 16; ++e) {
        int f = e * 256 + t; int i = f >> 6, j = f & 63;
        int n = n0 + j;
        float v = 0.f;
        if (n < NN) v = V[((long)b * CC + c0 + i) * NN + n];
        tile[i][j] = v;
    }
    __syncthreads();
#pragma unroll
    for (int e = 0; e < 16; ++e) {
        int f = e * 256 + t; int i = f >> 6, j = f & 63;
        int n = n0 + i;
        if (n < NN) VT[((long)b * NR + n) * CC + c0 + j] = f2bf(tile[j][i]);
    }
}

// Za fp32 [b][c][p] * sg[b][p] -> ZT bf16 [b][p][c]
__global__ __launch_bounds__(256)
void transpose_gate(const float* __restrict__ Z, const float* __restrict__ sg,
                    u16* __restrict__ ZT)
{
    __shared__ float tile[64][65];
    int b = blockIdx.z, c0 = blockIdx.y * 64, n0 = blockIdx.x * 64;
    int t = threadIdx.x;
#pragma unroll
    for (int e = 0; e < 16; ++e) {
        int f = e * 256 + t; int i = f >> 6, j = f & 63;
        int n = n0 + j;
        float v = 0.f;
        if (n < NN) v = Z[((long)b * CC + c0 + i) * NN + n];
        tile[i][j] = v;
    }
    __syncthreads();
#pragma unroll
    for (int e = 0; e < 16; ++e) {
        int f = e * 256 + t; int i = f >> 6, j = f & 63;
        int n = n0 + i;
        if (n < NN)
            ZT[((long)b * NR + n) * CC + c0 + j] = f2bf(tile[j][i] * sg[b * NN + n]);
    }
}

template<int CIN>
__global__ __launch_bounds__(256)
void cvt_convw(const float* __restrict__ W, u16* __restrict__ O)
{
    const int KT = 9 * CIN;
    long idx = (long)blockIdx.x * 256 + threadIdx.x;
    if (idx >= (long)CC * KT) return;
    int co = (int)(idx / KT);
    int r = (int)(idx % KT);
    int tap = r / CIN, ci = r % CIN;
    O[idx] = f2bf(W[((long)co * CIN + ci) * 9 + tap]);
}

// ---------------------------------------------------------------------------
// Softmax stats on per-batch fp32 S
// ---------------------------------------------------------------------------
__global__ __launch_bounds__(256)
void rowstats_kernel(const float* __restrict__ S, float* __restrict__ rmax,
                     float* __restrict__ rsum)
{
    int n = blockIdx.x;
    const float* Sp = S + (long)n * NN;
    int t = threadIdx.x;
    float mx = -3.0e38f, s = 0.f;
    for (int i = t; i < NN; i += 256) {
        float v = Sp[i];
        if (v > mx) { s = s * __expf(mx - v) + 1.f; mx = v; }
        else        { s += __expf(v - mx); }
    }
    __shared__ float lm[256], ls[256];
    lm[t] = mx; ls[t] = s;
    __syncthreads();
    for (int off = 128; off > 0; off >>= 1) {
        if (t < off) {
            float m1 = lm[t], m2 = lm[t + off];
            float M = fmaxf(m1, m2);
            ls[t] = ls[t] * __expf(m1 - M) + ls[t + off] * __expf(m2 - M);
            lm[t] = M;
        }
        __syncthreads();
    }
    if (t == 0) { rmax[n] = lm[0]; rsum[n] = ls[0]; }
}

__global__ __launch_bounds__(256)
void colstats_part_kernel(const float* __restrict__ S,
                          float* __restrict__ pmax, float* __restrict__ psum)
{
    const int ROWS = NN / RCH;
    int col = blockIdx.x * 256 + threadIdx.x;
    int rc = blockIdx.y;
    if (col >= NN) return;
    const float* Sp = S + (long)(rc * ROWS) * NN + col;
    float mx = -3.0e38f, s = 0.f;
    for (int r = 0; r < ROWS; ++r) {
        float v = Sp[(long)r * NN];
        if (v > mx) { s = s * __expf(mx - v) + 1.f; mx = v; }
        else        { s += __expf(v - mx); }
    }
    long o = (long)rc * NN + col;
    pmax[o] = mx; psum[o] = s;
}

__global__ __launch_bounds__(256)
void colstats_comb_kernel(const float* __restrict__ pmax, const float* __restrict__ psum,
                          float* __restrict__ cmax, float* __restrict__ csum)
{
    int col = blockIdx.x * 256 + threadIdx.x;
    if (col >= NN) return;
    float mx = -3.0e38f, s = 0.f;
    for (int rc = 0; rc < RCH; ++rc) {
        long o = (long)rc * NN + col;
        float m2 = pmax[o], s2 = psum[o];
        float M = fmaxf(mx, m2);
        s = s * __expf(mx - M) + s2 * __expf(m2 - M);
        mx = M;
    }
    cmax[col] = mx; csum[col] = s;
}

// Pb[m][n] = exp(S[n][m]-cmax[m])/csum[m], bf16, cols padded to NP with 0
__global__ __launch_bounds__(256)
void pb_build(const float* __restrict__ S, const float* __restrict__ cmx,
              const float* __restrict__ csm, u16* __restrict__ Pb)
{
    __shared__ float tile[64][65];
    int m0 = blockIdx.y * 64;
    int n0 = blockIdx.x * 64;
    int t = threadIdx.x;
#pragma unroll
    for (int e = 0; e < 16; ++e) {
        int f = e * 256 + t; int i = f >> 6, j = f & 63;
        int n = n0 + i, m = m0 + j;
        float v = 0.f;
        if (n < NN && m < NN)
            v = __expf(S[(long)n * NN + m] - cmx[m]) * (1.f / csm[m]);
        tile[j][i] = v;
    }
    __syncthreads();
#pragma unroll
    for (int e = 0; e < 16; ++e) {
        int f = e * 256 + t; int i = f >> 6, j = f & 63;
        int m = m0 + i;
        if (m < NN) Pb[(long)m * NP + n0 + j] = f2bf(tile[i][j]);
    }
}

// ---------------------------------------------------------------------------
// Per-pixel gate sigmoid: sg[b][p] = sigmoid(sum_c gw[c]*Z[c,p])
// ---------------------------------------------------------------------------
__global__ __launch_bounds__(256)
void gate_sig(const float* __restrict__ Z, const float* __restrict__ gw,
              float* __restrict__ sg)
{
    int t = threadIdx.x;
    int px = t & 63, ck = t >> 6;
    int b = blockIdx.y;
    int p = blockIdx.x * 64 + px;
    const float* Zp = Z + (long)b * CC * NN;
    float g = 0.f;
    if (p < NN) {
        for (int c = ck * 64; c < ck * 64 + 64; ++c) g += gw[c] * Zp[(long)c * NN + p];
    }
    __shared__ float red[256];
    red[t] = g;
    __syncthreads();
    if (t < 64) {
        int pp = blockIdx.x * 64 + t;
        if (pp < NN) {
            float tot = red[t] + red[t + 64] + red[t + 128] + red[t + 192];
            sg[b * NN + pp] = 1.f / (1.f + __expf(-tot));
        }
    }
}

// ---------------------------------------------------------------------------
// BatchNorm batch-stats -> scale/shift
// ---------------------------------------------------------------------------
__global__ __launch_bounds__(256)
void bn_stats_kernel(const float* __restrict__ Y, const float* __restrict__ g,
                     const float* __restrict__ beta, float* __restrict__ scale,
                     float* __restrict__ shift)
{
    int c = blockIdx.x, t = threadIdx.x;
    float s = 0.f, sq = 0.f;
    for (int b = 0; b < BB; ++b) {
        const float* p = Y + (long)b * CC * NN + (long)c * NN;
        for (int i = t; i < NN; i += 256) { float v = p[i]; s += v; sq += v * v; }
    }
    __shared__ float ls[256], lq[256];
    ls[t] = s; lq[t] = sq;
    __syncthreads();
    for (int off = 128; off > 0; off >>= 1) {
        if (t < off) { ls[t] += ls[t + off]; lq[t] += lq[t + off]; }
        __syncthreads();
    }
    if (t == 0) {
        const float inv = 1.f / (float)(BB * NN);
        float mean = ls[0] * inv;
        float var = fmaxf(lq[0] * inv - mean * mean, 0.f);
        float sc = g[c] * rsqrtf(var + 1e-5f);
        scale[c] = sc;
        shift[c] = beta[c] - mean * sc;
    }
}

// ---------------------------------------------------------------------------
// Fused BN-normalize + ReLU + 1x1 cls conv + bias
// ---------------------------------------------------------------------------
__global__ __launch_bounds__(256)
void cls_kernel(const float* __restrict__ Y, const float* __restrict__ scale,
                const float* __restrict__ shift, const float* __restrict__ cw,
                const float* __restrict__ cb, float* __restrict__ O)
{
    int t = threadIdx.x;
    int px = t & 63, ck = t >> 6;
    int b = blockIdx.y;
    int p = blockIdx.x * 64 + px;
    const float* Yb = Y + (long)b * CC * NN;
    float a0 = 0.f, a1 = 0.f;
    if (p < NN) {
        for (int c = ck * 64; c < ck * 64 + 64; ++c) {
            float v = Yb[(long)c * NN + p] * scale[c] + shift[c];
            v = fmaxf(v, 0.f);
            a0 += cw[c] * v;
            a1 += cw[CC + c] * v;
        }
    }
    __shared__ float r0[256], r1[256];
    r0[t] = a0; r1[t] = a1;
    __syncthreads();
    if (t < 64) {
        int pp = blockIdx.x * 64 + t;
        if (pp < NN) {
            float s0 = r0[t] + r0[t + 64] + r0[t + 128] + r0[t + 192];
            float s1 = r1[t] + r1[t + 64] + r1[t + 128] + r1[t + 192];
            O[(long)b * NCH * NN + pp] = s0 + cb[0];
            O[(long)b * NCH * NN + NN + pp] = s1 + cb[1];
        }
    }
}

// ---------------------------------------------------------------------------
// Bilinear resize 60x60 -> 473x473 (half-pixel, clamp) + sigmoid
// ---------------------------------------------------------------------------
__global__ __launch_bounds__(256)
void resize_sig_kernel(const float* __restrict__ I1, const float* __restrict__ I2,
                       float* __restrict__ O)
{
    const long HALF = (long)BB * NCH * HO * WO;
    long gid = (long)blockIdx.x * 256 + threadIdx.x;
    if (gid >= HALF) return;
    int half = blockIdx.y;
    const float* I = half ? I2 : I1;
    float* Op = O + half * HALF;

    int j = (int)(gid % WO);
    long r = gid / WO;
    int i = (int)(r % HO);
    int pc = (int)(r / HO);
    const float* ip = I + (long)pc * NN;

    const float SCL = 60.0f / 473.0f;
    float fy = (i + 0.5f) * SCL - 0.5f;
    float fx = (j + 0.5f) * SCL - 0.5f;
    int y0 = (int)floorf(fy);
    int x0 = (int)floorf(fx);
    float ty = fy - (float)y0;
    float tx = fx - (float)x0;
    int y0c = max(y0, 0), y1c = min(y0 + 1, 59);
    int x0c = max(x0, 0), x1c = min(x0 + 1, 59);
    float va = ip[y0c * 60 + x0c], vb = ip[y0c * 60 + x1c];
    float vc = ip[y1c * 60 + x0c], vd = ip[y1c * 60 + x1c];
    float v = (1.f - ty) * ((1.f - tx) * va + tx * vb) + ty * ((1.f - tx) * vc + tx * vd);
    Op[gid] = 1.f / (1.f + __expf(-v));
}

// ---------------------------------------------------------------------------
extern "C" void kernel_launch(void* const* d_in, const int* in_sizes, int n_in,
                              void* d_out, int out_size, void* d_ws, size_t ws_size,
                              hipStream_t stream)
{
    const float* V_a    = (const float*)d_in[0];
    const float* V_b    = (const float*)d_in[1];
    const float* D_a    = (const float*)d_in[2];
    const float* W_e    = (const float*)d_in[3];
    const float* gate_w = (const float*)d_in[4];
    const float* conv1_w = (const float*)d_in[5];
    const float* conv2_w = (const float*)d_in[6];
    const float* bn1_g = (const float*)d_in[7];
    const float* bn1_b = (const float*)d_in[8];
    const float* bn2_g = (const float*)d_in[9];
    const float* bn2_b = (const float*)d_in[10];
    const float* cls1_w = (const float*)d_in[11];
    const float* cls1_b = (const float*)d_in[12];
    const float* cls2_w = (const float*)d_in[13];
    const float* cls2_b = (const float*)d_in[14];
    float* out = (float*)d_out;

    // ---- workspace arena: ~146 MB (known-safe bound: 154.9 MB) ----
    size_t off = 0;
    char* wsb = (char*)d_ws;
    auto carve = [&](size_t bytes) -> char* {
        char* p = wsb + off; off += (bytes + 255) & ~(size_t)255; return p;
    };

    float* S    = (float*)carve((size_t)NN * NN * 4);      // 51.8 MB; conv partials alias
    float* part = S;                                       // 6*CC*NN*4 = 22.1 MB fits
    u16* Pb    = (u16*)carve((size_t)NR * NP * 2);         // 27.1 MB, per-batch
    u16* vab   = (u16*)carve((size_t)BB * CC * NP * 2);
    u16* vbb   = (u16*)carve((size_t)BB * CC * NP * 2);
    u16* vat   = (u16*)carve((size_t)BB * NR * CC * 2);
    u16* vbt   = (u16*)carve((size_t)BB * NR * CC * 2);
    u16* daT   = (u16*)carve((size_t)BB * NR * CC * 2);
    u16* gzaT  = (u16*)carve((size_t)BB * NR * CC * 2);
    u16* gzbT  = (u16*)carve((size_t)BB * NR * CC * 2);
    u16* wgtb  = (u16*)carve((size_t)BB * NR * CC * 2);
    u16* web   = (u16*)carve((size_t)CC * CC * 2);
    u16* wt1   = (u16*)carve((size_t)CC * 9 * 768 * 2);
    u16* wt2   = (u16*)carve((size_t)CC * 9 * 512 * 2);
    float* Za  = (float*)carve((size_t)BB * CC * NN * 4);  // y1 aliases after gates
    float* Zb  = (float*)carve((size_t)BB * CC * NN * 4);  // y2 aliases after gates
    float* y1  = Za;
    float* y2  = Zb;
    float* rmx = (float*)carve((size_t)BB * NN * 4);
    float* rsm = (float*)carve((size_t)BB * NN * 4);
    float* cmx = (float*)carve((size_t)BB * NN * 4);
    float* csm = (float*)carve((size_t)BB * NN * 4);
    float* sga = (float*)carve((size_t)BB * NN * 4);
    float* sgb = (float*)carve((size_t)BB * NN * 4);
    float* pcm = (float*)carve((size_t)RCH * NN * 4);
    float* pcs = (float*)carve((size_t)RCH * NN * 4);
    float* c1o = (float*)carve((size_t)BB * NCH * NN * 4);
    float* c2o = (float*)carve((size_t)BB * NCH * NN * 4);

    dim3 blk(256);

    // --- input conversions ---
    cvt_we<<<256, blk, 0, stream>>>(W_e, web);
    cvt_pad<<<(int)(((long)BB * CC * NP + 255) / 256), blk, 0, stream>>>(V_a, vab, BB * CC);
    cvt_pad<<<(int)(((long)BB * CC * NP + 255) / 256), blk, 0, stream>>>(V_b, vbb, BB * CC);
    transpose_cvt<<<dim3(57, 4, BB), blk, 0, stream>>>(V_a, vat);
    transpose_cvt<<<dim3(57, 4, BB), blk, 0, stream>>>(V_b, vbt);
    transpose_cvt<<<dim3(57, 4, BB), blk, 0, stream>>>(D_a, daT);
    cvt_convw<768><<<(int)(((long)CC * 9 * 768 + 255) / 256), blk, 0, stream>>>(conv1_w, wt1);
    cvt_convw<512><<<(int)(((long)CC * 9 * 512 + 255) / 256), blk, 0, stream>>>(conv2_w, wt2);

    // --- zero-init Z accumulators (Za,Zb contiguous carves) ---
    hipMemsetAsync(Za, 0, (size_t)2 * BB * CC * NN * 4, stream);

    // --- weighted (both batches) ---
    gemm_we<<<dim3(2, 29, BB), blk, 0, stream>>>(vat, web, wgtb);

    // --- attention, per batch (S + Pb buffers reused) ---
    for (int b = 0; b < BB; ++b) {
        const u16* wgtb_b = wgtb + (long)b * NR * CC;
        const u16* vbt_b  = vbt + (long)b * NR * CC;
        const u16* vab_b  = vab + (long)b * CC * NP;
        const u16* vbb_b  = vbb + (long)b * CC * NP;
        float* rmx_b = rmx + b * NN; float* rsm_b = rsm + b * NN;
        float* cmx_b = cmx + b * NN; float* csm_b = csm + b * NN;

        gemm_s<<<dim3(29, 29), blk, 0, stream>>>(wgtb_b, vbt_b, S);
        rowstats_kernel<<<dim3(NN), blk, 0, stream>>>(S, rmx_b, rsm_b);
        colstats_part_kernel<<<dim3((NN + 255) / 256, RCH), blk, 0, stream>>>(S, pcm, pcs);
        colstats_comb_kernel<<<dim3((NN + 255) / 256), blk, 0, stream>>>(pcm, pcs, cmx_b, csm_b);
        pb_build<<<dim3(57, 57), blk, 0, stream>>>(S, cmx_b, csm_b, Pb);
        gemm_z_split<<<dim3(29, 4, 2 * ZKS), blk, 0, stream>>>(
            vab_b, vbb_b, Pb, S, rmx_b, rsm_b,
            Zb + (long)b * CC * NN, Za + (long)b * CC * NN);
    }

    // --- gates: per-pixel sigmoid, then transpose-scale to [p][c] bf16 ---
    gate_sig<<<dim3(57, BB), blk, 0, stream>>>(Za, gate_w, sga);
    gate_sig<<<dim3(57, BB), blk, 0, stream>>>(Zb, gate_w, sgb);
    transpose_gate<<<dim3(57, 4, BB), blk, 0, stream>>>(Za, sga, gzaT);
    transpose_gate<<<dim3(57, 4, BB), blk, 0, stream>>>(Zb, sgb, gzbT);

    // --- convs: direct split-K GEMM (partials in dead S region) ---
    conv_direct<768><<<dim3(29, 4, 6), blk, 0, stream>>>(wt1, gzaT, vat, daT, part);
    conv_reduce<<<(int)(((long)BB * CC * NN + 255) / 256), blk, 0, stream>>>(part, y1);
    conv_direct<512><<<dim3(29, 4, 6), blk, 0, stream>>>(wt2, gzbT, vbt, vbt, part);
    conv_reduce<<<(int)(((long)BB * CC * NN + 255) / 256), blk, 0, stream>>>(part, y2);

    // --- BN + cls + resize --- (rmx/rsm/cmx/csm reused as scale/shift)
    bn_stats_kernel<<<256, blk, 0, stream>>>(y1, bn1_g, bn1_b, rmx, rsm);
    bn_stats_kernel<<<256, blk, 0, stream>>>(y2, bn2_g, bn2_b, cmx, csm);
    cls_kernel<<<dim3(57, BB), blk, 0, stream>>>(y1, rmx, rsm, cls1_w, cls1_b, c1o);
    cls_kernel<<<dim3(57, BB), blk, 0, stream>>>(y2, cmx, csm, cls2_w, cls2_b, c2o);

    resize_sig_kernel<<<dim3((int)(((long)BB * NCH * HO * WO + 255) / 256), 2), blk, 0, stream>>>(c1o, c2o, out);
}

// Round 7
// 754.032 us; speedup vs baseline: 4.6370x; 1.0457x over previous
//
#include <hip/hip_runtime.h>

#define BB 2
#define CC 256
#define NN 3600
#define NCH 2
#define HO 473
#define WO 473
#define NP 3648          // NN padded to mult of 64 (K padding)
#define NR 3712          // NN padded to mult of 128 (row padding)
#define LDT 72           // LDS tile row stride in u16 (16B-aligned)
#define NTI 29           // n-tiles of 128 covering NN
#define ZKS 6            // split-K slices for Z/conv GEMMs

typedef unsigned short u16;
typedef __attribute__((ext_vector_type(8))) short short8;
typedef __attribute__((ext_vector_type(4))) float f32x4;

static __device__ __forceinline__ u16 f2bf(float f) {
    unsigned u = __float_as_uint(f);
    unsigned r = (u + 0x7FFF + ((u >> 16) & 1)) >> 16;
    return (u16)r;
}

// ---------------------------------------------------------------------------
// 128x128 bf16 GEMM (gemm_we only): C[m][n] = sum_k A[m][k]*B[n][k], bf16 out
// ---------------------------------------------------------------------------
__global__ __launch_bounds__(256)
void gemm_we(const u16* __restrict__ vat, const u16* __restrict__ web,
             u16* __restrict__ wgtb)
{
    __shared__ u16 As[128 * LDT];
    __shared__ u16 Bs[128 * LDT];
    const u16* A = vat + (long)blockIdx.z * NR * CC;
    u16* Cp = wgtb + (long)blockIdx.z * NR * CC;

    const int t = threadIdx.x;
    const int w = t >> 6, lane = t & 63;
    const int mh = (w >> 1) * 64, nh = (w & 1) * 64;
    const int lm = lane & 15, quad = lane >> 4;
    const int m0 = blockIdx.y * 128, n0 = blockIdx.x * 128;

    f32x4 acc[4][4] = {};

    for (int k0 = 0; k0 < CC; k0 += 64) {
#pragma unroll
        for (int i = 0; i < 4; ++i) {
            int idx = i * 256 + t;
            int row = idx >> 3, c8 = (idx & 7) * 8;
            int rg = m0 + row;
            uint4 v = make_uint4(0u, 0u, 0u, 0u);
            if (rg < NN) v = *(const uint4*)(A + (long)rg * CC + k0 + c8);
            *(uint4*)(&As[row * LDT + c8]) = v;
            uint4 bv = make_uint4(0u, 0u, 0u, 0u);
            if (n0 + row < CC) bv = *(const uint4*)(web + (long)(n0 + row) * CC + k0 + c8);
            *(uint4*)(&Bs[row * LDT + c8]) = bv;
        }
        __syncthreads();
#pragma unroll
        for (int s = 0; s < 2; ++s) {
            short8 a[4], b[4];
#pragma unroll
            for (int i = 0; i < 4; ++i)
                a[i] = *(const short8*)(&As[(mh + i * 16 + lm) * LDT + s * 32 + quad * 8]);
#pragma unroll
            for (int j = 0; j < 4; ++j)
                b[j] = *(const short8*)(&Bs[(nh + j * 16 + lm) * LDT + s * 32 + quad * 8]);
#pragma unroll
            for (int i = 0; i < 4; ++i)
#pragma unroll
                for (int j = 0; j < 4; ++j)
                    acc[i][j] = __builtin_amdgcn_mfma_f32_16x16x32_bf16(a[i], b[j], acc[i][j], 0, 0, 0);
        }
        __syncthreads();
    }
#pragma unroll
    for (int i = 0; i < 4; ++i)
#pragma unroll
        for (int r = 0; r < 4; ++r) {
            int row = m0 + mh + i * 16 + quad * 4 + r;
            if (row < NN)
#pragma unroll
                for (int j = 0; j < 4; ++j) {
                    int col = n0 + nh + j * 16 + lm;
                    if (col < CC) Cp[(long)row * CC + col] = f2bf(acc[i][j][r]);
                }
        }
}

// ---------------------------------------------------------------------------
// S GEMM with fused softmax-stat partials.
// S[n][m] = sum_d wgt[n][d]*VbT[m][d]; tile 128x128, K=256.
// Partials: prowm/prows[bx][n] = max/sumexp over this block's 128 m-cols;
//           pcolm/pcols[by][m] = max/sumexp over this block's 128 n-rows.
// Invalid rows/cols (>= NN) masked exactly.
// ---------------------------------------------------------------------------
__global__ __launch_bounds__(256)
void gemm_s_stats(const u16* __restrict__ A, const u16* __restrict__ B,
                  float* __restrict__ S,
                  float* __restrict__ prowm, float* __restrict__ prows,
                  float* __restrict__ pcolm, float* __restrict__ pcols)
{
    __shared__ u16 As[128 * LDT];
    __shared__ u16 Bs[128 * LDT];

    const int t = threadIdx.x;
    const int w = t >> 6, lane = t & 63;
    const int mh = (w >> 1) * 64, nh = (w & 1) * 64;
    const int lm = lane & 15, quad = lane >> 4;
    const int m0 = blockIdx.y * 128, n0 = blockIdx.x * 128;

    f32x4 acc[4][4] = {};

    for (int k0 = 0; k0 < CC; k0 += 64) {
#pragma unroll
        for (int i = 0; i < 4; ++i) {
            int idx = i * 256 + t;
            int row = idx >> 3, c8 = (idx & 7) * 8;
            uint4 v = make_uint4(0u, 0u, 0u, 0u);
            if (m0 + row < NN) v = *(const uint4*)(A + (long)(m0 + row) * CC + k0 + c8);
            *(uint4*)(&As[row * LDT + c8]) = v;
            uint4 bv = make_uint4(0u, 0u, 0u, 0u);
            if (n0 + row < NN) bv = *(const uint4*)(B + (long)(n0 + row) * CC + k0 + c8);
            *(uint4*)(&Bs[row * LDT + c8]) = bv;
        }
        __syncthreads();
#pragma unroll
        for (int s = 0; s < 2; ++s) {
            short8 a[4], b[4];
#pragma unroll
            for (int i = 0; i < 4; ++i)
                a[i] = *(const short8*)(&As[(mh + i * 16 + lm) * LDT + s * 32 + quad * 8]);
#pragma unroll
            for (int j = 0; j < 4; ++j)
                b[j] = *(const short8*)(&Bs[(nh + j * 16 + lm) * LDT + s * 32 + quad * 8]);
#pragma unroll
            for (int i = 0; i < 4; ++i)
#pragma unroll
                for (int j = 0; j < 4; ++j)
                    acc[i][j] = __builtin_amdgcn_mfma_f32_16x16x32_bf16(a[i], b[j], acc[i][j], 0, 0, 0);
        }
        __syncthreads();
    }

    // store S
#pragma unroll
    for (int i = 0; i < 4; ++i)
#pragma unroll
        for (int r = 0; r < 4; ++r) {
            int row = m0 + mh + i * 16 + quad * 4 + r;
            if (row < NN)
#pragma unroll
                for (int j = 0; j < 4; ++j) {
                    int col = n0 + nh + j * 16 + lm;
                    if (col < NN) S[(long)row * NN + col] = acc[i][j][r];
                }
        }

    // ---- fused stats ----
    bool cval[4];
#pragma unroll
    for (int j = 0; j < 4; ++j) cval[j] = (n0 + nh + j * 16 + lm) < NN;

    float* sm = (float*)As;           // reuse LDS: 4 x [2][128] floats = 4 KB
    float* rowm = sm;                 // [2][128]
    float* rows_ = sm + 256;
    float* colm = sm + 512;
    float* cols_ = sm + 768;
    __syncthreads();

    // row stats (over this block's cols) — reduce over j then lm lanes
#pragma unroll
    for (int i = 0; i < 4; ++i)
#pragma unroll
        for (int r = 0; r < 4; ++r) {
            float m = -3.0e38f;
#pragma unroll
            for (int j = 0; j < 4; ++j) if (cval[j]) m = fmaxf(m, acc[i][j][r]);
            m = fmaxf(m, __shfl_xor(m, 1, 64));
            m = fmaxf(m, __shfl_xor(m, 2, 64));
            m = fmaxf(m, __shfl_xor(m, 4, 64));
            m = fmaxf(m, __shfl_xor(m, 8, 64));
            float s = 0.f;
#pragma unroll
            for (int j = 0; j < 4; ++j) if (cval[j]) s += __expf(acc[i][j][r] - m);
            s += __shfl_xor(s, 1, 64);
            s += __shfl_xor(s, 2, 64);
            s += __shfl_xor(s, 4, 64);
            s += __shfl_xor(s, 8, 64);
            if (lm == 0) {
                int rr = mh + i * 16 + quad * 4 + r;
                rowm[(w & 1) * 128 + rr] = m;
                rows_[(w & 1) * 128 + rr] = s;
            }
        }

    // col stats (over this block's rows) — reduce over i,r then quad lanes
#pragma unroll
    for (int j = 0; j < 4; ++j) {
        float m = -3.0e38f;
#pragma unroll
        for (int i = 0; i < 4; ++i)
#pragma unroll
            for (int r = 0; r < 4; ++r)
                if (m0 + mh + i * 16 + quad * 4 + r < NN) m = fmaxf(m, acc[i][j][r]);
        m = fmaxf(m, __shfl_xor(m, 16, 64));
        m = fmaxf(m, __shfl_xor(m, 32, 64));
        float s = 0.f;
#pragma unroll
        for (int i = 0; i < 4; ++i)
#pragma unroll
            for (int r = 0; r < 4; ++r)
                if (m0 + mh + i * 16 + quad * 4 + r < NN) s += __expf(acc[i][j][r] - m);
        s += __shfl_xor(s, 16, 64);
        s += __shfl_xor(s, 32, 64);
        if (quad == 0) {
            int ccl = nh + j * 16 + lm;
            colm[(w >> 1) * 128 + ccl] = m;
            cols_[(w >> 1) * 128 + ccl] = s;
        }
    }
    __syncthreads();

    if (t < 128) {
        float m1 = rowm[t], m2 = rowm[128 + t];
        float M = fmaxf(m1, m2);
        float s = rows_[t] * __expf(m1 - M) + rows_[128 + t] * __expf(m2 - M);
        if (m0 + t < NN) {
            prowm[(long)blockIdx.x * NR + m0 + t] = M;
            prows[(long)blockIdx.x * NR + m0 + t] = s;
        }
    } else {
        int c = t - 128;
        float m1 = colm[c], m2 = colm[128 + c];
        float M = fmaxf(m1, m2);
        float s = cols_[c] * __expf(m1 - M) + cols_[128 + c] * __expf(m2 - M);
        if (n0 + c < NN) {
            pcolm[(long)blockIdx.y * NR + n0 + c] = M;
            pcols[(long)blockIdx.y * NR + n0 + c] = s;
        }
    }
}

// merge NTI partials -> final stats. dir 0: row (rmx/rsm); dir 1: col (cmx/csm)
__global__ __launch_bounds__(256)
void stats_combine(const float* __restrict__ prowm, const float* __restrict__ prows,
                   const float* __restrict__ pcolm, const float* __restrict__ pcols,
                   float* __restrict__ rmx, float* __restrict__ rsm,
                   float* __restrict__ cmx, float* __restrict__ csm)
{
    int i = blockIdx.x * 256 + threadIdx.x;
    if (i >= NN) return;
    const float* pm = blockIdx.y ? pcolm : prowm;
    const float* ps = blockIdx.y ? pcols : prows;
    float m = -3.0e38f, s = 0.f;
#pragma unroll 4
    for (int tI = 0; tI < NTI; ++tI) {
        float m2 = pm[(long)tI * NR + i], s2 = ps[(long)tI * NR + i];
        float M = fmaxf(m, m2);
        s = s * __expf(m - M) + s2 * __expf(m2 - M);
        m = M;
    }
    if (blockIdx.y) { cmx[i] = m; csm[i] = s; }
    else            { rmx[i] = m; rsm[i] = s; }
}

// ---------------------------------------------------------------------------
// Wide Z GEMM: 256x128 tile, split-K (ZKS uneven slices of 57 k-iters),
// atomicAdd fp32. blockIdx: x = n-tile, y = ks, z = branch (0: Zb=vab.Pb,
// 1: Za=vbb.softmaxrows(S)). C zero-initialized before launch.
// ---------------------------------------------------------------------------
__global__ __launch_bounds__(256)
void gemm_z_wide(const u16* __restrict__ vab_b, const u16* __restrict__ vbb_b,
                 const u16* __restrict__ Pb, const float* __restrict__ S,
                 const float* __restrict__ rmx_b, const float* __restrict__ rsm_b,
                 float* __restrict__ Zb_b, float* __restrict__ Za_b)
{
    __shared__ u16 As[256 * LDT];
    __shared__ u16 Bs[128 * LDT];

    const int t = threadIdx.x;
    const int w = t >> 6, lane = t & 63;
    const int mh = (w >> 1) * 128, nh = (w & 1) * 64;
    const int lm = lane & 15, quad = lane >> 4;
    const int n0 = blockIdx.x * 128;
    const int ks = blockIdx.y;
    const int expb = blockIdx.z;
    const u16* A = expb ? vbb_b : vab_b;
    float* Cp = expb ? Za_b : Zb_b;

    const int base = 57 / ZKS, rem = 57 % ZKS;           // 9, 3
    const int it0 = ks * base + (ks < rem ? ks : rem);
    const int itn = base + (ks < rem ? 1 : 0);

    f32x4 acc[8][4] = {};

    for (int it = it0; it < it0 + itn; ++it) {
        const int k0 = it * 64;
#pragma unroll
        for (int i = 0; i < 8; ++i) {                     // A: 256 rows exact
            int idx = i * 256 + t;
            int row = idx >> 3, c8 = (idx & 7) * 8;
            uint4 v = *(const uint4*)(A + (long)row * NP + k0 + c8);
            *(uint4*)(&As[row * LDT + c8]) = v;
        }
#pragma unroll
        for (int i = 0; i < 4; ++i) {                     // B rows guarded
            int idx = i * 256 + t;
            int row = idx >> 3, c8 = (idx & 7) * 8;
            int rg = n0 + row;
            if (expb) {
                u16 tmp[8] = {0, 0, 0, 0, 0, 0, 0, 0};
                int kg = k0 + c8;
                if (rg < NN && kg < NN) {
                    float mv = rmx_b[rg];
                    float4 v0 = *(const float4*)(S + (long)rg * NN + kg);
                    float4 v1 = *(const float4*)(S + (long)rg * NN + kg + 4);
                    tmp[0] = f2bf(__expf(v0.x - mv)); tmp[1] = f2bf(__expf(v0.y - mv));
                    tmp[2] = f2bf(__expf(v0.z - mv)); tmp[3] = f2bf(__expf(v0.w - mv));
                    tmp[4] = f2bf(__expf(v1.x - mv)); tmp[5] = f2bf(__expf(v1.y - mv));
                    tmp[6] = f2bf(__expf(v1.z - mv)); tmp[7] = f2bf(__expf(v1.w - mv));
                }
                *(uint4*)(&Bs[row * LDT + c8]) = *(const uint4*)tmp;
            } else {
                uint4 v = make_uint4(0u, 0u, 0u, 0u);
                if (rg < NN) v = *(const uint4*)(Pb + (long)rg * NP + k0 + c8);
                *(uint4*)(&Bs[row * LDT + c8]) = v;
            }
        }
        __syncthreads();
#pragma unroll
        for (int s = 0; s < 2; ++s) {
            short8 a[8], b[4];
#pragma unroll
            for (int i = 0; i < 8; ++i)
                a[i] = *(const short8*)(&As[(mh + i * 16 + lm) * LDT + s * 32 + quad * 8]);
#pragma unroll
            for (int j = 0; j < 4; ++j)
                b[j] = *(const short8*)(&Bs[(nh + j * 16 + lm) * LDT + s * 32 + quad * 8]);
#pragma unroll
            for (int i = 0; i < 8; ++i)
#pragma unroll
                for (int j = 0; j < 4; ++j)
                    acc[i][j] = __builtin_amdgcn_mfma_f32_16x16x32_bf16(a[i], b[j], acc[i][j], 0, 0, 0);
        }
        __syncthreads();
    }

    float scl[4] = {1.f, 1.f, 1.f, 1.f};
    if (expb) {
#pragma unroll
        for (int j = 0; j < 4; ++j) {
            int col = n0 + nh + j * 16 + lm;
            if (col < NN) scl[j] = 1.f / rsm_b[col];
        }
    }
#pragma unroll
    for (int i = 0; i < 8; ++i)
#pragma unroll
        for (int r = 0; r < 4; ++r) {
            int row = mh + i * 16 + quad * 4 + r;
#pragma unroll
            for (int j = 0; j < 4; ++j) {
                int col = n0 + nh + j * 16 + lm;
                if (col < NN)
                    atomicAdd(&Cp[(long)row * NN + col], acc[i][j][r] * scl[j]);
            }
        }
}

// ---------------------------------------------------------------------------
// Wide direct conv: 256x128 tile, split-K (even slices), atomicAdd into Y.
// blockIdx: x = p-tile, y = ks (ZKS), z = batch. Y zero-initialized.
// ---------------------------------------------------------------------------
template<int CIN>
__global__ __launch_bounds__(256)
void conv_wide(const u16* __restrict__ W,
               const u16* __restrict__ P0, const u16* __restrict__ P1,
               const u16* __restrict__ P2, float* __restrict__ Y)
{
    const int KT = 9 * CIN;
    __shared__ u16 As[256 * LDT];
    __shared__ u16 Bs[128 * LDT];

    const int t = threadIdx.x;
    const int w = t >> 6, lane = t & 63;
    const int mh = (w >> 1) * 128, nh = (w & 1) * 64;
    const int lm = lane & 15, quad = lane >> 4;
    const int n0 = blockIdx.x * 128;
    const int ks = blockIdx.y, b = blockIdx.z;
    const long pstride = (long)NR * CC;

    const int per = (KT / 64) / ZKS;
    const int it0 = ks * per;

    f32x4 acc[8][4] = {};

    for (int it = it0; it < it0 + per; ++it) {
        const int k0 = it * 64;
        int tap = k0 / CIN;
        int kloc = k0 - tap * CIN;
        int plane = kloc >> 8, cip = kloc & 255;
        int dh = tap / 3 - 1, dw = tap - (tap / 3) * 3 - 1;
        int off = dh * 60 + dw;
        const u16* src = (plane == 0) ? P0 : ((plane == 1) ? P1 : P2);
        src += (long)b * pstride + cip;

#pragma unroll
        for (int i = 0; i < 8; ++i) {                 // A: 256 co rows exact
            int idx = i * 256 + t;
            int row = idx >> 3, c8 = (idx & 7) * 8;
            uint4 v = *(const uint4*)(W + (long)row * KT + k0 + c8);
            *(uint4*)(&As[row * LDT + c8]) = v;
        }
#pragma unroll
        for (int i = 0; i < 4; ++i) {                 // B: shifted plane rows
            int idx = i * 256 + t;
            int row = idx >> 3, c8 = (idx & 7) * 8;
            int p = n0 + row;
            uint4 v = make_uint4(0u, 0u, 0u, 0u);
            if (p < NN) {
                int h = p / 60, wp = p - h * 60;
                int hh = h + dh, wq = wp + dw;
                if (hh >= 0 && hh < 60 && wq >= 0 && wq < 60)
                    v = *(const uint4*)(src + (long)(p + off) * CC + c8);
            }
            *(uint4*)(&Bs[row * LDT + c8]) = v;
        }
        __syncthreads();
#pragma unroll
        for (int s = 0; s < 2; ++s) {
            short8 a[8], bfr[4];
#pragma unroll
            for (int i = 0; i < 8; ++i)
                a[i] = *(const short8*)(&As[(mh + i * 16 + lm) * LDT + s * 32 + quad * 8]);
#pragma unroll
            for (int j = 0; j < 4; ++j)
                bfr[j] = *(const short8*)(&Bs[(nh + j * 16 + lm) * LDT + s * 32 + quad * 8]);
#pragma unroll
            for (int i = 0; i < 8; ++i)
#pragma unroll
                for (int j = 0; j < 4; ++j)
                    acc[i][j] = __builtin_amdgcn_mfma_f32_16x16x32_bf16(a[i], bfr[j], acc[i][j], 0, 0, 0);
        }
        __syncthreads();
    }

    float* out = Y + (long)b * CC * NN;
#pragma unroll
    for (int i = 0; i < 8; ++i)
#pragma unroll
        for (int r = 0; r < 4; ++r) {
            int row = mh + i * 16 + quad * 4 + r;
#pragma unroll
            for (int j = 0; j < 4; ++j) {
                int col = n0 + nh + j * 16 + lm;
                if (col < NN)
                    atomicAdd(&out[(long)row * NN + col], acc[i][j][r]);
            }
        }
}

// ---------------------------------------------------------------------------
// Converters / transposes
// ---------------------------------------------------------------------------
__global__ __launch_bounds__(256)
void cvt_we(const float* __restrict__ W, u16* __restrict__ O)
{
    int i = blockIdx.x * 256 + threadIdx.x;
    if (i < CC * CC) O[i] = f2bf(W[i]);
}

__global__ __launch_bounds__(256)
void cvt_pad(const float* __restrict__ src, u16* __restrict__ dst, int R)
{
    long idx = (long)blockIdx.x * 256 + threadIdx.x;
    if (idx >= (long)R * NP) return;
    int j = (int)(idx % NP);
    long r = idx / NP;
    dst[idx] = (j < NN) ? f2bf(src[r * NN + j]) : (u16)0;
}

// V [b][256][3600] fp32 -> VT [b][3712][256] bf16
__global__ __launch_bounds__(256)
void transpose_cvt(const float* __restrict__ V, u16* __restrict__ VT)
{
    __shared__ float tile[64][65];
    int b = blockIdx.z, c0 = blockIdx.y * 64, n0 = blockIdx.x * 64;
    int t = threadIdx.x;
#pragma unroll
    for (int e = 0; e < 16; ++e) {
        int f = e * 256 + t; int i = f >> 6, j = f & 63;
        int n = n0 + j;
        float v = 0.f;
        if (n < NN) v = V[((long)b * CC + c0 + i) * NN + n];
        tile[i][j] = v;
    }
    __syncthreads();
#pragma unroll
    for (int e = 0; e < 16; ++e) {
        int f = e * 256 + t; int i = f >> 6, j = f & 63;
        int n = n0 + i;
        if (n < NN) VT[((long)b * NR + n) * CC + c0 + j] = f2bf(tile[j][i]);
    }
}

// Z fp32 [b][c][p] * sg[b][p] -> ZT bf16 [b][p][c]
__global__ __launch_bounds__(256)
void transpose_gate(const float* __restrict__ Z, const float* __restrict__ sg,
                    u16* __restrict__ ZT)
{
    __shared__ float tile[64][65];
    int b = blockIdx.z, c0 = blockIdx.y * 64, n0 = blockIdx.x * 64;
    int t = threadIdx.x;
#pragma unroll
    for (int e = 0; e < 16; ++e) {
        int f = e * 256 + t; int i = f >> 6, j = f & 63;
        int n = n0 + j;
        float v = 0.f;
        if (n < NN) v = Z[((long)b * CC + c0 + i) * NN + n];
        tile[i][j] = v;
    }
    __syncthreads();
#pragma unroll
    for (int e = 0; e < 16; ++e) {
        int f = e * 256 + t; int i = f >> 6, j = f & 63;
        int n = n0 + i;
        if (n < NN)
            ZT[((long)b * NR + n) * CC + c0 + j] = f2bf(tile[j][i] * sg[b * NN + n]);
    }
}

template<int CIN>
__global__ __launch_bounds__(256)
void cvt_convw(const float* __restrict__ W, u16* __restrict__ O)
{
    const int KT = 9 * CIN;
    long idx = (long)blockIdx.x * 256 + threadIdx.x;
    if (idx >= (long)CC * KT) return;
    int co = (int)(idx / KT);
    int r = (int)(idx % KT);
    int tap = r / CIN, ci = r % CIN;
    O[idx] = f2bf(W[((long)co * CIN + ci) * 9 + tap]);
}

// Pb[m][n] = exp(S[n][m]-cmax[m])/csum[m], bf16, cols padded to NP with 0
__global__ __launch_bounds__(256)
void pb_build(const float* __restrict__ S, const float* __restrict__ cmx,
              const float* __restrict__ csm, u16* __restrict__ Pb)
{
    __shared__ float tile[64][65];
    int m0 = blockIdx.y * 64;
    int n0 = blockIdx.x * 64;
    int t = threadIdx.x;
#pragma unroll
    for (int e = 0; e < 16; ++e) {
        int f = e * 256 + t; int i = f >> 6, j = f & 63;
        int n = n0 + i, m = m0 + j;
        float v = 0.f;
        if (n < NN && m < NN)
            v = __expf(S[(long)n * NN + m] - cmx[m]) * (1.f / csm[m]);
        tile[j][i] = v;
    }
    __syncthreads();
#pragma unroll
    for (int e = 0; e < 16; ++e) {
        int f = e * 256 + t; int i = f >> 6, j = f & 63;
        int m = m0 + i;
        if (m < NN) Pb[(long)m * NP + n0 + j] = f2bf(tile[i][j]);
    }
}

// ---------------------------------------------------------------------------
// Per-pixel gate sigmoid: sg[b][p] = sigmoid(sum_c gw[c]*Z[c,p])
// ---------------------------------------------------------------------------
__global__ __launch_bounds__(256)
void gate_sig(const float* __restrict__ Z, const float* __restrict__ gw,
              float* __restrict__ sg)
{
    int t = threadIdx.x;
    int px = t & 63, ck = t >> 6;
    int b = blockIdx.y;
    int p = blockIdx.x * 64 + px;
    const float* Zp = Z + (long)b * CC * NN;
    float g = 0.f;
    if (p < NN) {
        for (int c = ck * 64; c < ck * 64 + 64; ++c) g += gw[c] * Zp[(long)c * NN + p];
    }
    __shared__ float red[256];
    red[t] = g;
    __syncthreads();
    if (t < 64) {
        int pp = blockIdx.x * 64 + t;
        if (pp < NN) {
            float tot = red[t] + red[t + 64] + red[t + 128] + red[t + 192];
            sg[b * NN + pp] = 1.f / (1.f + __expf(-tot));
        }
    }
}

// ---------------------------------------------------------------------------
// BatchNorm batch-stats -> scale/shift
// ---------------------------------------------------------------------------
__global__ __launch_bounds__(256)
void bn_stats_kernel(const float* __restrict__ Y, const float* __restrict__ g,
                     const float* __restrict__ beta, float* __restrict__ scale,
                     float* __restrict__ shift)
{
    int c = blockIdx.x, t = threadIdx.x;
    float s = 0.f, sq = 0.f;
    for (int b = 0; b < BB; ++b) {
        const float* p = Y + (long)b * CC * NN + (long)c * NN;
        for (int i = t; i < NN; i += 256) { float v = p[i]; s += v; sq += v * v; }
    }
    __shared__ float ls[256], lq[256];
    ls[t] = s; lq[t] = sq;
    __syncthreads();
    for (int off = 128; off > 0; off >>= 1) {
        if (t < off) { ls[t] += ls[t + off]; lq[t] += lq[t + off]; }
        __syncthreads();
    }
    if (t == 0) {
        const float inv = 1.f / (float)(BB * NN);
        float mean = ls[0] * inv;
        float var = fmaxf(lq[0] * inv - mean * mean, 0.f);
        float sc = g[c] * rsqrtf(var + 1e-5f);
        scale[c] = sc;
        shift[c] = beta[c] - mean * sc;
    }
}

// ---------------------------------------------------------------------------
// Fused BN-normalize + ReLU + 1x1 cls conv + bias
// ---------------------------------------------------------------------------
__global__ __launch_bounds__(256)
void cls_kernel(const float* __restrict__ Y, const float* __restrict__ scale,
                const float* __restrict__ shift, const float* __restrict__ cw,
                const float* __restrict__ cb, float* __restrict__ O)
{
    int t = threadIdx.x;
    int px = t & 63, ck = t >> 6;
    int b = blockIdx.y;
    int p = blockIdx.x * 64 + px;
    const float* Yb = Y + (long)b * CC * NN;
    float a0 = 0.f, a1 = 0.f;
    if (p < NN) {
        for (int c = ck * 64; c < ck * 64 + 64; ++c) {
            float v = Yb[(long)c * NN + p] * scale[c] + shift[c];
            v = fmaxf(v, 0.f);
            a0 += cw[c] * v;
            a1 += cw[CC + c] * v;
        }
    }
    __shared__ float r0[256], r1[256];
    r0[t] = a0; r1[t] = a1;
    __syncthreads();
    if (t < 64) {
        int pp = blockIdx.x * 64 + t;
        if (pp < NN) {
            float s0 = r0[t] + r0[t + 64] + r0[t + 128] + r0[t + 192];
            float s1 = r1[t] + r1[t + 64] + r1[t + 128] + r1[t + 192];
            O[(long)b * NCH * NN + pp] = s0 + cb[0];
            O[(long)b * NCH * NN + NN + pp] = s1 + cb[1];
        }
    }
}

// ---------------------------------------------------------------------------
// Bilinear resize 60x60 -> 473x473 (half-pixel, clamp) + sigmoid
// ---------------------------------------------------------------------------
__global__ __launch_bounds__(256)
void resize_sig_kernel(const float* __restrict__ I1, const float* __restrict__ I2,
                       float* __restrict__ O)
{
    const long HALF = (long)BB * NCH * HO * WO;
    long gid = (long)blockIdx.x * 256 + threadIdx.x;
    if (gid >= HALF) return;
    int half = blockIdx.y;
    const float* I = half ? I2 : I1;
    float* Op = O + half * HALF;

    int j = (int)(gid % WO);
    long r = gid / WO;
    int i = (int)(r % HO);
    int pc = (int)(r / HO);
    const float* ip = I + (long)pc * NN;

    const float SCL = 60.0f / 473.0f;
    float fy = (i + 0.5f) * SCL - 0.5f;
    float fx = (j + 0.5f) * SCL - 0.5f;
    int y0 = (int)floorf(fy);
    int x0 = (int)floorf(fx);
    float ty = fy - (float)y0;
    float tx = fx - (float)x0;
    int y0c = max(y0, 0), y1c = min(y0 + 1, 59);
    int x0c = max(x0, 0), x1c = min(x0 + 1, 59);
    float va = ip[y0c * 60 + x0c], vb = ip[y0c * 60 + x1c];
    float vc = ip[y1c * 60 + x0c], vd = ip[y1c * 60 + x1c];
    float v = (1.f - ty) * ((1.f - tx) * va + tx * vb) + ty * ((1.f - tx) * vc + tx * vd);
    Op[gid] = 1.f / (1.f + __expf(-v));
}

// ---------------------------------------------------------------------------
extern "C" void kernel_launch(void* const* d_in, const int* in_sizes, int n_in,
                              void* d_out, int out_size, void* d_ws, size_t ws_size,
                              hipStream_t stream)
{
    const float* V_a    = (const float*)d_in[0];
    const float* V_b    = (const float*)d_in[1];
    const float* D_a    = (const float*)d_in[2];
    const float* W_e    = (const float*)d_in[3];
    const float* gate_w = (const float*)d_in[4];
    const float* conv1_w = (const float*)d_in[5];
    const float* conv2_w = (const float*)d_in[6];
    const float* bn1_g = (const float*)d_in[7];
    const float* bn1_b = (const float*)d_in[8];
    const float* bn2_g = (const float*)d_in[9];
    const float* bn2_b = (const float*)d_in[10];
    const float* cls1_w = (const float*)d_in[11];
    const float* cls1_b = (const float*)d_in[12];
    const float* cls2_w = (const float*)d_in[13];
    const float* cls2_b = (const float*)d_in[14];
    float* out = (float*)d_out;

    // ---- workspace arena: ~147 MB (known-safe bound: 154.9 MB) ----
    size_t off = 0;
    char* wsb = (char*)d_ws;
    auto carve = [&](size_t bytes) -> char* {
        char* p = wsb + off; off += (bytes + 255) & ~(size_t)255; return p;
    };

    float* S   = (float*)carve((size_t)NN * NN * 4);       // 51.8 MB, per-batch
    u16* Pb    = (u16*)carve((size_t)NR * NP * 2);         // 27.1 MB, per-batch
    u16* vab   = (u16*)carve((size_t)BB * CC * NP * 2);
    u16* vbb   = (u16*)carve((size_t)BB * CC * NP * 2);
    u16* vat   = (u16*)carve((size_t)BB * NR * CC * 2);
    u16* vbt   = (u16*)carve((size_t)BB * NR * CC * 2);
    u16* daT   = (u16*)carve((size_t)BB * NR * CC * 2);
    u16* gzaT  = (u16*)carve((size_t)BB * NR * CC * 2);
    u16* gzbT  = (u16*)carve((size_t)BB * NR * CC * 2);
    u16* wgtb  = (u16*)carve((size_t)BB * NR * CC * 2);
    u16* web   = (u16*)carve((size_t)CC * CC * 2);
    u16* wt1   = (u16*)carve((size_t)CC * 9 * 768 * 2);
    u16* wt2   = (u16*)carve((size_t)CC * 9 * 512 * 2);
    float* Za  = (float*)carve((size_t)BB * CC * NN * 4);  // contiguous 4-block
    float* Zb  = (float*)carve((size_t)BB * CC * NN * 4);  //   memset region
    float* y1  = (float*)carve((size_t)BB * CC * NN * 4);
    float* y2  = (float*)carve((size_t)BB * CC * NN * 4);
    float* rmx = (float*)carve((size_t)BB * NN * 4);
    float* rsm = (float*)carve((size_t)BB * NN * 4);
    float* cmx = (float*)carve((size_t)BB * NN * 4);
    float* csm = (float*)carve((size_t)BB * NN * 4);
    float* sga = (float*)carve((size_t)BB * NN * 4);
    float* sgb = (float*)carve((size_t)BB * NN * 4);
    float* prm = (float*)carve((size_t)NTI * NR * 4);
    float* prs = (float*)carve((size_t)NTI * NR * 4);
    float* pcm = (float*)carve((size_t)NTI * NR * 4);
    float* pcs = (float*)carve((size_t)NTI * NR * 4);
    float* c1o = (float*)carve((size_t)BB * NCH * NN * 4);
    float* c2o = (float*)carve((size_t)BB * NCH * NN * 4);

    dim3 blk(256);

    // zero-init all atomic accumulators (Za,Zb,y1,y2 contiguous)
    hipMemsetAsync(Za, 0, (size_t)4 * BB * CC * NN * 4, stream);

    // --- input conversions ---
    cvt_we<<<256, blk, 0, stream>>>(W_e, web);
    cvt_pad<<<(int)(((long)BB * CC * NP + 255) / 256), blk, 0, stream>>>(V_a, vab, BB * CC);
    cvt_pad<<<(int)(((long)BB * CC * NP + 255) / 256), blk, 0, stream>>>(V_b, vbb, BB * CC);
    transpose_cvt<<<dim3(57, 4, BB), blk, 0, stream>>>(V_a, vat);
    transpose_cvt<<<dim3(57, 4, BB), blk, 0, stream>>>(V_b, vbt);
    transpose_cvt<<<dim3(57, 4, BB), blk, 0, stream>>>(D_a, daT);
    cvt_convw<768><<<(int)(((long)CC * 9 * 768 + 255) / 256), blk, 0, stream>>>(conv1_w, wt1);
    cvt_convw<512><<<(int)(((long)CC * 9 * 512 + 255) / 256), blk, 0, stream>>>(conv2_w, wt2);

    // --- weighted (both batches) ---
    gemm_we<<<dim3(2, NTI, BB), blk, 0, stream>>>(vat, web, wgtb);

    // --- attention, per batch ---
    for (int b = 0; b < BB; ++b) {
        const u16* wgtb_b = wgtb + (long)b * NR * CC;
        const u16* vbt_b  = vbt + (long)b * NR * CC;
        const u16* vab_b  = vab + (long)b * CC * NP;
        const u16* vbb_b  = vbb + (long)b * CC * NP;
        float* rmx_b = rmx + b * NN; float* rsm_b = rsm + b * NN;
        float* cmx_b = cmx + b * NN; float* csm_b = csm + b * NN;

        gemm_s_stats<<<dim3(NTI, NTI), blk, 0, stream>>>(
            wgtb_b, vbt_b, S, prm, prs, pcm, pcs);
        stats_combine<<<dim3((NN + 255) / 256, 2), blk, 0, stream>>>(
            prm, prs, pcm, pcs, rmx_b, rsm_b, cmx_b, csm_b);
        pb_build<<<dim3(57, 57), blk, 0, stream>>>(S, cmx_b, csm_b, Pb);
        gemm_z_wide<<<dim3(NTI, ZKS, 2), blk, 0, stream>>>(
            vab_b, vbb_b, Pb, S, rmx_b, rsm_b,
            Zb + (long)b * CC * NN, Za + (long)b * CC * NN);
    }

    // --- gates: per-pixel sigmoid, then transpose-scale to [p][c] bf16 ---
    gate_sig<<<dim3(57, BB), blk, 0, stream>>>(Za, gate_w, sga);
    gate_sig<<<dim3(57, BB), blk, 0, stream>>>(Zb, gate_w, sgb);
    transpose_gate<<<dim3(57, 4, BB), blk, 0, stream>>>(Za, sga, gzaT);
    transpose_gate<<<dim3(57, 4, BB), blk, 0, stream>>>(Zb, sgb, gzbT);

    // --- convs: wide direct split-K GEMM, atomic into y1/y2 ---
    conv_wide<768><<<dim3(NTI, ZKS, BB), blk, 0, stream>>>(wt1, gzaT, vat, daT, y1);
    conv_wide<512><<<dim3(NTI, ZKS, BB), blk, 0, stream>>>(wt2, gzbT, vbt, vbt, y2);

    // --- BN + cls + resize --- (rmx/rsm/cmx/csm reused as scale/shift)
    bn_stats_kernel<<<256, blk, 0, stream>>>(y1, bn1_g, bn1_b, rmx, rsm);
    bn_stats_kernel<<<256, blk, 0, stream>>>(y2, bn2_g, bn2_b, cmx, csm);
    cls_kernel<<<dim3(57, BB), blk, 0, stream>>>(y1, rmx, rsm, cls1_w, cls1_b, c1o);
    cls_kernel<<<dim3(57, BB), blk, 0, stream>>>(y2, cmx, csm, cls2_w, cls2_b, c2o);

    resize_sig_kernel<<<dim3((int)(((long)BB * NCH * HO * WO + 255) / 256), 2), blk, 0, stream>>>(c1o, c2o, out);
}

// Round 8
// 730.954 us; speedup vs baseline: 4.7834x; 1.0316x over previous
//
#include <hip/hip_runtime.h>

#define BB 2
#define CC 256
#define NN 3600
#define NCH 2
#define HO 473
#define WO 473
#define NP 3648          // NN padded to mult of 64 (K/stride padding)
#define NR 3712          // NN padded to mult of 128 (row padding)
#define LDT 72           // LDS tile row stride in u16 (16B-aligned)
#define NTI 29           // tiles of 128 covering NN
#define ZKS 6            // split-K slices for Z/conv GEMMs

typedef unsigned short u16;
typedef __attribute__((ext_vector_type(8))) short short8;
typedef __attribute__((ext_vector_type(4))) float f32x4;

static __device__ __forceinline__ u16 f2bf(float f) {
    unsigned u = __float_as_uint(f);
    unsigned r = (u + 0x7FFF + ((u >> 16) & 1)) >> 16;
    return (u16)r;
}
static __device__ __forceinline__ u16 f2h(float f) {
    _Float16 h = (_Float16)f;
    return __builtin_bit_cast(unsigned short, h);
}
static __device__ __forceinline__ float h2f(u16 u) {
    _Float16 h = __builtin_bit_cast(_Float16, u);
    return (float)h;
}

// ---------------------------------------------------------------------------
// 128x128 bf16 GEMM (gemm_we only): C[m][n] = sum_k A[m][k]*B[n][k], bf16 out
// ---------------------------------------------------------------------------
__global__ __launch_bounds__(256)
void gemm_we(const u16* __restrict__ vat, const u16* __restrict__ web,
             u16* __restrict__ wgtb)
{
    __shared__ u16 As[128 * LDT];
    __shared__ u16 Bs[128 * LDT];
    const u16* A = vat + (long)blockIdx.z * NR * CC;
    u16* Cp = wgtb + (long)blockIdx.z * NR * CC;

    const int t = threadIdx.x;
    const int w = t >> 6, lane = t & 63;
    const int mh = (w >> 1) * 64, nh = (w & 1) * 64;
    const int lm = lane & 15, quad = lane >> 4;
    const int m0 = blockIdx.y * 128, n0 = blockIdx.x * 128;

    f32x4 acc[4][4] = {};

    for (int k0 = 0; k0 < CC; k0 += 64) {
#pragma unroll
        for (int i = 0; i < 4; ++i) {
            int idx = i * 256 + t;
            int row = idx >> 3, c8 = (idx & 7) * 8;
            int rg = m0 + row;
            uint4 v = make_uint4(0u, 0u, 0u, 0u);
            if (rg < NN) v = *(const uint4*)(A + (long)rg * CC + k0 + c8);
            *(uint4*)(&As[row * LDT + c8]) = v;
            uint4 bv = make_uint4(0u, 0u, 0u, 0u);
            if (n0 + row < CC) bv = *(const uint4*)(web + (long)(n0 + row) * CC + k0 + c8);
            *(uint4*)(&Bs[row * LDT + c8]) = bv;
        }
        __syncthreads();
#pragma unroll
        for (int s = 0; s < 2; ++s) {
            short8 a[4], b[4];
#pragma unroll
            for (int i = 0; i < 4; ++i)
                a[i] = *(const short8*)(&As[(mh + i * 16 + lm) * LDT + s * 32 + quad * 8]);
#pragma unroll
            for (int j = 0; j < 4; ++j)
                b[j] = *(const short8*)(&Bs[(nh + j * 16 + lm) * LDT + s * 32 + quad * 8]);
#pragma unroll
            for (int i = 0; i < 4; ++i)
#pragma unroll
                for (int j = 0; j < 4; ++j)
                    acc[i][j] = __builtin_amdgcn_mfma_f32_16x16x32_bf16(a[i], b[j], acc[i][j], 0, 0, 0);
        }
        __syncthreads();
    }
#pragma unroll
    for (int i = 0; i < 4; ++i)
#pragma unroll
        for (int r = 0; r < 4; ++r) {
            int row = m0 + mh + i * 16 + quad * 4 + r;
            if (row < NN)
#pragma unroll
                for (int j = 0; j < 4; ++j) {
                    int col = n0 + nh + j * 16 + lm;
                    if (col < CC) Cp[(long)row * CC + col] = f2bf(acc[i][j][r]);
                }
        }
}

// ---------------------------------------------------------------------------
// S GEMM with fused softmax-stat partials + dual fp16 output (S and S^T).
// S[n][m] = sum_d wgt[n][d]*VbT[m][d]; tile 128x128, K=256.
// Sh[n][m] fp16 (stride NP); STh[m][n] fp16 (stride NP, via LDS transpose).
// Partials: prowm/prows[bx][n]; pcolm/pcols[by][m]. Invalid indices masked.
// ---------------------------------------------------------------------------
__global__ __launch_bounds__(256)
void gemm_s_stats(const u16* __restrict__ A, const u16* __restrict__ B,
                  u16* __restrict__ Sh, u16* __restrict__ STh,
                  float* __restrict__ prowm, float* __restrict__ prows,
                  float* __restrict__ pcolm, float* __restrict__ pcols)
{
    __shared__ u16 smem[2 * 128 * LDT];     // As | Bs; reused as scratch later
    u16* As = smem;
    u16* Bs = smem + 128 * LDT;

    const int t = threadIdx.x;
    const int w = t >> 6, lane = t & 63;
    const int mh = (w >> 1) * 64, nh = (w & 1) * 64;
    const int lm = lane & 15, quad = lane >> 4;
    const int m0 = blockIdx.y * 128, n0 = blockIdx.x * 128;

    f32x4 acc[4][4] = {};

    for (int k0 = 0; k0 < CC; k0 += 64) {
#pragma unroll
        for (int i = 0; i < 4; ++i) {
            int idx = i * 256 + t;
            int row = idx >> 3, c8 = (idx & 7) * 8;
            uint4 v = make_uint4(0u, 0u, 0u, 0u);
            if (m0 + row < NN) v = *(const uint4*)(A + (long)(m0 + row) * CC + k0 + c8);
            *(uint4*)(&As[row * LDT + c8]) = v;
            uint4 bv = make_uint4(0u, 0u, 0u, 0u);
            if (n0 + row < NN) bv = *(const uint4*)(B + (long)(n0 + row) * CC + k0 + c8);
            *(uint4*)(&Bs[row * LDT + c8]) = bv;
        }
        __syncthreads();
#pragma unroll
        for (int s = 0; s < 2; ++s) {
            short8 a[4], b[4];
#pragma unroll
            for (int i = 0; i < 4; ++i)
                a[i] = *(const short8*)(&As[(mh + i * 16 + lm) * LDT + s * 32 + quad * 8]);
#pragma unroll
            for (int j = 0; j < 4; ++j)
                b[j] = *(const short8*)(&Bs[(nh + j * 16 + lm) * LDT + s * 32 + quad * 8]);
#pragma unroll
            for (int i = 0; i < 4; ++i)
#pragma unroll
                for (int j = 0; j < 4; ++j)
                    acc[i][j] = __builtin_amdgcn_mfma_f32_16x16x32_bf16(a[i], b[j], acc[i][j], 0, 0, 0);
        }
        __syncthreads();
    }

    // store S (fp16, row n contiguous in m)
#pragma unroll
    for (int i = 0; i < 4; ++i)
#pragma unroll
        for (int r = 0; r < 4; ++r) {
            int row = m0 + mh + i * 16 + quad * 4 + r;
            if (row < NN)
#pragma unroll
                for (int j = 0; j < 4; ++j) {
                    int col = n0 + nh + j * 16 + lm;
                    if (col < NN) Sh[(long)row * NP + col] = f2h(acc[i][j][r]);
                }
        }

    // ---- fused stats ----
    bool cval[4];
#pragma unroll
    for (int j = 0; j < 4; ++j) cval[j] = (n0 + nh + j * 16 + lm) < NN;

    float* sm = (float*)smem;         // 4 x [2][128] floats = 4 KB
    float* rowm = sm;
    float* rows_ = sm + 256;
    float* colm = sm + 512;
    float* cols_ = sm + 768;
    __syncthreads();

    // row stats (over this block's cols)
#pragma unroll
    for (int i = 0; i < 4; ++i)
#pragma unroll
        for (int r = 0; r < 4; ++r) {
            float m = -3.0e38f;
#pragma unroll
            for (int j = 0; j < 4; ++j) if (cval[j]) m = fmaxf(m, acc[i][j][r]);
            m = fmaxf(m, __shfl_xor(m, 1, 64));
            m = fmaxf(m, __shfl_xor(m, 2, 64));
            m = fmaxf(m, __shfl_xor(m, 4, 64));
            m = fmaxf(m, __shfl_xor(m, 8, 64));
            float s = 0.f;
#pragma unroll
            for (int j = 0; j < 4; ++j) if (cval[j]) s += __expf(acc[i][j][r] - m);
            s += __shfl_xor(s, 1, 64);
            s += __shfl_xor(s, 2, 64);
            s += __shfl_xor(s, 4, 64);
            s += __shfl_xor(s, 8, 64);
            if (lm == 0) {
                int rr = mh + i * 16 + quad * 4 + r;
                rowm[(w & 1) * 128 + rr] = m;
                rows_[(w & 1) * 128 + rr] = s;
            }
        }

    // col stats (over this block's rows)
#pragma unroll
    for (int j = 0; j < 4; ++j) {
        float m = -3.0e38f;
#pragma unroll
        for (int i = 0; i < 4; ++i)
#pragma unroll
            for (int r = 0; r < 4; ++r)
                if (m0 + mh + i * 16 + quad * 4 + r < NN) m = fmaxf(m, acc[i][j][r]);
        m = fmaxf(m, __shfl_xor(m, 16, 64));
        m = fmaxf(m, __shfl_xor(m, 32, 64));
        float s = 0.f;
#pragma unroll
        for (int i = 0; i < 4; ++i)
#pragma unroll
            for (int r = 0; r < 4; ++r)
                if (m0 + mh + i * 16 + quad * 4 + r < NN) s += __expf(acc[i][j][r] - m);
        s += __shfl_xor(s, 16, 64);
        s += __shfl_xor(s, 32, 64);
        if (quad == 0) {
            int ccl = nh + j * 16 + lm;
            colm[(w >> 1) * 128 + ccl] = m;
            cols_[(w >> 1) * 128 + ccl] = s;
        }
    }
    __syncthreads();

    if (t < 128) {
        float m1 = rowm[t], m2 = rowm[128 + t];
        float M = fmaxf(m1, m2);
        float s = rows_[t] * __expf(m1 - M) + rows_[128 + t] * __expf(m2 - M);
        if (m0 + t < NN) {
            prowm[(long)blockIdx.x * NR + m0 + t] = M;
            prows[(long)blockIdx.x * NR + m0 + t] = s;
        }
    } else {
        int c = t - 128;
        float m1 = colm[c], m2 = colm[128 + c];
        float M = fmaxf(m1, m2);
        float s = cols_[c] * __expf(m1 - M) + cols_[128 + c] * __expf(m2 - M);
        if (n0 + c < NN) {
            pcolm[(long)blockIdx.y * NR + n0 + c] = M;
            pcols[(long)blockIdx.y * NR + n0 + c] = s;
        }
    }

    // ---- S^T via LDS transpose: tr[m_local][n_local], stride 136 ----
    __syncthreads();
    u16* tr = smem;                   // 128*136 u16 = 33.8 KB <= 36.9 KB
#pragma unroll
    for (int i = 0; i < 4; ++i)
#pragma unroll
        for (int j = 0; j < 4; ++j)
#pragma unroll
            for (int r = 0; r < 4; ++r)
                tr[(nh + j * 16 + lm) * 136 + (mh + i * 16 + quad * 4 + r)] = f2h(acc[i][j][r]);
    __syncthreads();
    {
        int row = t >> 1, hf = t & 1;       // row = m-local, 64 cols per thread
        int mg = n0 + row;
        if (mg < NN) {
#pragma unroll
            for (int q = 0; q < 8; ++q) {
                int cb = m0 + hf * 64 + q * 8;
                if (cb < NN)
                    *(uint4*)(&STh[(long)mg * NP + cb]) =
                        *(const uint4*)(&tr[row * 136 + hf * 64 + q * 8]);
            }
        }
    }
}

// merge NTI partials -> final stats. y=0: row (rmx/rsm); y=1: col (cmx/csm)
__global__ __launch_bounds__(256)
void stats_combine(const float* __restrict__ prowm, const float* __restrict__ prows,
                   const float* __restrict__ pcolm, const float* __restrict__ pcols,
                   float* __restrict__ rmx, float* __restrict__ rsm,
                   float* __restrict__ cmx, float* __restrict__ csm)
{
    int i = blockIdx.x * 256 + threadIdx.x;
    if (i >= NN) return;
    const float* pm = blockIdx.y ? pcolm : prowm;
    const float* ps = blockIdx.y ? pcols : prows;
    float m = -3.0e38f, s = 0.f;
#pragma unroll 4
    for (int tI = 0; tI < NTI; ++tI) {
        float m2 = pm[(long)tI * NR + i], s2 = ps[(long)tI * NR + i];
        float M = fmaxf(m, m2);
        s = s * __expf(m - M) + s2 * __expf(m2 - M);
        m = M;
    }
    if (blockIdx.y) { cmx[i] = m; csm[i] = s; }
    else            { rmx[i] = m; rsm[i] = s; }
}

// ---------------------------------------------------------------------------
// Wide Z GEMM: 256x128 tile, split-K, atomicAdd fp32. Unified branches:
// z=0: Zb = vab . exp(ST rows - cmx)/csm ; z=1: Za = vbb . exp(S rows - rmx)/rsm
// blockIdx: x = n-tile, y = ks, z = branch. C zero-initialized before launch.
// ---------------------------------------------------------------------------
__global__ __launch_bounds__(256)
void gemm_z_wide(const u16* __restrict__ vab_b, const u16* __restrict__ vbb_b,
                 const u16* __restrict__ STh, const u16* __restrict__ Sh,
                 const float* __restrict__ cmx_b, const float* __restrict__ csm_b,
                 const float* __restrict__ rmx_b, const float* __restrict__ rsm_b,
                 float* __restrict__ Zb_b, float* __restrict__ Za_b)
{
    __shared__ u16 As[256 * LDT];
    __shared__ u16 Bs[128 * LDT];

    const int t = threadIdx.x;
    const int w = t >> 6, lane = t & 63;
    const int mh = (w >> 1) * 128, nh = (w & 1) * 64;
    const int lm = lane & 15, quad = lane >> 4;
    const int n0 = blockIdx.x * 128;
    const int ks = blockIdx.y;
    const int expb = blockIdx.z;
    const u16* A = expb ? vbb_b : vab_b;
    const u16* P = expb ? Sh : STh;
    const float* mx = expb ? rmx_b : cmx_b;
    const float* sm = expb ? rsm_b : csm_b;
    float* Cp = expb ? Za_b : Zb_b;

    const int base = 57 / ZKS, rem = 57 % ZKS;           // 9, 3
    const int it0 = ks * base + (ks < rem ? ks : rem);
    const int itn = base + (ks < rem ? 1 : 0);

    f32x4 acc[8][4] = {};

    for (int it = it0; it < it0 + itn; ++it) {
        const int k0 = it * 64;
#pragma unroll
        for (int i = 0; i < 8; ++i) {                     // A: 256 rows exact
            int idx = i * 256 + t;
            int row = idx >> 3, c8 = (idx & 7) * 8;
            uint4 v = *(const uint4*)(A + (long)row * NP + k0 + c8);
            *(uint4*)(&As[row * LDT + c8]) = v;
        }
#pragma unroll
        for (int i = 0; i < 4; ++i) {                     // B: exp(fp16 - mx)
            int idx = i * 256 + t;
            int row = idx >> 3, c8 = (idx & 7) * 8;
            int rg = n0 + row;
            int kg = k0 + c8;
            u16 tmp[8] = {0, 0, 0, 0, 0, 0, 0, 0};
            if (rg < NN && kg < NN) {
                float mv = mx[rg];
                uint4 hv = *(const uint4*)(P + (long)rg * NP + kg);
                const u16* hp = (const u16*)&hv;
#pragma unroll
                for (int e = 0; e < 8; ++e)
                    tmp[e] = f2bf(__expf(h2f(hp[e]) - mv));
            }
            *(uint4*)(&Bs[row * LDT + c8]) = *(const uint4*)tmp;
        }
        __syncthreads();
#pragma unroll
        for (int s = 0; s < 2; ++s) {
            short8 a[8], b[4];
#pragma unroll
            for (int i = 0; i < 8; ++i)
                a[i] = *(const short8*)(&As[(mh + i * 16 + lm) * LDT + s * 32 + quad * 8]);
#pragma unroll
            for (int j = 0; j < 4; ++j)
                b[j] = *(const short8*)(&Bs[(nh + j * 16 + lm) * LDT + s * 32 + quad * 8]);
#pragma unroll
            for (int i = 0; i < 8; ++i)
#pragma unroll
                for (int j = 0; j < 4; ++j)
                    acc[i][j] = __builtin_amdgcn_mfma_f32_16x16x32_bf16(a[i], b[j], acc[i][j], 0, 0, 0);
        }
        __syncthreads();
    }

    float scl[4] = {1.f, 1.f, 1.f, 1.f};
#pragma unroll
    for (int j = 0; j < 4; ++j) {
        int col = n0 + nh + j * 16 + lm;
        if (col < NN) scl[j] = 1.f / sm[col];
    }
#pragma unroll
    for (int i = 0; i < 8; ++i)
#pragma unroll
        for (int r = 0; r < 4; ++r) {
            int row = mh + i * 16 + quad * 4 + r;
#pragma unroll
            for (int j = 0; j < 4; ++j) {
                int col = n0 + nh + j * 16 + lm;
                if (col < NN)
                    atomicAdd(&Cp[(long)row * NN + col], acc[i][j][r] * scl[j]);
            }
        }
}

// ---------------------------------------------------------------------------
// Wide direct conv: 256x128 tile, split-K (even slices), atomicAdd into Y.
// blockIdx: x = p-tile, y = ks (ZKS), z = batch. Y zero-initialized.
// ---------------------------------------------------------------------------
template<int CIN>
__global__ __launch_bounds__(256)
void conv_wide(const u16* __restrict__ W,
               const u16* __restrict__ P0, const u16* __restrict__ P1,
               const u16* __restrict__ P2, float* __restrict__ Y)
{
    const int KT = 9 * CIN;
    __shared__ u16 As[256 * LDT];
    __shared__ u16 Bs[128 * LDT];

    const int t = threadIdx.x;
    const int w = t >> 6, lane = t & 63;
    const int mh = (w >> 1) * 128, nh = (w & 1) * 64;
    const int lm = lane & 15, quad = lane >> 4;
    const int n0 = blockIdx.x * 128;
    const int ks = blockIdx.y, b = blockIdx.z;
    const long pstride = (long)NR * CC;

    const int per = (KT / 64) / ZKS;
    const int it0 = ks * per;

    f32x4 acc[8][4] = {};

    for (int it = it0; it < it0 + per; ++it) {
        const int k0 = it * 64;
        int tap = k0 / CIN;
        int kloc = k0 - tap * CIN;
        int plane = kloc >> 8, cip = kloc & 255;
        int dh = tap / 3 - 1, dw = tap - (tap / 3) * 3 - 1;
        int off = dh * 60 + dw;
        const u16* src = (plane == 0) ? P0 : ((plane == 1) ? P1 : P2);
        src += (long)b * pstride + cip;

#pragma unroll
        for (int i = 0; i < 8; ++i) {                 // A: 256 co rows exact
            int idx = i * 256 + t;
            int row = idx >> 3, c8 = (idx & 7) * 8;
            uint4 v = *(const uint4*)(W + (long)row * KT + k0 + c8);
            *(uint4*)(&As[row * LDT + c8]) = v;
        }
#pragma unroll
        for (int i = 0; i < 4; ++i) {                 // B: shifted plane rows
            int idx = i * 256 + t;
            int row = idx >> 3, c8 = (idx & 7) * 8;
            int p = n0 + row;
            uint4 v = make_uint4(0u, 0u, 0u, 0u);
            if (p < NN) {
                int h = p / 60, wp = p - h * 60;
                int hh = h + dh, wq = wp + dw;
                if (hh >= 0 && hh < 60 && wq >= 0 && wq < 60)
                    v = *(const uint4*)(src + (long)(p + off) * CC + c8);
            }
            *(uint4*)(&Bs[row * LDT + c8]) = v;
        }
        __syncthreads();
#pragma unroll
        for (int s = 0; s < 2; ++s) {
            short8 a[8], bfr[4];
#pragma unroll
            for (int i = 0; i < 8; ++i)
                a[i] = *(const short8*)(&As[(mh + i * 16 + lm) * LDT + s * 32 + quad * 8]);
#pragma unroll
            for (int j = 0; j < 4; ++j)
                bfr[j] = *(const short8*)(&Bs[(nh + j * 16 + lm) * LDT + s * 32 + quad * 8]);
#pragma unroll
            for (int i = 0; i < 8; ++i)
#pragma unroll
                for (int j = 0; j < 4; ++j)
                    acc[i][j] = __builtin_amdgcn_mfma_f32_16x16x32_bf16(a[i], bfr[j], acc[i][j], 0, 0, 0);
        }
        __syncthreads();
    }

    float* out = Y + (long)b * CC * NN;
#pragma unroll
    for (int i = 0; i < 8; ++i)
#pragma unroll
        for (int r = 0; r < 4; ++r) {
            int row = mh + i * 16 + quad * 4 + r;
#pragma unroll
            for (int j = 0; j < 4; ++j) {
                int col = n0 + nh + j * 16 + lm;
                if (col < NN)
                    atomicAdd(&out[(long)row * NN + col], acc[i][j][r]);
            }
        }
}

// ---------------------------------------------------------------------------
// Converters / transposes
// ---------------------------------------------------------------------------
__global__ __launch_bounds__(256)
void cvt_we(const float* __restrict__ W, u16* __restrict__ O)
{
    int i = blockIdx.x * 256 + threadIdx.x;
    if (i < CC * CC) O[i] = f2bf(W[i]);
}

// V [b][256][3600] fp32 -> VT [b][3712][256] bf16; optionally also the
// NP-padded bf16 copy Vpad [b][256][3648] (zeros in pad).
__global__ __launch_bounds__(256)
void transpose_cvt(const float* __restrict__ V, u16* __restrict__ VT,
                   u16* __restrict__ Vpad)
{
    __shared__ float tile[64][65];
    int b = blockIdx.z, c0 = blockIdx.y * 64, n0 = blockIdx.x * 64;
    int t = threadIdx.x;
#pragma unroll
    for (int e = 0; e < 16; ++e) {
        int f = e * 256 + t; int i = f >> 6, j = f & 63;
        int n = n0 + j;
        float v = 0.f;
        if (n < NN) v = V[((long)b * CC + c0 + i) * NN + n];
        tile[i][j] = v;
        if (Vpad) Vpad[((long)b * CC + c0 + i) * NP + n] = f2bf(v);
    }
    __syncthreads();
#pragma unroll
    for (int e = 0; e < 16; ++e) {
        int f = e * 256 + t; int i = f >> 6, j = f & 63;
        int n = n0 + i;
        if (n < NN) VT[((long)b * NR + n) * CC + c0 + j] = f2bf(tile[j][i]);
    }
}

// Z fp32 [b][c][p] * sg[b][p] -> ZT bf16 [b][p][c]
__global__ __launch_bounds__(256)
void transpose_gate(const float* __restrict__ Z, const float* __restrict__ sg,
                    u16* __restrict__ ZT)
{
    __shared__ float tile[64][65];
    int b = blockIdx.z, c0 = blockIdx.y * 64, n0 = blockIdx.x * 64;
    int t = threadIdx.x;
#pragma unroll
    for (int e = 0; e < 16; ++e) {
        int f = e * 256 + t; int i = f >> 6, j = f & 63;
        int n = n0 + j;
        float v = 0.f;
        if (n < NN) v = Z[((long)b * CC + c0 + i) * NN + n];
        tile[i][j] = v;
    }
    __syncthreads();
#pragma unroll
    for (int e = 0; e < 16; ++e) {
        int f = e * 256 + t; int i = f >> 6, j = f & 63;
        int n = n0 + i;
        if (n < NN)
            ZT[((long)b * NR + n) * CC + c0 + j] = f2bf(tile[j][i] * sg[b * NN + n]);
    }
}

template<int CIN>
__global__ __launch_bounds__(256)
void cvt_convw(const float* __restrict__ W, u16* __restrict__ O)
{
    const int KT = 9 * CIN;
    long idx = (long)blockIdx.x * 256 + threadIdx.x;
    if (idx >= (long)CC * KT) return;
    int co = (int)(idx / KT);
    int r = (int)(idx % KT);
    int tap = r / CIN, ci = r % CIN;
    O[idx] = f2bf(W[((long)co * CIN + ci) * 9 + tap]);
}

// ---------------------------------------------------------------------------
// Per-pixel gate sigmoid: sg[b][p] = sigmoid(sum_c gw[c]*Z[c,p])
// ---------------------------------------------------------------------------
__global__ __launch_bounds__(256)
void gate_sig(const float* __restrict__ Z, const float* __restrict__ gw,
              float* __restrict__ sg)
{
    int t = threadIdx.x;
    int px = t & 63, ck = t >> 6;
    int b = blockIdx.y;
    int p = blockIdx.x * 64 + px;
    const float* Zp = Z + (long)b * CC * NN;
    float g = 0.f;
    if (p < NN) {
        for (int c = ck * 64; c < ck * 64 + 64; ++c) g += gw[c] * Zp[(long)c * NN + p];
    }
    __shared__ float red[256];
    red[t] = g;
    __syncthreads();
    if (t < 64) {
        int pp = blockIdx.x * 64 + t;
        if (pp < NN) {
            float tot = red[t] + red[t + 64] + red[t + 128] + red[t + 192];
            sg[b * NN + pp] = 1.f / (1.f + __expf(-tot));
        }
    }
}

// ---------------------------------------------------------------------------
// BatchNorm batch-stats -> scale/shift
// ---------------------------------------------------------------------------
__global__ __launch_bounds__(256)
void bn_stats_kernel(const float* __restrict__ Y, const float* __restrict__ g,
                     const float* __restrict__ beta, float* __restrict__ scale,
                     float* __restrict__ shift)
{
    int c = blockIdx.x, t = threadIdx.x;
    float s = 0.f, sq = 0.f;
    for (int b = 0; b < BB; ++b) {
        const float* p = Y + (long)b * CC * NN + (long)c * NN;
        for (int i = t; i < NN; i += 256) { float v = p[i]; s += v; sq += v * v; }
    }
    __shared__ float ls[256], lq[256];
    ls[t] = s; lq[t] = sq;
    __syncthreads();
    for (int off = 128; off > 0; off >>= 1) {
        if (t < off) { ls[t] += ls[t + off]; lq[t] += lq[t + off]; }
        __syncthreads();
    }
    if (t == 0) {
        const float inv = 1.f / (float)(BB * NN);
        float mean = ls[0] * inv;
        float var = fmaxf(lq[0] * inv - mean * mean, 0.f);
        float sc = g[c] * rsqrtf(var + 1e-5f);
        scale[c] = sc;
        shift[c] = beta[c] - mean * sc;
    }
}

// ---------------------------------------------------------------------------
// Fused BN-normalize + ReLU + 1x1 cls conv + bias
// ---------------------------------------------------------------------------
__global__ __launch_bounds__(256)
void cls_kernel(const float* __restrict__ Y, const float* __restrict__ scale,
                const float* __restrict__ shift, const float* __restrict__ cw,
                const float* __restrict__ cb, float* __restrict__ O)
{
    int t = threadIdx.x;
    int px = t & 63, ck = t >> 6;
    int b = blockIdx.y;
    int p = blockIdx.x * 64 + px;
    const float* Yb = Y + (long)b * CC * NN;
    float a0 = 0.f, a1 = 0.f;
    if (p < NN) {
        for (int c = ck * 64; c < ck * 64 + 64; ++c) {
            float v = Yb[(long)c * NN + p] * scale[c] + shift[c];
            v = fmaxf(v, 0.f);
            a0 += cw[c] * v;
            a1 += cw[CC + c] * v;
        }
    }
    __shared__ float r0[256], r1[256];
    r0[t] = a0; r1[t] = a1;
    __syncthreads();
    if (t < 64) {
        int pp = blockIdx.x * 64 + t;
        if (pp < NN) {
            float s0 = r0[t] + r0[t + 64] + r0[t + 128] + r0[t + 192];
            float s1 = r1[t] + r1[t + 64] + r1[t + 128] + r1[t + 192];
            O[(long)b * NCH * NN + pp] = s0 + cb[0];
            O[(long)b * NCH * NN + NN + pp] = s1 + cb[1];
        }
    }
}

// ---------------------------------------------------------------------------
// Bilinear resize 60x60 -> 473x473 (half-pixel, clamp) + sigmoid
// ---------------------------------------------------------------------------
__global__ __launch_bounds__(256)
void resize_sig_kernel(const float* __restrict__ I1, const float* __restrict__ I2,
                       float* __restrict__ O)
{
    const long HALF = (long)BB * NCH * HO * WO;
    long gid = (long)blockIdx.x * 256 + threadIdx.x;
    if (gid >= HALF) return;
    int half = blockIdx.y;
    const float* I = half ? I2 : I1;
    float* Op = O + half * HALF;

    int j = (int)(gid % WO);
    long r = gid / WO;
    int i = (int)(r % HO);
    int pc = (int)(r / HO);
    const float* ip = I + (long)pc * NN;

    const float SCL = 60.0f / 473.0f;
    float fy = (i + 0.5f) * SCL - 0.5f;
    float fx = (j + 0.5f) * SCL - 0.5f;
    int y0 = (int)floorf(fy);
    int x0 = (int)floorf(fx);
    float ty = fy - (float)y0;
    float tx = fx - (float)x0;
    int y0c = max(y0, 0), y1c = min(y0 + 1, 59);
    int x0c = max(x0, 0), x1c = min(x0 + 1, 59);
    float va = ip[y0c * 60 + x0c], vb = ip[y0c * 60 + x1c];
    float vc = ip[y1c * 60 + x0c], vd = ip[y1c * 60 + x1c];
    float v = (1.f - ty) * ((1.f - tx) * va + tx * vb) + ty * ((1.f - tx) * vc + tx * vd);
    Op[gid] = 1.f / (1.f + __expf(-v));
}

// ---------------------------------------------------------------------------
extern "C" void kernel_launch(void* const* d_in, const int* in_sizes, int n_in,
                              void* d_out, int out_size, void* d_ws, size_t ws_size,
                              hipStream_t stream)
{
    const float* V_a    = (const float*)d_in[0];
    const float* V_b    = (const float*)d_in[1];
    const float* D_a    = (const float*)d_in[2];
    const float* W_e    = (const float*)d_in[3];
    const float* gate_w = (const float*)d_in[4];
    const float* conv1_w = (const float*)d_in[5];
    const float* conv2_w = (const float*)d_in[6];
    const float* bn1_g = (const float*)d_in[7];
    const float* bn1_b = (const float*)d_in[8];
    const float* bn2_g = (const float*)d_in[9];
    const float* bn2_b = (const float*)d_in[10];
    const float* cls1_w = (const float*)d_in[11];
    const float* cls1_b = (const float*)d_in[12];
    const float* cls2_w = (const float*)d_in[13];
    const float* cls2_b = (const float*)d_in[14];
    float* out = (float*)d_out;

    // ---- workspace arena: ~143 MB (known-safe bound: 154.9 MB) ----
    size_t off = 0;
    char* wsb = (char*)d_ws;
    auto carve = [&](size_t bytes) -> char* {
        char* p = wsb + off; off += (bytes + 255) & ~(size_t)255; return p;
    };

    u16* Sh    = (u16*)carve((size_t)NN * NP * 2);         // 26.3 MB, per-batch
    u16* STh   = (u16*)carve((size_t)NN * NP * 2);         // 26.3 MB, per-batch
    u16* vab   = (u16*)carve((size_t)BB * CC * NP * 2);
    u16* vbb   = (u16*)carve((size_t)BB * CC * NP * 2);
    u16* vat   = (u16*)carve((size_t)BB * NR * CC * 2);
    u16* vbt   = (u16*)carve((size_t)BB * NR * CC * 2);
    u16* daT   = (u16*)carve((size_t)BB * NR * CC * 2);
    u16* gzaT  = (u16*)carve((size_t)BB * NR * CC * 2);
    u16* gzbT  = (u16*)carve((size_t)BB * NR * CC * 2);
    u16* wgtb  = (u16*)carve((size_t)BB * NR * CC * 2);
    u16* web   = (u16*)carve((size_t)CC * CC * 2);
    u16* wt1   = (u16*)carve((size_t)CC * 9 * 768 * 2);
    u16* wt2   = (u16*)carve((size_t)CC * 9 * 512 * 2);
    float* Za  = (float*)carve((size_t)BB * CC * NN * 4);  // contiguous 4-block
    float* Zb  = (float*)carve((size_t)BB * CC * NN * 4);  //   memset region
    float* y1  = (float*)carve((size_t)BB * CC * NN * 4);
    float* y2  = (float*)carve((size_t)BB * CC * NN * 4);
    float* rmx = (float*)carve((size_t)BB * NN * 4);
    float* rsm = (float*)carve((size_t)BB * NN * 4);
    float* cmx = (float*)carve((size_t)BB * NN * 4);
    float* csm = (float*)carve((size_t)BB * NN * 4);
    float* sga = (float*)carve((size_t)BB * NN * 4);
    float* sgb = (float*)carve((size_t)BB * NN * 4);
    float* prm = (float*)carve((size_t)NTI * NR * 4);
    float* prs = (float*)carve((size_t)NTI * NR * 4);
    float* pcm = (float*)carve((size_t)NTI * NR * 4);
    float* pcs = (float*)carve((size_t)NTI * NR * 4);
    float* c1o = (float*)carve((size_t)BB * NCH * NN * 4);
    float* c2o = (float*)carve((size_t)BB * NCH * NN * 4);

    dim3 blk(256);

    // zero-init all atomic accumulators (Za,Zb,y1,y2 contiguous)
    hipMemsetAsync(Za, 0, (size_t)4 * BB * CC * NN * 4, stream);

    // --- input conversions (padded copies fused into transposes) ---
    cvt_we<<<256, blk, 0, stream>>>(W_e, web);
    transpose_cvt<<<dim3(57, 4, BB), blk, 0, stream>>>(V_a, vat, vab);
    transpose_cvt<<<dim3(57, 4, BB), blk, 0, stream>>>(V_b, vbt, vbb);
    transpose_cvt<<<dim3(57, 4, BB), blk, 0, stream>>>(D_a, daT, nullptr);
    cvt_convw<768><<<(int)(((long)CC * 9 * 768 + 255) / 256), blk, 0, stream>>>(conv1_w, wt1);
    cvt_convw<512><<<(int)(((long)CC * 9 * 512 + 255) / 256), blk, 0, stream>>>(conv2_w, wt2);

    // --- weighted (both batches) ---
    gemm_we<<<dim3(2, NTI, BB), blk, 0, stream>>>(vat, web, wgtb);

    // --- attention, per batch ---
    for (int b = 0; b < BB; ++b) {
        const u16* wgtb_b = wgtb + (long)b * NR * CC;
        const u16* vbt_b  = vbt + (long)b * NR * CC;
        const u16* vab_b  = vab + (long)b * CC * NP;
        const u16* vbb_b  = vbb + (long)b * CC * NP;
        float* rmx_b = rmx + b * NN; float* rsm_b = rsm + b * NN;
        float* cmx_b = cmx + b * NN; float* csm_b = csm + b * NN;

        gemm_s_stats<<<dim3(NTI, NTI), blk, 0, stream>>>(
            wgtb_b, vbt_b, Sh, STh, prm, prs, pcm, pcs);
        stats_combine<<<dim3((NN + 255) / 256, 2), blk, 0, stream>>>(
            prm, prs, pcm, pcs, rmx_b, rsm_b, cmx_b, csm_b);
        gemm_z_wide<<<dim3(NTI, ZKS, 2), blk, 0, stream>>>(
            vab_b, vbb_b, STh, Sh, cmx_b, csm_b, rmx_b, rsm_b,
            Zb + (long)b * CC * NN, Za + (long)b * CC * NN);
    }

    // --- gates: per-pixel sigmoid, then transpose-scale to [p][c] bf16 ---
    gate_sig<<<dim3(57, BB), blk, 0, stream>>>(Za, gate_w, sga);
    gate_sig<<<dim3(57, BB), blk, 0, stream>>>(Zb, gate_w, sgb);
    transpose_gate<<<dim3(57, 4, BB), blk, 0, stream>>>(Za, sga, gzaT);
    transpose_gate<<<dim3(57, 4, BB), blk, 0, stream>>>(Zb, sgb, gzbT);

    // --- convs: wide direct split-K GEMM, atomic into y1/y2 ---
    conv_wide<768><<<dim3(NTI, ZKS, BB), blk, 0, stream>>>(wt1, gzaT, vat, daT, y1);
    conv_wide<512><<<dim3(NTI, ZKS, BB), blk, 0, stream>>>(wt2, gzbT, vbt, vbt, y2);

    // --- BN + cls + resize --- (rmx/rsm/cmx/csm reused as scale/shift)
    bn_stats_kernel<<<256, blk, 0, stream>>>(y1, bn1_g, bn1_b, rmx, rsm);
    bn_stats_kernel<<<256, blk, 0, stream>>>(y2, bn2_g, bn2_b, cmx, csm);
    cls_kernel<<<dim3(57, BB), blk, 0, stream>>>(y1, rmx, rsm, cls1_w, cls1_b, c1o);
    cls_kernel<<<dim3(57, BB), blk, 0, stream>>>(y2, cmx, csm, cls2_w, cls2_b, c2o);

    resize_sig_kernel<<<dim3((int)(((long)BB * NCH * HO * WO + 255) / 256), 2), blk, 0, stream>>>(c1o, c2o, out);
}

// Round 9
// 687.197 us; speedup vs baseline: 5.0879x; 1.0637x over previous
//
#include <hip/hip_runtime.h>

#define BB 2
#define CC 256
#define NN 3600
#define NCH 2
#define HO 473
#define WO 473
#define NP 3648          // NN padded to mult of 64 (K/stride padding)
#define NR 3712          // NN padded to mult of 128 (row padding)
#define LDT 72           // LDS tile row stride in u16 (16B-aligned)
#define NTI 29           // tiles of 128 covering NN
#define ZKS 6            // split-K slices for Z/conv GEMMs

typedef unsigned short u16;
typedef __attribute__((ext_vector_type(8))) short short8;
typedef __attribute__((ext_vector_type(4))) float f32x4;

static __device__ __forceinline__ u16 f2bf(float f) {
    unsigned u = __float_as_uint(f);
    unsigned r = (u + 0x7FFF + ((u >> 16) & 1)) >> 16;
    return (u16)r;
}
static __device__ __forceinline__ u16 f2h(float f) {
    _Float16 h = (_Float16)f;
    return __builtin_bit_cast(unsigned short, h);
}
static __device__ __forceinline__ float h2f(u16 u) {
    _Float16 h = __builtin_bit_cast(_Float16, u);
    return (float)h;
}

// ---------------------------------------------------------------------------
// 128x128 bf16 GEMM (gemm_we only): C[m][n] = sum_k A[m][k]*B[n][k], bf16 out
// ---------------------------------------------------------------------------
__global__ __launch_bounds__(256)
void gemm_we(const u16* __restrict__ vat, const u16* __restrict__ web,
             u16* __restrict__ wgtb)
{
    __shared__ u16 As[128 * LDT];
    __shared__ u16 Bs[128 * LDT];
    const u16* A = vat + (long)blockIdx.z * NR * CC;
    u16* Cp = wgtb + (long)blockIdx.z * NR * CC;

    const int t = threadIdx.x;
    const int w = t >> 6, lane = t & 63;
    const int mh = (w >> 1) * 64, nh = (w & 1) * 64;
    const int lm = lane & 15, quad = lane >> 4;
    const int m0 = blockIdx.y * 128, n0 = blockIdx.x * 128;

    f32x4 acc[4][4] = {};

    for (int k0 = 0; k0 < CC; k0 += 64) {
#pragma unroll
        for (int i = 0; i < 4; ++i) {
            int idx = i * 256 + t;
            int row = idx >> 3, c8 = (idx & 7) * 8;
            int rg = m0 + row;
            uint4 v = make_uint4(0u, 0u, 0u, 0u);
            if (rg < NN) v = *(const uint4*)(A + (long)rg * CC + k0 + c8);
            *(uint4*)(&As[row * LDT + c8]) = v;
            uint4 bv = make_uint4(0u, 0u, 0u, 0u);
            if (n0 + row < CC) bv = *(const uint4*)(web + (long)(n0 + row) * CC + k0 + c8);
            *(uint4*)(&Bs[row * LDT + c8]) = bv;
        }
        __syncthreads();
#pragma unroll
        for (int s = 0; s < 2; ++s) {
            short8 a[4], b[4];
#pragma unroll
            for (int i = 0; i < 4; ++i)
                a[i] = *(const short8*)(&As[(mh + i * 16 + lm) * LDT + s * 32 + quad * 8]);
#pragma unroll
            for (int j = 0; j < 4; ++j)
                b[j] = *(const short8*)(&Bs[(nh + j * 16 + lm) * LDT + s * 32 + quad * 8]);
#pragma unroll
            for (int i = 0; i < 4; ++i)
#pragma unroll
                for (int j = 0; j < 4; ++j)
                    acc[i][j] = __builtin_amdgcn_mfma_f32_16x16x32_bf16(a[i], b[j], acc[i][j], 0, 0, 0);
        }
        __syncthreads();
    }
#pragma unroll
    for (int i = 0; i < 4; ++i)
#pragma unroll
        for (int r = 0; r < 4; ++r) {
            int row = m0 + mh + i * 16 + quad * 4 + r;
            if (row < NN)
#pragma unroll
                for (int j = 0; j < 4; ++j) {
                    int col = n0 + nh + j * 16 + lm;
                    if (col < CC) Cp[(long)row * CC + col] = f2bf(acc[i][j][r]);
                }
        }
}

// ---------------------------------------------------------------------------
// S GEMM with fused softmax-stat partials + dual fp16 output (S and S^T).
// ---------------------------------------------------------------------------
__global__ __launch_bounds__(256)
void gemm_s_stats(const u16* __restrict__ A, const u16* __restrict__ B,
                  u16* __restrict__ Sh, u16* __restrict__ STh,
                  float* __restrict__ prowm, float* __restrict__ prows,
                  float* __restrict__ pcolm, float* __restrict__ pcols)
{
    __shared__ u16 smem[2 * 128 * LDT];     // As | Bs; reused as scratch later
    u16* As = smem;
    u16* Bs = smem + 128 * LDT;

    const int t = threadIdx.x;
    const int w = t >> 6, lane = t & 63;
    const int mh = (w >> 1) * 64, nh = (w & 1) * 64;
    const int lm = lane & 15, quad = lane >> 4;
    const int m0 = blockIdx.y * 128, n0 = blockIdx.x * 128;

    f32x4 acc[4][4] = {};

    for (int k0 = 0; k0 < CC; k0 += 64) {
#pragma unroll
        for (int i = 0; i < 4; ++i) {
            int idx = i * 256 + t;
            int row = idx >> 3, c8 = (idx & 7) * 8;
            uint4 v = make_uint4(0u, 0u, 0u, 0u);
            if (m0 + row < NN) v = *(const uint4*)(A + (long)(m0 + row) * CC + k0 + c8);
            *(uint4*)(&As[row * LDT + c8]) = v;
            uint4 bv = make_uint4(0u, 0u, 0u, 0u);
            if (n0 + row < NN) bv = *(const uint4*)(B + (long)(n0 + row) * CC + k0 + c8);
            *(uint4*)(&Bs[row * LDT + c8]) = bv;
        }
        __syncthreads();
#pragma unroll
        for (int s = 0; s < 2; ++s) {
            short8 a[4], b[4];
#pragma unroll
            for (int i = 0; i < 4; ++i)
                a[i] = *(const short8*)(&As[(mh + i * 16 + lm) * LDT + s * 32 + quad * 8]);
#pragma unroll
            for (int j = 0; j < 4; ++j)
                b[j] = *(const short8*)(&Bs[(nh + j * 16 + lm) * LDT + s * 32 + quad * 8]);
#pragma unroll
            for (int i = 0; i < 4; ++i)
#pragma unroll
                for (int j = 0; j < 4; ++j)
                    acc[i][j] = __builtin_amdgcn_mfma_f32_16x16x32_bf16(a[i], b[j], acc[i][j], 0, 0, 0);
        }
        __syncthreads();
    }

    // store S (fp16, row n contiguous in m)
#pragma unroll
    for (int i = 0; i < 4; ++i)
#pragma unroll
        for (int r = 0; r < 4; ++r) {
            int row = m0 + mh + i * 16 + quad * 4 + r;
            if (row < NN)
#pragma unroll
                for (int j = 0; j < 4; ++j) {
                    int col = n0 + nh + j * 16 + lm;
                    if (col < NN) Sh[(long)row * NP + col] = f2h(acc[i][j][r]);
                }
        }

    // ---- fused stats ----
    bool cval[4];
#pragma unroll
    for (int j = 0; j < 4; ++j) cval[j] = (n0 + nh + j * 16 + lm) < NN;

    float* sm = (float*)smem;         // 4 x [2][128] floats = 4 KB
    float* rowm = sm;
    float* rows_ = sm + 256;
    float* colm = sm + 512;
    float* cols_ = sm + 768;
    __syncthreads();

    // row stats (over this block's cols)
#pragma unroll
    for (int i = 0; i < 4; ++i)
#pragma unroll
        for (int r = 0; r < 4; ++r) {
            float m = -3.0e38f;
#pragma unroll
            for (int j = 0; j < 4; ++j) if (cval[j]) m = fmaxf(m, acc[i][j][r]);
            m = fmaxf(m, __shfl_xor(m, 1, 64));
            m = fmaxf(m, __shfl_xor(m, 2, 64));
            m = fmaxf(m, __shfl_xor(m, 4, 64));
            m = fmaxf(m, __shfl_xor(m, 8, 64));
            float s = 0.f;
#pragma unroll
            for (int j = 0; j < 4; ++j) if (cval[j]) s += __expf(acc[i][j][r] - m);
            s += __shfl_xor(s, 1, 64);
            s += __shfl_xor(s, 2, 64);
            s += __shfl_xor(s, 4, 64);
            s += __shfl_xor(s, 8, 64);
            if (lm == 0) {
                int rr = mh + i * 16 + quad * 4 + r;
                rowm[(w & 1) * 128 + rr] = m;
                rows_[(w & 1) * 128 + rr] = s;
            }
        }

    // col stats (over this block's rows)
#pragma unroll
    for (int j = 0; j < 4; ++j) {
        float m = -3.0e38f;
#pragma unroll
        for (int i = 0; i < 4; ++i)
#pragma unroll
            for (int r = 0; r < 4; ++r)
                if (m0 + mh + i * 16 + quad * 4 + r < NN) m = fmaxf(m, acc[i][j][r]);
        m = fmaxf(m, __shfl_xor(m, 16, 64));
        m = fmaxf(m, __shfl_xor(m, 32, 64));
        float s = 0.f;
#pragma unroll
        for (int i = 0; i < 4; ++i)
#pragma unroll
            for (int r = 0; r < 4; ++r)
                if (m0 + mh + i * 16 + quad * 4 + r < NN) s += __expf(acc[i][j][r] - m);
        s += __shfl_xor(s, 16, 64);
        s += __shfl_xor(s, 32, 64);
        if (quad == 0) {
            int ccl = nh + j * 16 + lm;
            colm[(w >> 1) * 128 + ccl] = m;
            cols_[(w >> 1) * 128 + ccl] = s;
        }
    }
    __syncthreads();

    if (t < 128) {
        float m1 = rowm[t], m2 = rowm[128 + t];
        float M = fmaxf(m1, m2);
        float s = rows_[t] * __expf(m1 - M) + rows_[128 + t] * __expf(m2 - M);
        if (m0 + t < NN) {
            prowm[(long)blockIdx.x * NR + m0 + t] = M;
            prows[(long)blockIdx.x * NR + m0 + t] = s;
        }
    } else {
        int c = t - 128;
        float m1 = colm[c], m2 = colm[128 + c];
        float M = fmaxf(m1, m2);
        float s = cols_[c] * __expf(m1 - M) + cols_[128 + c] * __expf(m2 - M);
        if (n0 + c < NN) {
            pcolm[(long)blockIdx.y * NR + n0 + c] = M;
            pcols[(long)blockIdx.y * NR + n0 + c] = s;
        }
    }

    // ---- S^T via LDS transpose: tr[m_local][n_local], stride 136 ----
    __syncthreads();
    u16* tr = smem;                   // 128*136 u16 = 33.8 KB
#pragma unroll
    for (int i = 0; i < 4; ++i)
#pragma unroll
        for (int j = 0; j < 4; ++j)
#pragma unroll
            for (int r = 0; r < 4; ++r)
                tr[(nh + j * 16 + lm) * 136 + (mh + i * 16 + quad * 4 + r)] = f2h(acc[i][j][r]);
    __syncthreads();
    {
        int row = t >> 1, hf = t & 1;
        int mg = n0 + row;
        if (mg < NN) {
#pragma unroll
            for (int q = 0; q < 8; ++q) {
                int cb = m0 + hf * 64 + q * 8;
                if (cb < NN)
                    *(uint4*)(&STh[(long)mg * NP + cb]) =
                        *(const uint4*)(&tr[row * 136 + hf * 64 + q * 8]);
            }
        }
    }
}

// merge NTI partials -> final stats. y=0: row (rmx/rsm); y=1: col (cmx/csm)
__global__ __launch_bounds__(256)
void stats_combine(const float* __restrict__ prowm, const float* __restrict__ prows,
                   const float* __restrict__ pcolm, const float* __restrict__ pcols,
                   float* __restrict__ rmx, float* __restrict__ rsm,
                   float* __restrict__ cmx, float* __restrict__ csm)
{
    int i = blockIdx.x * 256 + threadIdx.x;
    if (i >= NN) return;
    const float* pm = blockIdx.y ? pcolm : prowm;
    const float* ps = blockIdx.y ? pcols : prows;
    float m = -3.0e38f, s = 0.f;
#pragma unroll 4
    for (int tI = 0; tI < NTI; ++tI) {
        float m2 = pm[(long)tI * NR + i], s2 = ps[(long)tI * NR + i];
        float M = fmaxf(m, m2);
        s = s * __expf(m - M) + s2 * __expf(m2 - M);
        m = M;
    }
    if (blockIdx.y) { cmx[i] = m; csm[i] = s; }
    else            { rmx[i] = m; rsm[i] = s; }
}

// ---------------------------------------------------------------------------
// In-place P build: fp16 S row -> bf16 exp(v - mx[row]) / sm[row]; pad cols
// zeroed. blockIdx.x = row; blockIdx.y: 0 = Sh (row stats), 1 = STh (col stats)
// ---------------------------------------------------------------------------
__global__ __launch_bounds__(256)
void p_build(u16* __restrict__ Sh, u16* __restrict__ STh,
             const float* __restrict__ rmx, const float* __restrict__ rsm,
             const float* __restrict__ cmx, const float* __restrict__ csm)
{
    int r = blockIdx.x;
    u16* M = blockIdx.y ? STh : Sh;
    const float* mx = blockIdx.y ? cmx : rmx;
    const float* sm = blockIdx.y ? csm : rsm;
    float mv = mx[r];
    float inv = 1.f / sm[r];
    u16* row = M + (long)r * NP;
    int t = threadIdx.x;
    for (int c0 = t * 8; c0 < NP; c0 += 2048) {
        uint4 hv = *(const uint4*)(row + c0);
        const u16* hp = (const u16*)&hv;
        u16 o[8];
#pragma unroll
        for (int e = 0; e < 8; ++e) {
            int c = c0 + e;
            o[e] = (c < NN) ? f2bf(__expf(h2f(hp[e]) - mv) * inv) : (u16)0;
        }
        *(uint4*)(row + c0) = *(const uint4*)o;
    }
}

// ---------------------------------------------------------------------------
// Z GEMM, 128x128 tiles, pure bf16 staging, split-K + atomicAdd.
// blockIdx: x = n-tile, y = ks, z = mtile*2 + branch (0: Zb=vab.PT, 1: Za=vbb.P)
// C zero-initialized before launch. P/PT are normalized bf16 (p_build).
// ---------------------------------------------------------------------------
__global__ __launch_bounds__(256, 4)
void gemm_z_128(const u16* __restrict__ vab_b, const u16* __restrict__ vbb_b,
                const u16* __restrict__ PT, const u16* __restrict__ P,
                float* __restrict__ Zb_b, float* __restrict__ Za_b)
{
    __shared__ u16 As[128 * LDT];
    __shared__ u16 Bs[128 * LDT];

    const int t = threadIdx.x;
    const int w = t >> 6, lane = t & 63;
    const int mh = (w >> 1) * 64, nh = (w & 1) * 64;
    const int lm = lane & 15, quad = lane >> 4;
    const int n0 = blockIdx.x * 128;
    const int ks = blockIdx.y;
    const int zz = blockIdx.z;
    const int branch = zz & 1;
    const int m0 = (zz >> 1) * 128;
    const u16* A = branch ? vbb_b : vab_b;
    const u16* B = branch ? P : PT;
    float* Cp = branch ? Za_b : Zb_b;

    const int base = 57 / ZKS, rem = 57 % ZKS;   // 9, 3
    const int it0 = ks * base + (ks < rem ? ks : rem);
    const int itn = base + (ks < rem ? 1 : 0);

    f32x4 acc[4][4] = {};

    for (int it = it0; it < it0 + itn; ++it) {
        const int k0 = it * 64;
#pragma unroll
        for (int i = 0; i < 4; ++i) {
            int idx = i * 256 + t;
            int row = idx >> 3, c8 = (idx & 7) * 8;
            uint4 v = *(const uint4*)(A + (long)(m0 + row) * NP + k0 + c8);
            *(uint4*)(&As[row * LDT + c8]) = v;
            int rg = n0 + row;
            uint4 bv = make_uint4(0u, 0u, 0u, 0u);
            if (rg < NN) bv = *(const uint4*)(B + (long)rg * NP + k0 + c8);
            *(uint4*)(&Bs[row * LDT + c8]) = bv;
        }
        __syncthreads();
#pragma unroll
        for (int s = 0; s < 2; ++s) {
            short8 a[4], b[4];
#pragma unroll
            for (int i = 0; i < 4; ++i)
                a[i] = *(const short8*)(&As[(mh + i * 16 + lm) * LDT + s * 32 + quad * 8]);
#pragma unroll
            for (int j = 0; j < 4; ++j)
                b[j] = *(const short8*)(&Bs[(nh + j * 16 + lm) * LDT + s * 32 + quad * 8]);
#pragma unroll
            for (int i = 0; i < 4; ++i)
#pragma unroll
                for (int j = 0; j < 4; ++j)
                    acc[i][j] = __builtin_amdgcn_mfma_f32_16x16x32_bf16(a[i], b[j], acc[i][j], 0, 0, 0);
        }
        __syncthreads();
    }

#pragma unroll
    for (int i = 0; i < 4; ++i)
#pragma unroll
        for (int r = 0; r < 4; ++r) {
            int row = m0 + mh + i * 16 + quad * 4 + r;
#pragma unroll
            for (int j = 0; j < 4; ++j) {
                int col = n0 + nh + j * 16 + lm;
                if (col < NN)
                    atomicAdd(&Cp[(long)row * NN + col], acc[i][j][r]);
            }
        }
}

// ---------------------------------------------------------------------------
// Direct conv, 128x128 tiles, split-K + atomicAdd into Y (zero-initialized).
// blockIdx: x = p-tile, y = ks (ZKS), z = b*2 + mtile.
// ---------------------------------------------------------------------------
template<int CIN>
__global__ __launch_bounds__(256, 4)
void conv_128(const u16* __restrict__ W,
              const u16* __restrict__ P0, const u16* __restrict__ P1,
              const u16* __restrict__ P2, float* __restrict__ Y)
{
    const int KT = 9 * CIN;
    __shared__ u16 As[128 * LDT];
    __shared__ u16 Bs[128 * LDT];

    const int t = threadIdx.x;
    const int w = t >> 6, lane = t & 63;
    const int mh = (w >> 1) * 64, nh = (w & 1) * 64;
    const int lm = lane & 15, quad = lane >> 4;
    const int n0 = blockIdx.x * 128;
    const int ks = blockIdx.y;
    const int zz = blockIdx.z, b = zz >> 1;
    const int m0 = (zz & 1) * 128;
    const long pstride = (long)NR * CC;

    const int per = (KT / 64) / ZKS;
    const int it0 = ks * per;

    f32x4 acc[4][4] = {};

    for (int it = it0; it < it0 + per; ++it) {
        const int k0 = it * 64;
        int tap = k0 / CIN;
        int kloc = k0 - tap * CIN;
        int plane = kloc >> 8, cip = kloc & 255;
        int dh = tap / 3 - 1, dw = tap - (tap / 3) * 3 - 1;
        int off = dh * 60 + dw;
        const u16* src = (plane == 0) ? P0 : ((plane == 1) ? P1 : P2);
        src += (long)b * pstride + cip;

#pragma unroll
        for (int i = 0; i < 4; ++i) {
            int idx = i * 256 + t;
            int row = idx >> 3, c8 = (idx & 7) * 8;
            uint4 v = *(const uint4*)(W + (long)(m0 + row) * KT + k0 + c8);
            *(uint4*)(&As[row * LDT + c8]) = v;
            int p = n0 + row;
            uint4 bv = make_uint4(0u, 0u, 0u, 0u);
            if (p < NN) {
                int h = p / 60, wp = p - h * 60;
                int hh = h + dh, wq = wp + dw;
                if (hh >= 0 && hh < 60 && wq >= 0 && wq < 60)
                    bv = *(const uint4*)(src + (long)(p + off) * CC + c8);
            }
            *(uint4*)(&Bs[row * LDT + c8]) = bv;
        }
        __syncthreads();
#pragma unroll
        for (int s = 0; s < 2; ++s) {
            short8 a[4], bfr[4];
#pragma unroll
            for (int i = 0; i < 4; ++i)
                a[i] = *(const short8*)(&As[(mh + i * 16 + lm) * LDT + s * 32 + quad * 8]);
#pragma unroll
            for (int j = 0; j < 4; ++j)
                bfr[j] = *(const short8*)(&Bs[(nh + j * 16 + lm) * LDT + s * 32 + quad * 8]);
#pragma unroll
            for (int i = 0; i < 4; ++i)
#pragma unroll
                for (int j = 0; j < 4; ++j)
                    acc[i][j] = __builtin_amdgcn_mfma_f32_16x16x32_bf16(a[i], bfr[j], acc[i][j], 0, 0, 0);
        }
        __syncthreads();
    }

    float* out = Y + (long)b * CC * NN;
#pragma unroll
    for (int i = 0; i < 4; ++i)
#pragma unroll
        for (int r = 0; r < 4; ++r) {
            int row = m0 + mh + i * 16 + quad * 4 + r;
#pragma unroll
            for (int j = 0; j < 4; ++j) {
                int col = n0 + nh + j * 16 + lm;
                if (col < NN)
                    atomicAdd(&out[(long)row * NN + col], acc[i][j][r]);
            }
        }
}

// ---------------------------------------------------------------------------
// Converters / transposes
// ---------------------------------------------------------------------------
__global__ __launch_bounds__(256)
void cvt_we(const float* __restrict__ W, u16* __restrict__ O)
{
    int i = blockIdx.x * 256 + threadIdx.x;
    if (i < CC * CC) O[i] = f2bf(W[i]);
}

// V [b][256][3600] fp32 -> VT [b][3712][256] bf16; optionally also the
// NP-padded bf16 copy Vpad [b][256][3648] (zeros in pad).
__global__ __launch_bounds__(256)
void transpose_cvt(const float* __restrict__ V, u16* __restrict__ VT,
                   u16* __restrict__ Vpad)
{
    __shared__ float tile[64][65];
    int b = blockIdx.z, c0 = blockIdx.y * 64, n0 = blockIdx.x * 64;
    int t = threadIdx.x;
#pragma unroll
    for (int e = 0; e < 16; ++e) {
        int f = e * 256 + t; int i = f >> 6, j = f & 63;
        int n = n0 + j;
        float v = 0.f;
        if (n < NN) v = V[((long)b * CC + c0 + i) * NN + n];
        tile[i][j] = v;
        if (Vpad) Vpad[((long)b * CC + c0 + i) * NP + n] = f2bf(v);
    }
    __syncthreads();
#pragma unroll
    for (int e = 0; e < 16; ++e) {
        int f = e * 256 + t; int i = f >> 6, j = f & 63;
        int n = n0 + i;
        if (n < NN) VT[((long)b * NR + n) * CC + c0 + j] = f2bf(tile[j][i]);
    }
}

// Z fp32 [b][c][p] * sg[b][p] -> ZT bf16 [b][p][c]
__global__ __launch_bounds__(256)
void transpose_gate(const float* __restrict__ Z, const float* __restrict__ sg,
                    u16* __restrict__ ZT)
{
    __shared__ float tile[64][65];
    int b = blockIdx.z, c0 = blockIdx.y * 64, n0 = blockIdx.x * 64;
    int t = threadIdx.x;
#pragma unroll
    for (int e = 0; e < 16; ++e) {
        int f = e * 256 + t; int i = f >> 6, j = f & 63;
        int n = n0 + j;
        float v = 0.f;
        if (n < NN) v = Z[((long)b * CC + c0 + i) * NN + n];
        tile[i][j] = v;
    }
    __syncthreads();
#pragma unroll
    for (int e = 0; e < 16; ++e) {
        int f = e * 256 + t; int i = f >> 6, j = f & 63;
        int n = n0 + i;
        if (n < NN)
            ZT[((long)b * NR + n) * CC + c0 + j] = f2bf(tile[j][i] * sg[b * NN + n]);
    }
}

template<int CIN>
__global__ __launch_bounds__(256)
void cvt_convw(const float* __restrict__ W, u16* __restrict__ O)
{
    const int KT = 9 * CIN;
    long idx = (long)blockIdx.x * 256 + threadIdx.x;
    if (idx >= (long)CC * KT) return;
    int co = (int)(idx / KT);
    int r = (int)(idx % KT);
    int tap = r / CIN, ci = r % CIN;
    O[idx] = f2bf(W[((long)co * CIN + ci) * 9 + tap]);
}

// ---------------------------------------------------------------------------
// Per-pixel gate sigmoid: sg[b][p] = sigmoid(sum_c gw[c]*Z[c,p])
// ---------------------------------------------------------------------------
__global__ __launch_bounds__(256)
void gate_sig(const float* __restrict__ Z, const float* __restrict__ gw,
              float* __restrict__ sg)
{
    int t = threadIdx.x;
    int px = t & 63, ck = t >> 6;
    int b = blockIdx.y;
    int p = blockIdx.x * 64 + px;
    const float* Zp = Z + (long)b * CC * NN;
    float g = 0.f;
    if (p < NN) {
        for (int c = ck * 64; c < ck * 64 + 64; ++c) g += gw[c] * Zp[(long)c * NN + p];
    }
    __shared__ float red[256];
    red[t] = g;
    __syncthreads();
    if (t < 64) {
        int pp = blockIdx.x * 64 + t;
        if (pp < NN) {
            float tot = red[t] + red[t + 64] + red[t + 128] + red[t + 192];
            sg[b * NN + pp] = 1.f / (1.f + __expf(-tot));
        }
    }
}

// ---------------------------------------------------------------------------
// BatchNorm batch-stats -> scale/shift
// ---------------------------------------------------------------------------
__global__ __launch_bounds__(256)
void bn_stats_kernel(const float* __restrict__ Y, const float* __restrict__ g,
                     const float* __restrict__ beta, float* __restrict__ scale,
                     float* __restrict__ shift)
{
    int c = blockIdx.x, t = threadIdx.x;
    float s = 0.f, sq = 0.f;
    for (int b = 0; b < BB; ++b) {
        const float* p = Y + (long)b * CC * NN + (long)c * NN;
        for (int i = t; i < NN; i += 256) { float v = p[i]; s += v; sq += v * v; }
    }
    __shared__ float ls[256], lq[256];
    ls[t] = s; lq[t] = sq;
    __syncthreads();
    for (int off = 128; off > 0; off >>= 1) {
        if (t < off) { ls[t] += ls[t + off]; lq[t] += lq[t + off]; }
        __syncthreads();
    }
    if (t == 0) {
        const float inv = 1.f / (float)(BB * NN);
        float mean = ls[0] * inv;
        float var = fmaxf(lq[0] * inv - mean * mean, 0.f);
        float sc = g[c] * rsqrtf(var + 1e-5f);
        scale[c] = sc;
        shift[c] = beta[c] - mean * sc;
    }
}

// ---------------------------------------------------------------------------
// Fused BN-normalize + ReLU + 1x1 cls conv + bias
// ---------------------------------------------------------------------------
__global__ __launch_bounds__(256)
void cls_kernel(const float* __restrict__ Y, const float* __restrict__ scale,
                const float* __restrict__ shift, const float* __restrict__ cw,
                const float* __restrict__ cb, float* __restrict__ O)
{
    int t = threadIdx.x;
    int px = t & 63, ck = t >> 6;
    int b = blockIdx.y;
    int p = blockIdx.x * 64 + px;
    const float* Yb = Y + (long)b * CC * NN;
    float a0 = 0.f, a1 = 0.f;
    if (p < NN) {
        for (int c = ck * 64; c < ck * 64 + 64; ++c) {
            float v = Yb[(long)c * NN + p] * scale[c] + shift[c];
            v = fmaxf(v, 0.f);
            a0 += cw[c] * v;
            a1 += cw[CC + c] * v;
        }
    }
    __shared__ float r0[256], r1[256];
    r0[t] = a0; r1[t] = a1;
    __syncthreads();
    if (t < 64) {
        int pp = blockIdx.x * 64 + t;
        if (pp < NN) {
            float s0 = r0[t] + r0[t + 64] + r0[t + 128] + r0[t + 192];
            float s1 = r1[t] + r1[t + 64] + r1[t + 128] + r1[t + 192];
            O[(long)b * NCH * NN + pp] = s0 + cb[0];
            O[(long)b * NCH * NN + NN + pp] = s1 + cb[1];
        }
    }
}

// ---------------------------------------------------------------------------
// Bilinear resize 60x60 -> 473x473 (half-pixel, clamp) + sigmoid
// ---------------------------------------------------------------------------
__global__ __launch_bounds__(256)
void resize_sig_kernel(const float* __restrict__ I1, const float* __restrict__ I2,
                       float* __restrict__ O)
{
    const long HALF = (long)BB * NCH * HO * WO;
    long gid = (long)blockIdx.x * 256 + threadIdx.x;
    if (gid >= HALF) return;
    int half = blockIdx.y;
    const float* I = half ? I2 : I1;
    float* Op = O + half * HALF;

    int j = (int)(gid % WO);
    long r = gid / WO;
    int i = (int)(r % HO);
    int pc = (int)(r / HO);
    const float* ip = I + (long)pc * NN;

    const float SCL = 60.0f / 473.0f;
    float fy = (i + 0.5f) * SCL - 0.5f;
    float fx = (j + 0.5f) * SCL - 0.5f;
    int y0 = (int)floorf(fy);
    int x0 = (int)floorf(fx);
    float ty = fy - (float)y0;
    float tx = fx - (float)x0;
    int y0c = max(y0, 0), y1c = min(y0 + 1, 59);
    int x0c = max(x0, 0), x1c = min(x0 + 1, 59);
    float va = ip[y0c * 60 + x0c], vb = ip[y0c * 60 + x1c];
    float vc = ip[y1c * 60 + x0c], vd = ip[y1c * 60 + x1c];
    float v = (1.f - ty) * ((1.f - tx) * va + tx * vb) + ty * ((1.f - tx) * vc + tx * vd);
    Op[gid] = 1.f / (1.f + __expf(-v));
}

// ---------------------------------------------------------------------------
extern "C" void kernel_launch(void* const* d_in, const int* in_sizes, int n_in,
                              void* d_out, int out_size, void* d_ws, size_t ws_size,
                              hipStream_t stream)
{
    const float* V_a    = (const float*)d_in[0];
    const float* V_b    = (const float*)d_in[1];
    const float* D_a    = (const float*)d_in[2];
    const float* W_e    = (const float*)d_in[3];
    const float* gate_w = (const float*)d_in[4];
    const float* conv1_w = (const float*)d_in[5];
    const float* conv2_w = (const float*)d_in[6];
    const float* bn1_g = (const float*)d_in[7];
    const float* bn1_b = (const float*)d_in[8];
    const float* bn2_g = (const float*)d_in[9];
    const float* bn2_b = (const float*)d_in[10];
    const float* cls1_w = (const float*)d_in[11];
    const float* cls1_b = (const float*)d_in[12];
    const float* cls2_w = (const float*)d_in[13];
    const float* cls2_b = (const float*)d_in[14];
    float* out = (float*)d_out;

    // ---- workspace arena: ~143 MB (known-safe bound: 154.9 MB) ----
    size_t off = 0;
    char* wsb = (char*)d_ws;
    auto carve = [&](size_t bytes) -> char* {
        char* p = wsb + off; off += (bytes + 255) & ~(size_t)255; return p;
    };

    u16* Sh    = (u16*)carve((size_t)NN * NP * 2);         // 26.3 MB, per-batch
    u16* STh   = (u16*)carve((size_t)NN * NP * 2);         // 26.3 MB, per-batch
    u16* vab   = (u16*)carve((size_t)BB * CC * NP * 2);
    u16* vbb   = (u16*)carve((size_t)BB * CC * NP * 2);
    u16* vat   = (u16*)carve((size_t)BB * NR * CC * 2);
    u16* vbt   = (u16*)carve((size_t)BB * NR * CC * 2);
    u16* daT   = (u16*)carve((size_t)BB * NR * CC * 2);
    u16* gzaT  = (u16*)carve((size_t)BB * NR * CC * 2);
    u16* gzbT  = (u16*)carve((size_t)BB * NR * CC * 2);
    u16* wgtb  = (u16*)carve((size_t)BB * NR * CC * 2);
    u16* web   = (u16*)carve((size_t)CC * CC * 2);
    u16* wt1   = (u16*)carve((size_t)CC * 9 * 768 * 2);
    u16* wt2   = (u16*)carve((size_t)CC * 9 * 512 * 2);
    float* Za  = (float*)carve((size_t)BB * CC * NN * 4);  // contiguous 4-block
    float* Zb  = (float*)carve((size_t)BB * CC * NN * 4);  //   memset region
    float* y1  = (float*)carve((size_t)BB * CC * NN * 4);
    float* y2  = (float*)carve((size_t)BB * CC * NN * 4);
    float* rmx = (float*)carve((size_t)BB * NN * 4);
    float* rsm = (float*)carve((size_t)BB * NN * 4);
    float* cmx = (float*)carve((size_t)BB * NN * 4);
    float* csm = (float*)carve((size_t)BB * NN * 4);
    float* sga = (float*)carve((size_t)BB * NN * 4);
    float* sgb = (float*)carve((size_t)BB * NN * 4);
    float* prm = (float*)carve((size_t)NTI * NR * 4);
    float* prs = (float*)carve((size_t)NTI * NR * 4);
    float* pcm = (float*)carve((size_t)NTI * NR * 4);
    float* pcs = (float*)carve((size_t)NTI * NR * 4);
    float* c1o = (float*)carve((size_t)BB * NCH * NN * 4);
    float* c2o = (float*)carve((size_t)BB * NCH * NN * 4);

    dim3 blk(256);

    // zero-init all atomic accumulators (Za,Zb,y1,y2 contiguous)
    hipMemsetAsync(Za, 0, (size_t)4 * BB * CC * NN * 4, stream);

    // --- input conversions (padded copies fused into transposes) ---
    cvt_we<<<256, blk, 0, stream>>>(W_e, web);
    transpose_cvt<<<dim3(57, 4, BB), blk, 0, stream>>>(V_a, vat, vab);
    transpose_cvt<<<dim3(57, 4, BB), blk, 0, stream>>>(V_b, vbt, vbb);
    transpose_cvt<<<dim3(57, 4, BB), blk, 0, stream>>>(D_a, daT, nullptr);
    cvt_convw<768><<<(int)(((long)CC * 9 * 768 + 255) / 256), blk, 0, stream>>>(conv1_w, wt1);
    cvt_convw<512><<<(int)(((long)CC * 9 * 512 + 255) / 256), blk, 0, stream>>>(conv2_w, wt2);

    // --- weighted (both batches) ---
    gemm_we<<<dim3(2, NTI, BB), blk, 0, stream>>>(vat, web, wgtb);

    // --- attention, per batch ---
    for (int b = 0; b < BB; ++b) {
        const u16* wgtb_b = wgtb + (long)b * NR * CC;
        const u16* vbt_b  = vbt + (long)b * NR * CC;
        const u16* vab_b  = vab + (long)b * CC * NP;
        const u16* vbb_b  = vbb + (long)b * CC * NP;
        float* rmx_b = rmx + b * NN; float* rsm_b = rsm + b * NN;
        float* cmx_b = cmx + b * NN; float* csm_b = csm + b * NN;

        gemm_s_stats<<<dim3(NTI, NTI), blk, 0, stream>>>(
            wgtb_b, vbt_b, Sh, STh, prm, prs, pcm, pcs);
        stats_combine<<<dim3((NN + 255) / 256, 2), blk, 0, stream>>>(
            prm, prs, pcm, pcs, rmx_b, rsm_b, cmx_b, csm_b);
        p_build<<<dim3(NN, 2), blk, 0, stream>>>(Sh, STh, rmx_b, rsm_b, cmx_b, csm_b);
        gemm_z_128<<<dim3(NTI, ZKS, 4), blk, 0, stream>>>(
            vab_b, vbb_b, STh, Sh,
            Zb + (long)b * CC * NN, Za + (long)b * CC * NN);
    }

    // --- gates: per-pixel sigmoid, then transpose-scale to [p][c] bf16 ---
    gate_sig<<<dim3(57, BB), blk, 0, stream>>>(Za, gate_w, sga);
    gate_sig<<<dim3(57, BB), blk, 0, stream>>>(Zb, gate_w, sgb);
    transpose_gate<<<dim3(57, 4, BB), blk, 0, stream>>>(Za, sga, gzaT);
    transpose_gate<<<dim3(57, 4, BB), blk, 0, stream>>>(Zb, sgb, gzbT);

    // --- convs: 128-tile direct split-K GEMM, atomic into y1/y2 ---
    conv_128<768><<<dim3(NTI, ZKS, BB * 2), blk, 0, stream>>>(wt1, gzaT, vat, daT, y1);
    conv_128<512><<<dim3(NTI, ZKS, BB * 2), blk, 0, stream>>>(wt2, gzbT, vbt, vbt, y2);

    // --- BN + cls + resize --- (rmx/rsm/cmx/csm reused as scale/shift)
    bn_stats_kernel<<<256, blk, 0, stream>>>(y1, bn1_g, bn1_b, rmx, rsm);
    bn_stats_kernel<<<256, blk, 0, stream>>>(y2, bn2_g, bn2_b, cmx, csm);
    cls_kernel<<<dim3(57, BB), blk, 0, stream>>>(y1, rmx, rsm, cls1_w, cls1_b, c1o);
    cls_kernel<<<dim3(57, BB), blk, 0, stream>>>(y2, cmx, csm, cls2_w, cls2_b, c2o);

    resize_sig_kernel<<<dim3((int)(((long)BB * NCH * HO * WO + 255) / 256), 2), blk, 0, stream>>>(c1o, c2o, out);
}